// Round 8
// baseline (778.842 us; speedup 1.0000x reference)
//
#include <hip/hip_runtime.h>
#include <hip/hip_bf16.h>

typedef __hip_bfloat16 bf16_t;

static const int cT  = 12;    // future steps
static const int cN  = 128;   // agents
static const int cH  = 128;   // hidden
static const int cK  = 20;    // modes
static const int cKN = 2560;  // cK*cN
static const int cS  = 4;     // batch split
static const int cNS = 32;    // agents per scene
static const int cL  = 640;   // cK*cNS attention length
static const int cHD = 32;    // head dim

#define CONV_TOTAL 977986

__constant__ int c_off[38] = {0,196608,212992,229376,229632,229888,557568,560128,562688,
  565248,630784,696320,696832,762368,827904,828416,844800,844928,861312,861440,877824,
  877952,910720,910976,943744,943872,960256,960384,960512,960640,960896,960960,977344,
  977472,977600,977728,977984,977986};
__constant__ int c_len[37] = {196608,16384,16384,256,256,327680,2560,2560,2560,
  65536,65536,512,65536,65536,512,16384,128,16384,128,16384,128,
  32768,256,32768,128,16384,128,128,128,256,2,16384,128,128,128,256,2};

struct Ptrs { const void* p[37]; };

typedef __attribute__((ext_vector_type(4))) float f32x4;
typedef __attribute__((ext_vector_type(8))) __bf16 bf16x8;

__device__ __forceinline__ float sigm(float x){ return 1.f/(1.f+expf(-x)); }
__device__ __forceinline__ unsigned short f2h(float x){ return (unsigned short)(__float_as_uint(x)>>16); }
__device__ __forceinline__ float hif(float x){ return __uint_as_float(__float_as_uint(x)&0xFFFF0000u); }

// dtype sniffing + NaN canary
__global__ __launch_bounds__(256) void k_detect(const unsigned short* ge_u16, int* flagp, unsigned int* outw){
  __shared__ int cnt;
  if (threadIdx.x == 0) cnt = 0;
  __syncthreads();
  int ok = 0;
  for (int i = threadIdx.x; i < 128; i += 64){
    unsigned short u = ge_u16[2*i];
    int ex = (u >> 7) & 0xFF;
    if (ex >= 100 && ex <= 140) ok++;
  }
  atomicAdd(&cnt, ok);
  __syncthreads();
  if (threadIdx.x == 0){
    *flagp = (cnt >= 96) ? 1 : 0;
    outw[0] = 0x7FC07FC0u;
  }
}

// convert all 37 inputs to fp32 into the conv region
__global__ __launch_bounds__(256) void k_convert(Ptrs ptrs, const int* flagp, float* dst){
  int g = blockIdx.x*256 + threadIdx.x;
  if (g >= CONV_TOTAL) return;
  int flag = *flagp;
  int seg = 0;
  while (seg < 36 && g >= c_off[seg+1]) ++seg;
  int local = g - c_off[seg];
  if (local >= c_len[seg]) return;
  float v;
  if (flag) v = __bfloat162float(((const bf16_t*)ptrs.p[seg])[local]);
  else      v = ((const float*)ptrs.p[seg])[local];
  dst[g] = v;
}

// ge = relu(LN_2560(x @ mhp_W + b)), 2 rows per block, weight reuse across rows
__global__ __launch_bounds__(256) void k_mhp(const float* x, const float* W, const float* b,
                      const float* g, const float* be, float* out){
  const int ROWS = 2;
  int r0 = blockIdx.x*ROWS;
  __shared__ float xs[ROWS][cH];
  __shared__ float red[256][3];
  int tid = threadIdx.x;
  if (tid < ROWS*32){
    int rr = tid>>5, u4 = tid&31;
    ((float4*)&xs[rr][0])[u4] = ((const float4*)x)[(r0+rr)*32 + u4];
  }
  __syncthreads();
  float y[ROWS][10];
  #pragma unroll
  for (int m = 0; m < 10; ++m){ float bb = b[tid + 256*m]; y[0][m] = bb; y[1][m] = bb; }
  for (int i = 0; i < cH; ++i){
    float x0 = xs[0][i], x1 = xs[1][i];
    const float* wr = W + i*2560 + tid;
    #pragma unroll
    for (int m = 0; m < 10; ++m){
      float w = wr[256*m];
      y[0][m] += x0*w; y[1][m] += x1*w;
    }
  }
  float ps0 = 0.f, ps1 = 0.f;
  #pragma unroll
  for (int m = 0; m < 10; ++m){ ps0 += y[0][m]; ps1 += y[1][m]; }
  red[tid][0] = ps0; red[tid][1] = ps1; __syncthreads();
  for (int s2 = 128; s2 > 0; s2 >>= 1){
    if (tid < s2){ red[tid][0] += red[tid+s2][0]; red[tid][1] += red[tid+s2][1]; }
    __syncthreads();
  }
  float mean0 = red[0][0]*(1.f/2560.f), mean1 = red[0][1]*(1.f/2560.f);
  __syncthreads();
  float pv0 = 0.f, pv1 = 0.f;
  #pragma unroll
  for (int m = 0; m < 10; ++m){
    float d0 = y[0][m]-mean0, d1 = y[1][m]-mean1;
    pv0 += d0*d0; pv1 += d1*d1;
  }
  red[tid][0] = pv0; red[tid][1] = pv1; __syncthreads();
  for (int s2 = 128; s2 > 0; s2 >>= 1){
    if (tid < s2){ red[tid][0] += red[tid+s2][0]; red[tid][1] += red[tid+s2][1]; }
    __syncthreads();
  }
  float inv0 = rsqrtf(red[0][0]*(1.f/2560.f) + 1e-5f);
  float inv1 = rsqrtf(red[0][1]*(1.f/2560.f) + 1e-5f);
  #pragma unroll
  for (int rr = 0; rr < ROWS; ++rr){
    int rg = r0 + rr;
    int t = rg >> 7, nn = rg & 127;
    float mean = rr ? mean1 : mean0;
    float inv  = rr ? inv1  : inv0;
    #pragma unroll
    for (int m = 0; m < 10; ++m){
      int col = tid + 256*m;
      float z = (y[rr][m]-mean)*inv*g[col] + be[col];
      z = fmaxf(z, 0.f);
      int k = col >> 7, hh2 = col & 127;
      out[((t*cKN) + k*cN + nn)*cH + hh2] = z;
    }
  }
}

// round-12: preconvert the 4 LSTM weight matrices [128][512] into
// fragment-ordered split-bf16 arrays (per mat: 65536 hi + 65536 lo ushorts,
// layout ((n*4+s)*64+l)*8+e with k = 32s + 16(e>>2) + 4g + (e&3), col=16n+(l&15)).
// Output overlays the dead mhp_W region (1.31 MB >= 1 MB). One-time, ~10us.
__global__ __launch_bounds__(256) void k_wprep(const float* w0, const float* w1,
    const float* w2, const float* w3, unsigned short* out){
  int idx = blockIdx.x*256 + threadIdx.x;   // 32768 total
  int m = idx >> 13;
  int rest = idx & 8191;
  int n = rest >> 8;
  int s = (rest >> 6) & 3;
  int l = rest & 63;
  int g = l >> 4, c16 = l & 15;
  const float* W = (m==0) ? w0 : ((m==1) ? w1 : ((m==2) ? w2 : w3));
  unsigned short hi[8], lo[8];
  #pragma unroll
  for (int e = 0; e < 8; ++e){
    int k = 32*s + 16*(e>>2) + 4*g + (e&3);
    float v = W[k*512 + 16*n + c16];
    hi[e] = f2h(v); lo[e] = f2h(v - hif(v));
  }
  size_t base = (size_t)m*131072 + (size_t)((n*4 + s)*64 + l)*8;
  *(uint4*)&out[base]         = *(const uint4*)hi;
  *(uint4*)&out[base + 65536] = *(const uint4*)lo;
}

// round-14: MFMA LSTM, stall-targeted rework. R7 (116us, MfmaUtil 8, VGPR
// still 128) mislocated the stall: (a) 2 barriers/step each with a full
// vmcnt(0) drain, and the x-prefetch issued right BEFORE the end barrier
// (drain eats its latency serially); (b) tt-major MFMA order = ~24-deep
// dependent accumulator chains (~16cyc stall each); (c) depth-1 weight
// prefetch covers ~40 of ~200cyc L2 latency.
// Fixes: (1) single barrier/step via HF double-buffer (HF[2], 16KB LDS):
// write HF[b] -> barrier -> read HF[b]; next step writes HF[b^1]; program
// order + 1 barrier covers all hazards. (2) ALL heavy loads (x/soc t+1,
// weight gen-0) issued pre-barrier so the mandatory drain absorbs their
// latency concurrently. (3) generation pipeline: gen = 4 groups (tt=0..3)
// at k-slice s; MFMAs p-major/tt-inner (consecutive MFMAs hit different
// accumulators -> 4-way ILP); gen s+1 A-frags load at s start, B-frags
// after the A-products (~120-240cyc cover).
__global__ __launch_bounds__(512, 2) void k_lstm_mfma(const float* ge, float* outh,
    const float* hs0, const float* cn0, const float* soc,
    const unsigned short* wfA, const unsigned short* wfB,
    const float* bias, int phase){
  int r0 = blockIdx.x * 16;
  int tid = threadIdx.x;
  int w = tid >> 6, l = tid & 63;
  int g = l >> 4, c16 = l & 15;
  int scol = w*16 + c16;                 // state col owned by this lane
  __shared__ unsigned short HFh[2][4][64][8], HFl[2][4][64][8];   // 16 KB
  // producer slot constants: scol -> (s, gf, e); lane writes rows 4g+r
  int ps = scol >> 5, prem = scol & 31;
  int pgf = (prem >> 2) & 3;
  int pe  = ((prem >> 4) << 2) + (prem & 3);
  float c[4], h[4];
  #pragma unroll
  for (int r = 0; r < 4; ++r){
    int nn = (r0 + 4*g + r) & 127;
    c[r] = cn0[nn*cH + scol];
    h[r] = hs0[nn*cH + scol];
  }
  float bias_t[4];
  #pragma unroll
  for (int tt = 0; tt < 4; ++tt) bias_t[tt] = bias[tt*128 + scol];

  // prefetch x (and soc) for t=0
  f32x4 xr[8];
  float socr[4] = {0.f, 0.f, 0.f, 0.f};
  {
    const f32x4* gp = (const f32x4*)ge + ((size_t)(r0 + c16))*32;
    #pragma unroll
    for (int s = 0; s < 4; ++s){ xr[2*s] = gp[8*s + g]; xr[2*s+1] = gp[8*s + 4 + g]; }
    if (phase == 2){
      #pragma unroll
      for (int r = 0; r < 4; ++r)
        socr[r] = soc[(size_t)(r0 + 4*g + r)*cH + scol];
    }
  }

  for (int t = 0; t < cT; ++t){
    int b = t & 1;
    if (phase == 2){
      #pragma unroll
      for (int r = 0; r < 4; ++r){
        c[r] += socr[r];
        h[r] += tanhf(c[r]);
      }
    }
    // h fragments into HF[b]
    #pragma unroll
    for (int r = 0; r < 4; ++r){
      HFh[b][ps][pgf*16 + 4*g + r][pe] = f2h(h[r]);
      HFl[b][ps][pgf*16 + 4*g + r][pe] = f2h(h[r] - hif(h[r]));
    }
    // convert x(t) -> frags (xr is then free for the t+1 prefetch)
    bf16x8 xh[4], xl[4];
    #pragma unroll
    for (int s = 0; s < 4; ++s){
      union { unsigned short u[8]; bf16x8 v; } uh, ul;
      #pragma unroll
      for (int m2 = 0; m2 < 4; ++m2){
        float a0 = xr[2*s][m2], b0 = xr[2*s+1][m2];
        uh.u[m2]   = f2h(a0); ul.u[m2]   = f2h(a0 - hif(a0));
        uh.u[4+m2] = f2h(b0); ul.u[4+m2] = f2h(b0 - hif(b0));
      }
      xh[s] = uh.v; xl[s] = ul.v;
    }
    // issue t+1 x/soc prefetch pre-barrier (drain absorbs latency)
    if (t < cT-1){
      const f32x4* gp = (const f32x4*)ge + ((size_t)(t+1)*cKN + r0 + c16)*32;
      #pragma unroll
      for (int s = 0; s < 4; ++s){ xr[2*s] = gp[8*s + g]; xr[2*s+1] = gp[8*s + 4 + g]; }
      if (phase == 2){
        #pragma unroll
        for (int r = 0; r < 4; ++r)
          socr[r] = soc[(size_t)(t+1)*cKN*cH + (size_t)(r0 + 4*g + r)*cH + scol];
      }
    }
    // issue weight generation-0 (s=0) pre-barrier
    bf16x8 cAh[4], cAl[4], cBh[4], cBl[4];
    #pragma unroll
    for (int tt = 0; tt < 4; ++tt){
      size_t fo = (size_t)(((w + 8*tt)*4 + 0)*64 + l)*8;
      cAh[tt] = *(const bf16x8*)&wfA[fo];
      cAl[tt] = *(const bf16x8*)&wfA[65536 + fo];
      cBh[tt] = *(const bf16x8*)&wfB[fo];
      cBl[tt] = *(const bf16x8*)&wfB[65536 + fo];
    }
    __syncthreads();      // single barrier: HF[b] visible; all loads drained
    f32x4 a4[4];
    #pragma unroll
    for (int tt = 0; tt < 4; ++tt){
      f32x4 acc = {bias_t[tt], bias_t[tt], bias_t[tt], bias_t[tt]};
      a4[tt] = acc;
    }
    // 4 generations (k-slices), p-major/tt-inner MFMA order
    bf16x8 nAh[4], nAl[4], nBh[4], nBl[4];
    #pragma unroll
    for (int s = 0; s < 4; ++s){
      bf16x8 hhs = *(const bf16x8*)&HFh[b][s][l][0];
      bf16x8 hls = *(const bf16x8*)&HFl[b][s][l][0];
      if (s < 3){
        #pragma unroll
        for (int tt = 0; tt < 4; ++tt){
          size_t fo = (size_t)(((w + 8*tt)*4 + (s+1))*64 + l)*8;
          nAh[tt] = *(const bf16x8*)&wfA[fo];
          nAl[tt] = *(const bf16x8*)&wfA[65536 + fo];
        }
      }
      #pragma unroll
      for (int tt = 0; tt < 4; ++tt) a4[tt] = __builtin_amdgcn_mfma_f32_16x16x32_bf16(xl[s], cAh[tt], a4[tt], 0, 0, 0);
      #pragma unroll
      for (int tt = 0; tt < 4; ++tt) a4[tt] = __builtin_amdgcn_mfma_f32_16x16x32_bf16(xh[s], cAl[tt], a4[tt], 0, 0, 0);
      #pragma unroll
      for (int tt = 0; tt < 4; ++tt) a4[tt] = __builtin_amdgcn_mfma_f32_16x16x32_bf16(xh[s], cAh[tt], a4[tt], 0, 0, 0);
      if (s < 3){
        #pragma unroll
        for (int tt = 0; tt < 4; ++tt){
          size_t fo = (size_t)(((w + 8*tt)*4 + (s+1))*64 + l)*8;
          nBh[tt] = *(const bf16x8*)&wfB[fo];
          nBl[tt] = *(const bf16x8*)&wfB[65536 + fo];
        }
      }
      #pragma unroll
      for (int tt = 0; tt < 4; ++tt) a4[tt] = __builtin_amdgcn_mfma_f32_16x16x32_bf16(hls, cBh[tt], a4[tt], 0, 0, 0);
      #pragma unroll
      for (int tt = 0; tt < 4; ++tt) a4[tt] = __builtin_amdgcn_mfma_f32_16x16x32_bf16(hhs, cBl[tt], a4[tt], 0, 0, 0);
      #pragma unroll
      for (int tt = 0; tt < 4; ++tt) a4[tt] = __builtin_amdgcn_mfma_f32_16x16x32_bf16(hhs, cBh[tt], a4[tt], 0, 0, 0);
      if (s < 3){
        #pragma unroll
        for (int tt = 0; tt < 4; ++tt){
          cAh[tt] = nAh[tt]; cAl[tt] = nAl[tt];
          cBh[tt] = nBh[tt]; cBl[tt] = nBl[tt];
        }
      }
    }
    // gates + state update + output store
    #pragma unroll
    for (int r = 0; r < 4; ++r){
      float ig = sigm(a4[0][r]), fg = sigm(a4[1][r]);
      float gg = tanhf(a4[2][r]), og = sigm(a4[3][r]);
      c[r] = fg*c[r] + ig*gg;
      h[r] = og*tanhf(c[r]);
      outh[(size_t)t*cKN*cH + (size_t)(r0 + 4*g + r)*cH + scol] = h[r];
    }
    // no end barrier: HF is double-buffered (next step writes HF[b^1])
  }
}

// loc & scale heads, wave-local: wave = (head, row-pair), shfl reductions, no trees.
__global__ __launch_bounds__(256) void k_heads(const float* x,
  const float* lW1, const float* lb1, const float* lg, const float* lbe, const float* lW2, const float* lb2v,
  const float* sW1, const float* sb1, const float* sg, const float* sbe, const float* sW2, const float* sb2v,
  void* outv, int q0, float* locsc, const float* maxv, const float* svp, const int* flagp){
  const int ROWS = 4;
  int r0 = blockIdx.x*ROWS;
  __shared__ float xs[ROWS][cH];
  int tid = threadIdx.x;
  if (tid < ROWS*32){
    int rr = tid>>5, u4 = tid&31;
    ((float4*)&xs[rr][0])[u4] = ((const float4*)x)[(size_t)(r0+rr)*32 + u4];
  }
  __syncthreads();
  int wv = tid >> 6, lane = tid & 63;
  int head = wv & 1;
  int ra = (wv >> 1)*2, rb = ra + 1;     // local rows
  const float* W1 = head ? sW1 : lW1;
  const float* b1 = head ? sb1 : lb1;
  const float* gv = head ? sg  : lg;
  const float* be = head ? sbe : lbe;
  const float* W2 = head ? sW2 : lW2;
  const float* b2 = head ? sb2v: lb2v;
  int j0 = lane, j1 = lane + 64;
  float a00 = b1[j0], a01 = b1[j1];
  float a10 = a00, a11 = a01;
  for (int i = 0; i < cH; ++i){
    float w0 = W1[i*cH + j0], w1 = W1[i*cH + j1];
    float xa = xs[ra][i], xb = xs[rb][i];
    a00 += xa*w0; a01 += xa*w1;
    a10 += xb*w0; a11 += xb*w1;
  }
  float s0 = a00 + a01, s1 = a10 + a11;
  #pragma unroll
  for (int off = 1; off < 64; off <<= 1){
    s0 += __shfl_xor(s0, off);
    s1 += __shfl_xor(s1, off);
  }
  float mean0 = s0*(1.f/128.f), mean1 = s1*(1.f/128.f);
  float d00 = a00-mean0, d01 = a01-mean0, d10 = a10-mean1, d11 = a11-mean1;
  float v0 = d00*d00 + d01*d01, v1 = d10*d10 + d11*d11;
  #pragma unroll
  for (int off = 1; off < 64; off <<= 1){
    v0 += __shfl_xor(v0, off);
    v1 += __shfl_xor(v1, off);
  }
  float inv0 = rsqrtf(v0*(1.f/128.f) + 1e-5f);
  float inv1 = rsqrtf(v1*(1.f/128.f) + 1e-5f);
  float g0 = gv[j0], g1 = gv[j1], be0 = be[j0], be1 = be[j1];
  float z00 = fmaxf(d00*inv0*g0 + be0, 0.f);
  float z01 = fmaxf(d01*inv0*g1 + be1, 0.f);
  float z10 = fmaxf(d10*inv1*g0 + be0, 0.f);
  float z11 = fmaxf(d11*inv1*g1 + be1, 0.f);
  float w2a0 = W2[j0*2+0], w2a1 = W2[j0*2+1];
  float w2b0 = W2[j1*2+0], w2b1 = W2[j1*2+1];
  float oa0 = z00*w2a0 + z01*w2b0;   // row ra, out 0
  float oa1 = z00*w2a1 + z01*w2b1;   // row ra, out 1
  float ob0 = z10*w2a0 + z11*w2b0;
  float ob1 = z10*w2a1 + z11*w2b1;
  #pragma unroll
  for (int off = 1; off < 64; off <<= 1){
    oa0 += __shfl_xor(oa0, off);
    oa1 += __shfl_xor(oa1, off);
    ob0 += __shfl_xor(ob0, off);
    ob1 += __shfl_xor(ob1, off);
  }
  if (lane == 0){
    int flag = *flagp;
    float bias0 = b2[0], bias1 = b2[1];
    float ro[2][2] = {{oa0 + bias0, oa1 + bias1},{ob0 + bias0, ob1 + bias1}};
    int lr[2] = {ra, rb};
    for (int e = 0; e < 2; ++e){
      int rg = r0 + lr[e];
      int t = rg / cKN, rem = rg - t*cKN;
      int k = rem >> 7, nn = rem & 127;
      float u0 = ro[e][0], u1 = ro[e][1];
      if (head == 0){
        size_t oi = (((size_t)q0*cK + k)*cN + nn)*(cT*2) + t*2;
        if (flag){ ((bf16_t*)outv)[oi] = __float2bfloat16(u0); ((bf16_t*)outv)[oi+1] = __float2bfloat16(u1); }
        else     { ((float*)outv)[oi] = u0; ((float*)outv)[oi+1] = u1; }
        if (locsc){
          locsc[((size_t)t*cKN + rem)*2 + 0] = u0*maxv[nn*2+0] + svp[nn*2+0];
          locsc[((size_t)t*cKN + rem)*2 + 1] = u1*maxv[nn*2+1] + svp[nn*2+1];
        }
      } else {
        float e0 = (u0 > 0.f ? u0 : expm1f(u0)) + 1.001f;
        float e1 = (u1 > 0.f ? u1 : expm1f(u1)) + 1.001f;
        size_t oi = (((size_t)(q0+1)*cK + k)*cN + nn)*(cT*2) + t*2;
        if (flag){ ((bf16_t*)outv)[oi] = __float2bfloat16(e0); ((bf16_t*)outv)[oi+1] = __float2bfloat16(e1); }
        else     { ((float*)outv)[oi] = e0; ((float*)outv)[oi+1] = e1; }
      }
    }
  }
}

__global__ __launch_bounds__(256) void k_mask(const float* locsc, unsigned char* m){
  int st = blockIdx.x;
  int s = st / cT, t = st - s*cT;
  __shared__ float lx[cK][cNS], ly[cK][cNS];
  int tid = threadIdx.x;
  for (int p = tid; p < cK*cNS; p += 256){
    int k = p >> 5, i = p & 31;
    int row = t*cKN + k*cN + s*cNS + i;
    lx[k][i] = locsc[row*2+0];
    ly[k][i] = locsc[row*2+1];
  }
  __syncthreads();
  for (int p = tid; p < 1024; p += 256){
    int i = p >> 5, j = p & 31;
    bool any = false;
    for (int k = 0; k < cK; ++k){
      float dx = fabsf(lx[k][i]-lx[k][j]);
      float dy = fabsf(ly[k][i]-ly[k][j]);
      any = any || ((dx < 10.f) && (dy < 10.f));
    }
    m[st*1024 + p] = any ? 1 : 0;
  }
}

// QKV projection, 16 rows/block, weight reuse for 8 rows/thread
__global__ __launch_bounds__(256) void k_qkv(const float* x,
  const float* Wq, const float* bq, const float* Wk, const float* bk,
  const float* Wv, const float* bv,
  float* Q, float* K2, float* V){
  const int ROWS = 16;
  int r0 = blockIdx.x*ROWS;
  __shared__ float xs[ROWS][cH];
  int tid = threadIdx.x;
  for (int p = tid; p < ROWS*32; p += 256){
    int rr = p>>5, u4 = p&31;
    ((float4*)&xs[rr][0])[u4] = ((const float4*)x)[(size_t)(r0+rr)*32 + u4];
  }
  __syncthreads();
  int cl = tid & 127, half = tid >> 7;
  float aq[8], ak[8], av[8];
  float bq0 = bq[cl], bk0 = bk[cl], bv0 = bv[cl];
  #pragma unroll
  for (int r = 0; r < 8; ++r){ aq[r] = bq0; ak[r] = bk0; av[r] = bv0; }
  for (int i = 0; i < cH; ++i){
    float wq = Wq[i*cH+cl], wk = Wk[i*cH+cl], wv = Wv[i*cH+cl];
    #pragma unroll
    for (int q2 = 0; q2 < 8; ++q2){
      float xi = xs[half + 2*q2][i];
      aq[q2] += xi*wq; ak[q2] += xi*wk; av[q2] += xi*wv;
    }
  }
  #pragma unroll
  for (int q2 = 0; q2 < 8; ++q2){
    size_t gi = (size_t)(r0 + half + 2*q2)*cH + cl;
    Q[gi] = aq[q2]; K2[gi] = ak[q2]; V[gi] = av[q2];
  }
}

// round-10: MFMA attention (validated). Split-bf16 3-mfma products; QK^T =
// mfma(A=K, B=Q) with k-map k=16(e>>2)+4g+(e&3); PV A-frag = lane's own
// S-accumulator. No-max softmax. K/V staged to LDS in fragment order.
__global__ __launch_bounds__(256) void k_attn(const float* Q, const float* Kx, const float* V,
                       const unsigned char* msk, float* ctx){
  int qs   = blockIdx.x;        // 0..4 : group of 8 q-tiles (2 per wave)
  int head = blockIdx.y;        // 0..3
  int st   = blockIdx.z;        // s*cT + t
  int s = st / cT, t = st - s*cT;
  __shared__ unsigned short KLh[2][1024], KLl[2][1024], VLh[2][1024], VLl[2][1024]; // 16 KB
  int tid = threadIdx.x;
  int w = tid >> 6, lane = tid & 63;
  int g = lane >> 4, col = lane & 15;
  const float scl = 0.17677669529663687f;   // 1/sqrt(32)

  // mask rows (q_agent = col, col+16) packed to 32-bit words (byte->bit)
  unsigned int mw0 = 0, mw1 = 0;
  {
    const unsigned int* mr0 = (const unsigned int*)(msk + st*1024 + col*32);
    const unsigned int* mr1 = (const unsigned int*)(msk + st*1024 + (16+col)*32);
    #pragma unroll
    for (int j2 = 0; j2 < 8; ++j2){
      mw0 |= (((mr0[j2] * 0x01020408u) >> 24) & 0xFu) << (4*j2);
      mw1 |= (((mr1[j2] * 0x01020408u) >> 24) & 0xFu) << (4*j2);
    }
  }

  // Q fragments (pre-scaled by scl), 2 tiles per wave; B col = lane&15
  bf16x8 Qh[2], Ql[2];
  int modes[2], ahs[2];
  #pragma unroll
  for (int i = 0; i < 2; ++i){
    int tt = qs*8 + 4*i + w;       // 0..39
    int mode = tt >> 1, ah = tt & 1;
    modes[i] = mode; ahs[i] = ah;
    int qrow = t*cKN + mode*cN + s*cNS + ah*16 + col;
    const f32x4* qp = (const f32x4*)Q + (size_t)qrow*32 + head*8;
    f32x4 qa = qp[g], qb = qp[4+g];     // dims 4g..4g+3, 16+4g..16+4g+3
    union { unsigned short u[8]; bf16x8 v; } uh, ul;
    #pragma unroll
    for (int m = 0; m < 4; ++m){
      float x0 = qa[m]*scl;
      uh.u[m] = f2h(x0);
      ul.u[m] = f2h(x0 - hif(x0));
      float x1 = qb[m]*scl;
      uh.u[4+m] = f2h(x1);
      ul.u[4+m] = f2h(x1 - hif(x1));
    }
    Qh[i] = uh.v; Ql[i] = ul.v;
  }

  // staging indices
  int kk = tid >> 3, f4 = tid & 7;                 // K: key kk, dims 4*f4..+3
  int kwi = (((kk>>4)*4 + (f4&3))*16 + (kk&15))*8 + (f4>>2)*4;
  int vd = tid & 31, quad = tid >> 5;              // V: dim vd, keys base..+3
  int vkey = (quad>>2)*16 + (quad&3)*4;
  int vwi = (((vd>>4)*4 + (quad&3))*16 + (vd&15))*8 + (quad>>2)*4;

  const size_t cstepK = (size_t)cN*32;             // float4 per chunk (one mode)
  const size_t cstepV = (size_t)cN*128;            // float per chunk
  const float4* kptr = (const float4*)Kx + ((size_t)(t*cKN + s*cNS + kk))*32 + head*8 + f4;
  const float*  vptr = V + ((size_t)(t*cKN + s*cNS + vkey))*128 + head*32 + vd;

  float4 kv; float vm0, vm1, vm2, vm3;
  kv = *kptr; kptr += cstepK;
  vm0 = vptr[0]; vm1 = vptr[128]; vm2 = vptr[256]; vm3 = vptr[384]; vptr += cstepV;
  {
    unsigned int h0 = (unsigned int)f2h(kv.x) | ((unsigned int)f2h(kv.y)<<16);
    unsigned int h1 = (unsigned int)f2h(kv.z) | ((unsigned int)f2h(kv.w)<<16);
    float r0 = kv.x-hif(kv.x), r1 = kv.y-hif(kv.y), r2 = kv.z-hif(kv.z), r3 = kv.w-hif(kv.w);
    unsigned int l0 = (unsigned int)f2h(r0) | ((unsigned int)f2h(r1)<<16);
    unsigned int l1 = (unsigned int)f2h(r2) | ((unsigned int)f2h(r3)<<16);
    *(uint2*)&KLh[0][kwi] = make_uint2(h0,h1);
    *(uint2*)&KLl[0][kwi] = make_uint2(l0,l1);
    unsigned int vh0 = (unsigned int)f2h(vm0) | ((unsigned int)f2h(vm1)<<16);
    unsigned int vh1 = (unsigned int)f2h(vm2) | ((unsigned int)f2h(vm3)<<16);
    float s0 = vm0-hif(vm0), s1 = vm1-hif(vm1), s2 = vm2-hif(vm2), s3 = vm3-hif(vm3);
    unsigned int vl0 = (unsigned int)f2h(s0) | ((unsigned int)f2h(s1)<<16);
    unsigned int vl1 = (unsigned int)f2h(s2) | ((unsigned int)f2h(s3)<<16);
    *(uint2*)&VLh[0][vwi] = make_uint2(vh0,vh1);
    *(uint2*)&VLl[0][vwi] = make_uint2(vl0,vl1);
  }
  __syncthreads();

  const f32x4 Z = {0.f, 0.f, 0.f, 0.f};
  f32x4 O[2][2] = {{Z, Z}, {Z, Z}};
  float lac[2] = {0.f, 0.f};

  for (int ch = 0; ch < 20; ++ch){
    int par = ch & 1;
    if (ch < 19){
      kv = *kptr; kptr += cstepK;
      vm0 = vptr[0]; vm1 = vptr[128]; vm2 = vptr[256]; vm3 = vptr[384]; vptr += cstepV;
    }
    // fragment reads (shared across this wave's tiles)
    bf16x8 KAh0 = *(const bf16x8*)&KLh[par][( g      *16 + col)*8];
    bf16x8 KAl0 = *(const bf16x8*)&KLl[par][( g      *16 + col)*8];
    bf16x8 KAh1 = *(const bf16x8*)&KLh[par][((4 + g) *16 + col)*8];
    bf16x8 KAl1 = *(const bf16x8*)&KLl[par][((4 + g) *16 + col)*8];
    bf16x8 VBh0 = *(const bf16x8*)&VLh[par][( g      *16 + col)*8];
    bf16x8 VBl0 = *(const bf16x8*)&VLl[par][( g      *16 + col)*8];
    bf16x8 VBh1 = *(const bf16x8*)&VLh[par][((4 + g) *16 + col)*8];
    bf16x8 VBl1 = *(const bf16x8*)&VLl[par][((4 + g) *16 + col)*8];
    #pragma unroll
    for (int i = 0; i < 2; ++i){
      f32x4 sa = Z, sb = Z;
      sa = __builtin_amdgcn_mfma_f32_16x16x32_bf16(KAl0, Qh[i], sa, 0, 0, 0);
      sa = __builtin_amdgcn_mfma_f32_16x16x32_bf16(KAh0, Ql[i], sa, 0, 0, 0);
      sa = __builtin_amdgcn_mfma_f32_16x16x32_bf16(KAh0, Qh[i], sa, 0, 0, 0);
      sb = __builtin_amdgcn_mfma_f32_16x16x32_bf16(KAl1, Qh[i], sb, 0, 0, 0);
      sb = __builtin_amdgcn_mfma_f32_16x16x32_bf16(KAh1, Ql[i], sb, 0, 0, 0);
      sb = __builtin_amdgcn_mfma_f32_16x16x32_bf16(KAh1, Qh[i], sb, 0, 0, 0);
      unsigned int mw = ahs[i] ? mw1 : mw0;
      float p[8];
      #pragma unroll
      for (int r = 0; r < 4; ++r){
        float e0 = __expf(sa[r]);
        float e1 = __expf(sb[r]);
        p[r]   = ((mw >> (4*g + r)) & 1)        ? e0 : 0.f;
        p[4+r] = ((mw >> (16 + 4*g + r)) & 1)   ? e1 : 0.f;
      }
      lac[i] += ((p[0]+p[1])+(p[2]+p[3])) + ((p[4]+p[5])+(p[6]+p[7]));
      union { unsigned short u[8]; bf16x8 v; } Ph, Pl;
      #pragma unroll
      for (int e = 0; e < 8; ++e){
        Ph.u[e] = f2h(p[e]);
        Pl.u[e] = f2h(p[e] - hif(p[e]));
      }
      O[i][0] = __builtin_amdgcn_mfma_f32_16x16x32_bf16(Pl.v, VBh0, O[i][0], 0, 0, 0);
      O[i][0] = __builtin_amdgcn_mfma_f32_16x16x32_bf16(Ph.v, VBl0, O[i][0], 0, 0, 0);
      O[i][0] = __builtin_amdgcn_mfma_f32_16x16x32_bf16(Ph.v, VBh0, O[i][0], 0, 0, 0);
      O[i][1] = __builtin_amdgcn_mfma_f32_16x16x32_bf16(Pl.v, VBh1, O[i][1], 0, 0, 0);
      O[i][1] = __builtin_amdgcn_mfma_f32_16x16x32_bf16(Ph.v, VBl1, O[i][1], 0, 0, 0);
      O[i][1] = __builtin_amdgcn_mfma_f32_16x16x32_bf16(Ph.v, VBh1, O[i][1], 0, 0, 0);
    }
    __syncthreads();   // all frag reads of [par] done
    if (ch < 19){
      int nb = 1 - par;
      unsigned int h0 = (unsigned int)f2h(kv.x) | ((unsigned int)f2h(kv.y)<<16);
      unsigned int h1 = (unsigned int)f2h(kv.z) | ((unsigned int)f2h(kv.w)<<16);
      float r0 = kv.x-hif(kv.x), r1 = kv.y-hif(kv.y), r2 = kv.z-hif(kv.z), r3 = kv.w-hif(kv.w);
      unsigned int l0 = (unsigned int)f2h(r0) | ((unsigned int)f2h(r1)<<16);
      unsigned int l1 = (unsigned int)f2h(r2) | ((unsigned int)f2h(r3)<<16);
      *(uint2*)&KLh[nb][kwi] = make_uint2(h0,h1);
      *(uint2*)&KLl[nb][kwi] = make_uint2(l0,l1);
      unsigned int vh0 = (unsigned int)f2h(vm0) | ((unsigned int)f2h(vm1)<<16);
      unsigned int vh1 = (unsigned int)f2h(vm2) | ((unsigned int)f2h(vm3)<<16);
      float s0 = vm0-hif(vm0), s1 = vm1-hif(vm1), s2 = vm2-hif(vm2), s3 = vm3-hif(vm3);
      unsigned int vl0 = (unsigned int)f2h(s0) | ((unsigned int)f2h(s1)<<16);
      unsigned int vl1 = (unsigned int)f2h(s2) | ((unsigned int)f2h(s3)<<16);
      *(uint2*)&VLh[nb][vwi] = make_uint2(vh0,vh1);
      *(uint2*)&VLl[nb][vwi] = make_uint2(vl0,vl1);
    }
    __syncthreads();   // next buffer visible
  }

  // epilogue: row denominators + normalized writes
  #pragma unroll
  for (int i = 0; i < 2; ++i){
    float lsum = lac[i];
    lsum += __shfl_xor(lsum, 16);
    lsum += __shfl_xor(lsum, 32);
    int base = t*cKN + modes[i]*cN + s*cNS + ahs[i]*16;
    #pragma unroll
    for (int r = 0; r < 4; ++r){
      float lq = __shfl(lsum, 4*g + r);
      float rinv = 1.f / lq;
      float* cp = ctx + (size_t)(base + 4*g + r)*cH + head*cHD;
      cp[col]      = O[i][0][r] * rinv;
      cp[col+16]   = O[i][1][r] * rinv;
    }
  }
}

// Wo1 + relu, 8 rows/block, weight reuse
__global__ __launch_bounds__(256) void k_wo1(const float* x, const float* W, const float* b, float* o){
  const int ROWS = 8;
  int r0 = blockIdx.x*ROWS;
  __shared__ float xs[ROWS][cH];
  int tid = threadIdx.x;
  {
    int rr = tid>>5, u4 = tid&31;
    ((float4*)&xs[rr][0])[u4] = ((const float4*)x)[(size_t)(r0+rr)*32 + u4];
  }
  __syncthreads();
  float a[8];
  float bb = b[tid];
  #pragma unroll
  for (int r = 0; r < 8; ++r) a[r] = bb;
  for (int i = 0; i < cH; ++i){
    float w = W[i*256 + tid];
    #pragma unroll
    for (int r = 0; r < 8; ++r) a[r] += xs[r][i]*w;
  }
  #pragma unroll
  for (int r = 0; r < 8; ++r) o[(size_t)(r0+r)*256 + tid] = fmaxf(a[r], 0.f);
}

// Wo2, 16 rows/block, weight reuse
__global__ __launch_bounds__(256) void k_wo2(const float* x, const float* W, const float* b, float* o){
  const int ROWS = 16;
  int r0 = blockIdx.x*ROWS;
  __shared__ float xs[ROWS][256];
  int tid = threadIdx.x;
  for (int p = tid; p < ROWS*64; p += 256){
    int rr = p>>6, u4 = p&63;
    ((float4*)&xs[rr][0])[u4] = ((const float4*)x)[(size_t)(r0+rr)*64 + u4];
  }
  __syncthreads();
  int cl = tid & 127, half = tid >> 7;
  float a[8];
  float bb = b[cl];
  #pragma unroll
  for (int r = 0; r < 8; ++r) a[r] = bb;
  for (int i = 0; i < 256; ++i){
    float w = W[i*cH + cl];
    #pragma unroll
    for (int q2 = 0; q2 < 8; ++q2) a[q2] += xs[half + 2*q2][i]*w;
  }
  #pragma unroll
  for (int q2 = 0; q2 < 8; ++q2) o[(size_t)(r0 + half + 2*q2)*cH + cl] = a[q2];
}

extern "C" void kernel_launch(void* const* d_in, const int* in_sizes, int n_in,
                              void* d_out, int out_size, void* d_ws, size_t ws_size,
                              hipStream_t stream){
  (void)in_sizes; (void)n_in; (void)out_size; (void)ws_size;

  int*   flagp = (int*)d_ws;
  float* conv  = (float*)d_ws + 64;
  float* big   = (float*)d_ws + 978112;

  const float* ge_f   = conv + 0;
  const float* hs_f   = conv + 196608;
  const float* cn_f   = conv + 212992;
  const float* sv_f   = conv + 229376;
  const float* mx_f   = conv + 229632;
  const float* mhpW_f = conv + 229888;
  const float* mhpb_f = conv + 557568;
  const float* mhpg_f = conv + 560128;
  const float* mhpbe_f= conv + 562688;
  const float* l1Wih_f= conv + 565248;
  const float* l1Whh_f= conv + 630784;
  const float* l1b_f  = conv + 696320;
  const float* l2Wih_f= conv + 696832;
  const float* l2Whh_f= conv + 762368;
  const float* l2b_f  = conv + 827904;
  const float* Wq_f   = conv + 828416;
  const float* bq_f   = conv + 844800;
  const float* Wk_f   = conv + 844928;
  const float* bk_f   = conv + 861312;
  const float* Wv_f   = conv + 861440;
  const float* bv_f   = conv + 877824;
  const float* Wo1_f  = conv + 877952;
  const float* bo1_f  = conv + 910720;
  const float* Wo2_f  = conv + 910976;
  const float* bo2_f  = conv + 943744;
  const float* locW1_f= conv + 943872;
  const float* locb1_f= conv + 960256;
  const float* locg_f = conv + 960384;
  const float* locbe_f= conv + 960512;
  const float* locW2_f= conv + 960640;
  const float* locb2_f= conv + 960896;
  const float* sclW1_f= conv + 960960;
  const float* sclb1_f= conv + 977344;
  const float* sclg_f = conv + 977472;
  const float* sclbe_f= conv + 977600;
  const float* sclW2_f= conv + 977728;
  const float* sclb2_f= conv + 977984;

  const size_t SLOT = (size_t)cT*cKN*cH;
  float* geb = big;
  float* o1b = big + SLOT;
  float* Qb  = big + 2*SLOT;
  float* Kb  = big + 3*SLOT;
  float* Vb  = big + 4*SLOT;
  float* locsc = big + 5*SLOT;
  unsigned char* maskb = (unsigned char*)(locsc + (size_t)cT*cKN*2);
  float* t1 = Qb;        // spans slots 2-3 (Q/K dead after attn)
  float* social = Vb;    // overlays V after attention

  // LSTM weight fragments overlay the mhp_W region (1.31 MB, dead after k_mhp)
  unsigned short* wfrag = (unsigned short*)(conv + 229888);

  Ptrs ptrs;
  for (int i = 0; i < 37; ++i) ptrs.p[i] = d_in[i];

  k_detect<<<1, 64, 0, stream>>>((const unsigned short*)d_in[0], flagp, (unsigned int*)d_out);
  k_convert<<<(CONV_TOTAL+255)/256, 256, 0, stream>>>(ptrs, flagp, conv);
  k_mhp<<<cT*cN/2, 256, 0, stream>>>(ge_f, mhpW_f, mhpb_f, mhpg_f, mhpbe_f, geb);
  k_wprep<<<128, 256, 0, stream>>>(l1Wih_f, l1Whh_f, l2Wih_f, l2Whh_f, wfrag);
  k_lstm_mfma<<<160, 512, 0, stream>>>(geb, o1b, hs_f, cn_f, (const float*)0,
                                       wfrag + 0, wfrag + 131072, l1b_f, 1);
  k_heads<<<cT*cKN/4, 256, 0, stream>>>(o1b, locW1_f,locb1_f,locg_f,locbe_f,locW2_f,locb2_f,
                                        sclW1_f,sclb1_f,sclg_f,sclbe_f,sclW2_f,sclb2_f,
                                        d_out, 0, locsc, mx_f, sv_f, flagp);
  k_mask<<<cS*cT, 256, 0, stream>>>(locsc, maskb);
  k_qkv<<<cT*cKN/16, 256, 0, stream>>>(o1b, Wq_f,bq_f, Wk_f,bk_f, Wv_f,bv_f, Qb, Kb, Vb);
  {
    dim3 ag(5, 4, cS*cT);
    k_attn<<<ag, 256, 0, stream>>>(Qb, Kb, Vb, maskb, o1b);   // ctx overlays out1
  }
  k_wo1<<<cT*cKN/8, 256, 0, stream>>>(o1b, Wo1_f, bo1_f, t1);
  k_wo2<<<cT*cKN/16, 256, 0, stream>>>(t1, Wo2_f, bo2_f, social);
  k_lstm_mfma<<<160, 512, 0, stream>>>(geb, o1b, hs_f, cn_f, social,
                                       wfrag + 262144, wfrag + 393216, l2b_f, 2);
  k_heads<<<cT*cKN/4, 256, 0, stream>>>(o1b, locW1_f,locb1_f,locg_f,locbe_f,locW2_f,locb2_f,
                                        sclW1_f,sclb1_f,sclg_f,sclbe_f,sclW2_f,sclb2_f,
                                        d_out, 2, (float*)0, mx_f, sv_f, flagp);
}

// Round 9
// 650.517 us; speedup vs baseline: 1.1973x; 1.1973x over previous
//
#include <hip/hip_runtime.h>
#include <hip/hip_bf16.h>

typedef __hip_bfloat16 bf16_t;

static const int cT  = 12;    // future steps
static const int cN  = 128;   // agents
static const int cH  = 128;   // hidden
static const int cK  = 20;    // modes
static const int cKN = 2560;  // cK*cN
static const int cS  = 4;     // batch split
static const int cNS = 32;    // agents per scene
static const int cL  = 640;   // cK*cNS attention length
static const int cHD = 32;    // head dim

#define CONV_TOTAL 977986

__constant__ int c_off[38] = {0,196608,212992,229376,229632,229888,557568,560128,562688,
  565248,630784,696320,696832,762368,827904,828416,844800,844928,861312,861440,877824,
  877952,910720,910976,943744,943872,960256,960384,960512,960640,960896,960960,977344,
  977472,977600,977728,977984,977986};
__constant__ int c_len[37] = {196608,16384,16384,256,256,327680,2560,2560,2560,
  65536,65536,512,65536,65536,512,16384,128,16384,128,16384,128,
  32768,256,32768,128,16384,128,128,128,256,2,16384,128,128,128,256,2};

struct Ptrs { const void* p[37]; };

typedef __attribute__((ext_vector_type(4))) float f32x4;
typedef __attribute__((ext_vector_type(8))) __bf16 bf16x8;

__device__ __forceinline__ float sigm(float x){ return 1.f/(1.f+expf(-x)); }
__device__ __forceinline__ unsigned short f2h(float x){ return (unsigned short)(__float_as_uint(x)>>16); }
__device__ __forceinline__ float hif(float x){ return __uint_as_float(__float_as_uint(x)&0xFFFF0000u); }

// dtype sniffing + NaN canary
__global__ __launch_bounds__(256) void k_detect(const unsigned short* ge_u16, int* flagp, unsigned int* outw){
  __shared__ int cnt;
  if (threadIdx.x == 0) cnt = 0;
  __syncthreads();
  int ok = 0;
  for (int i = threadIdx.x; i < 128; i += 64){
    unsigned short u = ge_u16[2*i];
    int ex = (u >> 7) & 0xFF;
    if (ex >= 100 && ex <= 140) ok++;
  }
  atomicAdd(&cnt, ok);
  __syncthreads();
  if (threadIdx.x == 0){
    *flagp = (cnt >= 96) ? 1 : 0;
    outw[0] = 0x7FC07FC0u;
  }
}

// convert all 37 inputs to fp32 into the conv region
__global__ __launch_bounds__(256) void k_convert(Ptrs ptrs, const int* flagp, float* dst){
  int g = blockIdx.x*256 + threadIdx.x;
  if (g >= CONV_TOTAL) return;
  int flag = *flagp;
  int seg = 0;
  while (seg < 36 && g >= c_off[seg+1]) ++seg;
  int local = g - c_off[seg];
  if (local >= c_len[seg]) return;
  float v;
  if (flag) v = __bfloat162float(((const bf16_t*)ptrs.p[seg])[local]);
  else      v = ((const float*)ptrs.p[seg])[local];
  dst[g] = v;
}

// ge = relu(LN_2560(x @ mhp_W + b)), 2 rows per block, weight reuse across rows
__global__ __launch_bounds__(256) void k_mhp(const float* x, const float* W, const float* b,
                      const float* g, const float* be, float* out){
  const int ROWS = 2;
  int r0 = blockIdx.x*ROWS;
  __shared__ float xs[ROWS][cH];
  __shared__ float red[256][3];
  int tid = threadIdx.x;
  if (tid < ROWS*32){
    int rr = tid>>5, u4 = tid&31;
    ((float4*)&xs[rr][0])[u4] = ((const float4*)x)[(r0+rr)*32 + u4];
  }
  __syncthreads();
  float y[ROWS][10];
  #pragma unroll
  for (int m = 0; m < 10; ++m){ float bb = b[tid + 256*m]; y[0][m] = bb; y[1][m] = bb; }
  for (int i = 0; i < cH; ++i){
    float x0 = xs[0][i], x1 = xs[1][i];
    const float* wr = W + i*2560 + tid;
    #pragma unroll
    for (int m = 0; m < 10; ++m){
      float w = wr[256*m];
      y[0][m] += x0*w; y[1][m] += x1*w;
    }
  }
  float ps0 = 0.f, ps1 = 0.f;
  #pragma unroll
  for (int m = 0; m < 10; ++m){ ps0 += y[0][m]; ps1 += y[1][m]; }
  red[tid][0] = ps0; red[tid][1] = ps1; __syncthreads();
  for (int s2 = 128; s2 > 0; s2 >>= 1){
    if (tid < s2){ red[tid][0] += red[tid+s2][0]; red[tid][1] += red[tid+s2][1]; }
    __syncthreads();
  }
  float mean0 = red[0][0]*(1.f/2560.f), mean1 = red[0][1]*(1.f/2560.f);
  __syncthreads();
  float pv0 = 0.f, pv1 = 0.f;
  #pragma unroll
  for (int m = 0; m < 10; ++m){
    float d0 = y[0][m]-mean0, d1 = y[1][m]-mean1;
    pv0 += d0*d0; pv1 += d1*d1;
  }
  red[tid][0] = pv0; red[tid][1] = pv1; __syncthreads();
  for (int s2 = 128; s2 > 0; s2 >>= 1){
    if (tid < s2){ red[tid][0] += red[tid+s2][0]; red[tid][1] += red[tid+s2][1]; }
    __syncthreads();
  }
  float inv0 = rsqrtf(red[0][0]*(1.f/2560.f) + 1e-5f);
  float inv1 = rsqrtf(red[0][1]*(1.f/2560.f) + 1e-5f);
  #pragma unroll
  for (int rr = 0; rr < ROWS; ++rr){
    int rg = r0 + rr;
    int t = rg >> 7, nn = rg & 127;
    float mean = rr ? mean1 : mean0;
    float inv  = rr ? inv1  : inv0;
    #pragma unroll
    for (int m = 0; m < 10; ++m){
      int col = tid + 256*m;
      float z = (y[rr][m]-mean)*inv*g[col] + be[col];
      z = fmaxf(z, 0.f);
      int k = col >> 7, hh2 = col & 127;
      out[((t*cKN) + k*cN + nn)*cH + hh2] = z;
    }
  }
}

// preconvert the 4 LSTM weight matrices [128][512] into fragment-ordered
// split-bf16 arrays (per mat: 65536 hi + 65536 lo ushorts,
// layout ((n*4+s)*64+l)*8+e with k = 32s + 16(e>>2) + 4g + (e&3), col=16n+(l&15)).
// Output overlays the dead mhp_W region (1.31 MB >= 1 MB). One-time, ~10us.
__global__ __launch_bounds__(256) void k_wprep(const float* w0, const float* w1,
    const float* w2, const float* w3, unsigned short* out){
  int idx = blockIdx.x*256 + threadIdx.x;   // 32768 total
  int m = idx >> 13;
  int rest = idx & 8191;
  int n = rest >> 8;
  int s = (rest >> 6) & 3;
  int l = rest & 63;
  int g = l >> 4, c16 = l & 15;
  const float* W = (m==0) ? w0 : ((m==1) ? w1 : ((m==2) ? w2 : w3));
  unsigned short hi[8], lo[8];
  #pragma unroll
  for (int e = 0; e < 8; ++e){
    int k = 32*s + 16*(e>>2) + 4*g + (e&3);
    float v = W[k*512 + 16*n + c16];
    hi[e] = f2h(v); lo[e] = f2h(v - hif(v));
  }
  size_t base = (size_t)m*131072 + (size_t)((n*4 + s)*64 + l)*8;
  *(uint4*)&out[base]         = *(const uint4*)hi;
  *(uint4*)&out[base + 65536] = *(const uint4*)lo;
}

// round-15: preconvert Wq/Wk/Wv/Wo1/Wo2 into the same fragment order
// (generalized N, KF). Outputs overlay dead f32 weight regions:
//  outA (l1Wih span, 262144 ushorts): Wq@0, Wk@32768, Wv@65536, Wo1@98304
//  outB (l2Wih span): Wo2@0.  Live biases l1b/l2b are NOT overwritten.
__global__ __launch_bounds__(256) void k_wprep2(const float* wq, const float* wk,
    const float* wv, const float* wo1, const float* wo2,
    unsigned short* outA, unsigned short* outB){
  int idx = blockIdx.x*256 + threadIdx.x;   // 14336 total
  if (idx >= 14336) return;
  const float* W; int KF, N, local, half; unsigned short* out; size_t off;
  if (idx < 2048)      { W=wq;  KF=4; N=128; off=0;      local=idx;       half=16384; out=outA; }
  else if (idx < 4096) { W=wk;  KF=4; N=128; off=32768;  local=idx-2048;  half=16384; out=outA; }
  else if (idx < 6144) { W=wv;  KF=4; N=128; off=65536;  local=idx-4096;  half=16384; out=outA; }
  else if (idx < 10240){ W=wo1; KF=4; N=256; off=98304;  local=idx-6144;  half=32768; out=outA; }
  else                 { W=wo2; KF=8; N=128; off=0;      local=idx-10240; half=32768; out=outB; }
  int l = local & 63;
  int rest = local >> 6;
  int s = rest & (KF-1);
  int n = (KF == 8) ? (rest >> 3) : (rest >> 2);
  int g = l >> 4, c16 = l & 15;
  unsigned short hi[8], lo[8];
  #pragma unroll
  for (int e = 0; e < 8; ++e){
    int k = 32*s + 16*(e>>2) + 4*g + (e&3);
    float v = W[k*N + 16*n + c16];
    hi[e] = f2h(v); lo[e] = f2h(v - hif(v));
  }
  size_t base = off + (size_t)local*8;
  *(uint4*)&out[base]        = *(const uint4*)hi;
  *(uint4*)&out[base + half] = *(const uint4*)lo;
}

// round-15: MFMA LSTM, de-spilled. R7/R8's deep register pipelines spilled
// (WRITE_SIZE 15.4 -> 22.4 -> 30.7 MB as live state grew; compiler pins 128
// VGPR). Revert to the R6 no-spill j-loop (depth-1 group prefetch) and keep
// only the zero-register-cost improvements: (1) single barrier/step via
// HF[2] double-buffer (16KB LDS); (2) t+1 x/soc prefetch issued pre-barrier
// (same liveness as R6's loop-tail prefetch); (3) s-major group order so
// consecutive 6-MFMA groups hit different accumulators.
__global__ __launch_bounds__(512) void k_lstm_mfma(const float* ge, float* outh,
    const float* hs0, const float* cn0, const float* soc,
    const unsigned short* wfA, const unsigned short* wfB,
    const float* bias, int phase){
  int r0 = blockIdx.x * 16;
  int tid = threadIdx.x;
  int w = tid >> 6, l = tid & 63;
  int g = l >> 4, c16 = l & 15;
  int scol = w*16 + c16;                 // state col owned by this lane
  __shared__ unsigned short HFh[2][4][64][8], HFl[2][4][64][8];   // 16 KB
  // producer slot constants: scol -> (s, gf, e); lane writes rows 4g+r
  int ps = scol >> 5, prem = scol & 31;
  int pgf = (prem >> 2) & 3;
  int pe  = ((prem >> 4) << 2) + (prem & 3);
  float c[4], h[4];
  #pragma unroll
  for (int r = 0; r < 4; ++r){
    int nn = (r0 + 4*g + r) & 127;
    c[r] = cn0[nn*cH + scol];
    h[r] = hs0[nn*cH + scol];
  }
  float bias_t[4];
  #pragma unroll
  for (int tt = 0; tt < 4; ++tt) bias_t[tt] = bias[tt*128 + scol];

  // prefetch x (and soc) for t=0
  f32x4 xr[8];
  float socr[4] = {0.f, 0.f, 0.f, 0.f};
  {
    const f32x4* gp = (const f32x4*)ge + ((size_t)(r0 + c16))*32;
    #pragma unroll
    for (int s = 0; s < 4; ++s){ xr[2*s] = gp[8*s + g]; xr[2*s+1] = gp[8*s + 4 + g]; }
    if (phase == 2){
      #pragma unroll
      for (int r = 0; r < 4; ++r)
        socr[r] = soc[(size_t)(r0 + 4*g + r)*cH + scol];
    }
  }

  for (int t = 0; t < cT; ++t){
    int b = t & 1;
    if (phase == 2){
      #pragma unroll
      for (int r = 0; r < 4; ++r){
        c[r] += socr[r];
        h[r] += tanhf(c[r]);
      }
    }
    // h fragments into HF[b]
    #pragma unroll
    for (int r = 0; r < 4; ++r){
      HFh[b][ps][pgf*16 + 4*g + r][pe] = f2h(h[r]);
      HFl[b][ps][pgf*16 + 4*g + r][pe] = f2h(h[r] - hif(h[r]));
    }
    // convert x(t) -> frags (xr then free for t+1 prefetch)
    bf16x8 xh[4], xl[4];
    #pragma unroll
    for (int s = 0; s < 4; ++s){
      union { unsigned short u[8]; bf16x8 v; } uh, ul;
      #pragma unroll
      for (int m2 = 0; m2 < 4; ++m2){
        float a0 = xr[2*s][m2], b0 = xr[2*s+1][m2];
        uh.u[m2]   = f2h(a0); ul.u[m2]   = f2h(a0 - hif(a0));
        uh.u[4+m2] = f2h(b0); ul.u[4+m2] = f2h(b0 - hif(b0));
      }
      xh[s] = uh.v; xl[s] = ul.v;
    }
    // t+1 x/soc prefetch issued pre-barrier (drain absorbs latency)
    if (t < cT-1){
      const f32x4* gp = (const f32x4*)ge + ((size_t)(t+1)*cKN + r0 + c16)*32;
      #pragma unroll
      for (int s = 0; s < 4; ++s){ xr[2*s] = gp[8*s + g]; xr[2*s+1] = gp[8*s + 4 + g]; }
      if (phase == 2){
        #pragma unroll
        for (int r = 0; r < 4; ++r)
          socr[r] = soc[(size_t)(t+1)*cKN*cH + (size_t)(r0 + 4*g + r)*cH + scol];
      }
    }
    __syncthreads();                      // HF[b] visible (single barrier/step)
    bf16x8 hh[4], hl[4];
    #pragma unroll
    for (int s = 0; s < 4; ++s){
      hh[s] = *(const bf16x8*)&HFh[b][s][l][0];
      hl[s] = *(const bf16x8*)&HFl[b][s][l][0];
    }
    f32x4 a4[4];
    #pragma unroll
    for (int tt = 0; tt < 4; ++tt){
      f32x4 acc = {bias_t[tt], bias_t[tt], bias_t[tt], bias_t[tt]};
      a4[tt] = acc;
    }
    // 16 groups, s-major (j: s=j>>2, tt=j&3), depth-1 prefetch (R6 register budget)
    {
      bf16x8 cAh, cAl, cBh, cBl, nAh, nAl, nBh, nBl;
      {
        size_t fo = (size_t)((w*4 + 0)*64 + l)*8;   // tt=0, s=0
        cAh = *(const bf16x8*)&wfA[fo];
        cAl = *(const bf16x8*)&wfA[65536 + fo];
        cBh = *(const bf16x8*)&wfB[fo];
        cBl = *(const bf16x8*)&wfB[65536 + fo];
      }
      #pragma unroll
      for (int j = 0; j < 16; ++j){
        int s = j >> 2, tt = j & 3;
        if (j < 15){
          int j2 = j + 1;
          int s2 = j2 >> 2, tt2 = j2 & 3;
          size_t fo = (size_t)(((w + 8*tt2)*4 + s2)*64 + l)*8;
          nAh = *(const bf16x8*)&wfA[fo];
          nAl = *(const bf16x8*)&wfA[65536 + fo];
          nBh = *(const bf16x8*)&wfB[fo];
          nBl = *(const bf16x8*)&wfB[65536 + fo];
        }
        f32x4 acc = a4[tt];
        acc = __builtin_amdgcn_mfma_f32_16x16x32_bf16(xl[s], cAh, acc, 0, 0, 0);
        acc = __builtin_amdgcn_mfma_f32_16x16x32_bf16(xh[s], cAl, acc, 0, 0, 0);
        acc = __builtin_amdgcn_mfma_f32_16x16x32_bf16(xh[s], cAh, acc, 0, 0, 0);
        acc = __builtin_amdgcn_mfma_f32_16x16x32_bf16(hl[s], cBh, acc, 0, 0, 0);
        acc = __builtin_amdgcn_mfma_f32_16x16x32_bf16(hh[s], cBl, acc, 0, 0, 0);
        acc = __builtin_amdgcn_mfma_f32_16x16x32_bf16(hh[s], cBh, acc, 0, 0, 0);
        a4[tt] = acc;
        cAh = nAh; cAl = nAl; cBh = nBh; cBl = nBl;
      }
    }
    // gates + state update + output store
    #pragma unroll
    for (int r = 0; r < 4; ++r){
      float ig = sigm(a4[0][r]), fg = sigm(a4[1][r]);
      float gg = tanhf(a4[2][r]), og = sigm(a4[3][r]);
      c[r] = fg*c[r] + ig*gg;
      h[r] = og*tanhf(c[r]);
      outh[(size_t)t*cKN*cH + (size_t)(r0 + 4*g + r)*cH + scol] = h[r];
    }
    // no end barrier: HF double-buffered (next step writes HF[b^1]; a wave
    // can only overwrite HF[b] at t+2 after passing barrier(t+1), which all
    // waves reach only after finishing their HF[b] reads at step t).
  }
}

// round-15: generic MFMA GEMM (clone of the validated lstm pattern).
// block = 16 rows, 4 independent waves (no LDS/barriers); wave wv owns
// n-tiles {wv, wv+4, ...}. x frags per-lane from global; weight frags
// preconverted (k_wprep2). Split-bf16 3-mfma products.
template<int KF>
__global__ __launch_bounds__(256) void k_gemm(const float* x, const unsigned short* wf,
    const float* bias, float* out, int NT, int N, int relu, int half){
  int r0 = blockIdx.x * 16;
  int tid = threadIdx.x;
  int wv = tid >> 6, l = tid & 63;
  int g = l >> 4, c16 = l & 15;
  bf16x8 xh[KF], xl[KF];
  const f32x4* gp = (const f32x4*)x + (size_t)(r0 + c16)*(KF*8);
  #pragma unroll
  for (int s = 0; s < KF; ++s){
    f32x4 qa = gp[8*s + g], qb = gp[8*s + 4 + g];
    union { unsigned short u[8]; bf16x8 v; } uh, ul;
    #pragma unroll
    for (int m2 = 0; m2 < 4; ++m2){
      float a0 = qa[m2], b0 = qb[m2];
      uh.u[m2]   = f2h(a0); ul.u[m2]   = f2h(a0 - hif(a0));
      uh.u[4+m2] = f2h(b0); ul.u[4+m2] = f2h(b0 - hif(b0));
    }
    xh[s] = uh.v; xl[s] = ul.v;
  }
  for (int nt = wv; nt < NT; nt += 4){
    float bb = bias[nt*16 + c16];
    f32x4 acc = {bb, bb, bb, bb};
    #pragma unroll
    for (int s = 0; s < KF; ++s){
      const unsigned short* fb = wf + (size_t)((nt*KF + s)*64 + l)*8;
      bf16x8 Wh = *(const bf16x8*)fb;
      bf16x8 Wl = *(const bf16x8*)(fb + half);
      acc = __builtin_amdgcn_mfma_f32_16x16x32_bf16(xl[s], Wh, acc, 0, 0, 0);
      acc = __builtin_amdgcn_mfma_f32_16x16x32_bf16(xh[s], Wl, acc, 0, 0, 0);
      acc = __builtin_amdgcn_mfma_f32_16x16x32_bf16(xh[s], Wh, acc, 0, 0, 0);
    }
    if (relu){
      #pragma unroll
      for (int r = 0; r < 4; ++r) acc[r] = fmaxf(acc[r], 0.f);
    }
    #pragma unroll
    for (int r = 0; r < 4; ++r)
      out[(size_t)(r0 + 4*g + r)*N + nt*16 + c16] = acc[r];
  }
}

// round-15: fused QKV MFMA GEMM (NT=24: tiles 0-7 Q, 8-15 K, 16-23 V).
__global__ __launch_bounds__(256) void k_gemm3(const float* x, const unsigned short* wf,
    const float* bq, const float* bk, const float* bv,
    float* Q, float* K2, float* V){
  int r0 = blockIdx.x * 16;
  int tid = threadIdx.x;
  int wv = tid >> 6, l = tid & 63;
  int g = l >> 4, c16 = l & 15;
  bf16x8 xh[4], xl[4];
  const f32x4* gp = (const f32x4*)x + (size_t)(r0 + c16)*32;
  #pragma unroll
  for (int s = 0; s < 4; ++s){
    f32x4 qa = gp[8*s + g], qb = gp[8*s + 4 + g];
    union { unsigned short u[8]; bf16x8 v; } uh, ul;
    #pragma unroll
    for (int m2 = 0; m2 < 4; ++m2){
      float a0 = qa[m2], b0 = qb[m2];
      uh.u[m2]   = f2h(a0); ul.u[m2]   = f2h(a0 - hif(a0));
      uh.u[4+m2] = f2h(b0); ul.u[4+m2] = f2h(b0 - hif(b0));
    }
    xh[s] = uh.v; xl[s] = ul.v;
  }
  for (int nt = wv; nt < 24; nt += 4){
    int m = nt >> 3, n = nt & 7;
    const float* bias = (m==0) ? bq : ((m==1) ? bk : bv);
    float* out = (m==0) ? Q : ((m==1) ? K2 : V);
    float bb = bias[n*16 + c16];
    f32x4 acc = {bb, bb, bb, bb};
    const unsigned short* base = wf + (size_t)m*32768;
    #pragma unroll
    for (int s = 0; s < 4; ++s){
      const unsigned short* fb = base + (size_t)((n*4 + s)*64 + l)*8;
      bf16x8 Wh = *(const bf16x8*)fb;
      bf16x8 Wl = *(const bf16x8*)(fb + 16384);
      acc = __builtin_amdgcn_mfma_f32_16x16x32_bf16(xl[s], Wh, acc, 0, 0, 0);
      acc = __builtin_amdgcn_mfma_f32_16x16x32_bf16(xh[s], Wl, acc, 0, 0, 0);
      acc = __builtin_amdgcn_mfma_f32_16x16x32_bf16(xh[s], Wh, acc, 0, 0, 0);
    }
    #pragma unroll
    for (int r = 0; r < 4; ++r)
      out[(size_t)(r0 + 4*g + r)*cH + n*16 + c16] = acc[r];
  }
}

// loc & scale heads, wave-local: wave = (head, row-pair), shfl reductions, no trees.
__global__ __launch_bounds__(256) void k_heads(const float* x,
  const float* lW1, const float* lb1, const float* lg, const float* lbe, const float* lW2, const float* lb2v,
  const float* sW1, const float* sb1, const float* sg, const float* sbe, const float* sW2, const float* sb2v,
  void* outv, int q0, float* locsc, const float* maxv, const float* svp, const int* flagp){
  const int ROWS = 4;
  int r0 = blockIdx.x*ROWS;
  __shared__ float xs[ROWS][cH];
  int tid = threadIdx.x;
  if (tid < ROWS*32){
    int rr = tid>>5, u4 = tid&31;
    ((float4*)&xs[rr][0])[u4] = ((const float4*)x)[(size_t)(r0+rr)*32 + u4];
  }
  __syncthreads();
  int wv = tid >> 6, lane = tid & 63;
  int head = wv & 1;
  int ra = (wv >> 1)*2, rb = ra + 1;     // local rows
  const float* W1 = head ? sW1 : lW1;
  const float* b1 = head ? sb1 : lb1;
  const float* gv = head ? sg  : lg;
  const float* be = head ? sbe : lbe;
  const float* W2 = head ? sW2 : lW2;
  const float* b2 = head ? sb2v: lb2v;
  int j0 = lane, j1 = lane + 64;
  float a00 = b1[j0], a01 = b1[j1];
  float a10 = a00, a11 = a01;
  for (int i = 0; i < cH; ++i){
    float w0 = W1[i*cH + j0], w1 = W1[i*cH + j1];
    float xa = xs[ra][i], xb = xs[rb][i];
    a00 += xa*w0; a01 += xa*w1;
    a10 += xb*w0; a11 += xb*w1;
  }
  float s0 = a00 + a01, s1 = a10 + a11;
  #pragma unroll
  for (int off = 1; off < 64; off <<= 1){
    s0 += __shfl_xor(s0, off);
    s1 += __shfl_xor(s1, off);
  }
  float mean0 = s0*(1.f/128.f), mean1 = s1*(1.f/128.f);
  float d00 = a00-mean0, d01 = a01-mean0, d10 = a10-mean1, d11 = a11-mean1;
  float v0 = d00*d00 + d01*d01, v1 = d10*d10 + d11*d11;
  #pragma unroll
  for (int off = 1; off < 64; off <<= 1){
    v0 += __shfl_xor(v0, off);
    v1 += __shfl_xor(v1, off);
  }
  float inv0 = rsqrtf(v0*(1.f/128.f) + 1e-5f);
  float inv1 = rsqrtf(v1*(1.f/128.f) + 1e-5f);
  float g0 = gv[j0], g1 = gv[j1], be0 = be[j0], be1 = be[j1];
  float z00 = fmaxf(d00*inv0*g0 + be0, 0.f);
  float z01 = fmaxf(d01*inv0*g1 + be1, 0.f);
  float z10 = fmaxf(d10*inv1*g0 + be0, 0.f);
  float z11 = fmaxf(d11*inv1*g1 + be1, 0.f);
  float w2a0 = W2[j0*2+0], w2a1 = W2[j0*2+1];
  float w2b0 = W2[j1*2+0], w2b1 = W2[j1*2+1];
  float oa0 = z00*w2a0 + z01*w2b0;   // row ra, out 0
  float oa1 = z00*w2a1 + z01*w2b1;   // row ra, out 1
  float ob0 = z10*w2a0 + z11*w2b0;
  float ob1 = z10*w2a1 + z11*w2b1;
  #pragma unroll
  for (int off = 1; off < 64; off <<= 1){
    oa0 += __shfl_xor(oa0, off);
    oa1 += __shfl_xor(oa1, off);
    ob0 += __shfl_xor(ob0, off);
    ob1 += __shfl_xor(ob1, off);
  }
  if (lane == 0){
    int flag = *flagp;
    float bias0 = b2[0], bias1 = b2[1];
    float ro[2][2] = {{oa0 + bias0, oa1 + bias1},{ob0 + bias0, ob1 + bias1}};
    int lr[2] = {ra, rb};
    for (int e = 0; e < 2; ++e){
      int rg = r0 + lr[e];
      int t = rg / cKN, rem = rg - t*cKN;
      int k = rem >> 7, nn = rem & 127;
      float u0 = ro[e][0], u1 = ro[e][1];
      if (head == 0){
        size_t oi = (((size_t)q0*cK + k)*cN + nn)*(cT*2) + t*2;
        if (flag){ ((bf16_t*)outv)[oi] = __float2bfloat16(u0); ((bf16_t*)outv)[oi+1] = __float2bfloat16(u1); }
        else     { ((float*)outv)[oi] = u0; ((float*)outv)[oi+1] = u1; }
        if (locsc){
          locsc[((size_t)t*cKN + rem)*2 + 0] = u0*maxv[nn*2+0] + svp[nn*2+0];
          locsc[((size_t)t*cKN + rem)*2 + 1] = u1*maxv[nn*2+1] + svp[nn*2+1];
        }
      } else {
        float e0 = (u0 > 0.f ? u0 : expm1f(u0)) + 1.001f;
        float e1 = (u1 > 0.f ? u1 : expm1f(u1)) + 1.001f;
        size_t oi = (((size_t)(q0+1)*cK + k)*cN + nn)*(cT*2) + t*2;
        if (flag){ ((bf16_t*)outv)[oi] = __float2bfloat16(e0); ((bf16_t*)outv)[oi+1] = __float2bfloat16(e1); }
        else     { ((float*)outv)[oi] = e0; ((float*)outv)[oi+1] = e1; }
      }
    }
  }
}

__global__ __launch_bounds__(256) void k_mask(const float* locsc, unsigned char* m){
  int st = blockIdx.x;
  int s = st / cT, t = st - s*cT;
  __shared__ float lx[cK][cNS], ly[cK][cNS];
  int tid = threadIdx.x;
  for (int p = tid; p < cK*cNS; p += 256){
    int k = p >> 5, i = p & 31;
    int row = t*cKN + k*cN + s*cNS + i;
    lx[k][i] = locsc[row*2+0];
    ly[k][i] = locsc[row*2+1];
  }
  __syncthreads();
  for (int p = tid; p < 1024; p += 256){
    int i = p >> 5, j = p & 31;
    bool any = false;
    for (int k = 0; k < cK; ++k){
      float dx = fabsf(lx[k][i]-lx[k][j]);
      float dy = fabsf(ly[k][i]-ly[k][j]);
      any = any || ((dx < 10.f) && (dy < 10.f));
    }
    m[st*1024 + p] = any ? 1 : 0;
  }
}

// round-10: MFMA attention (validated). Split-bf16 3-mfma products; QK^T =
// mfma(A=K, B=Q) with k-map k=16(e>>2)+4g+(e&3); PV A-frag = lane's own
// S-accumulator. No-max softmax. K/V staged to LDS in fragment order.
__global__ __launch_bounds__(256) void k_attn(const float* Q, const float* Kx, const float* V,
                       const unsigned char* msk, float* ctx){
  int qs   = blockIdx.x;        // 0..4 : group of 8 q-tiles (2 per wave)
  int head = blockIdx.y;        // 0..3
  int st   = blockIdx.z;        // s*cT + t
  int s = st / cT, t = st - s*cT;
  __shared__ unsigned short KLh[2][1024], KLl[2][1024], VLh[2][1024], VLl[2][1024]; // 16 KB
  int tid = threadIdx.x;
  int w = tid >> 6, lane = tid & 63;
  int g = lane >> 4, col = lane & 15;
  const float scl = 0.17677669529663687f;   // 1/sqrt(32)

  // mask rows (q_agent = col, col+16) packed to 32-bit words (byte->bit)
  unsigned int mw0 = 0, mw1 = 0;
  {
    const unsigned int* mr0 = (const unsigned int*)(msk + st*1024 + col*32);
    const unsigned int* mr1 = (const unsigned int*)(msk + st*1024 + (16+col)*32);
    #pragma unroll
    for (int j2 = 0; j2 < 8; ++j2){
      mw0 |= (((mr0[j2] * 0x01020408u) >> 24) & 0xFu) << (4*j2);
      mw1 |= (((mr1[j2] * 0x01020408u) >> 24) & 0xFu) << (4*j2);
    }
  }

  // Q fragments (pre-scaled by scl), 2 tiles per wave; B col = lane&15
  bf16x8 Qh[2], Ql[2];
  int modes[2], ahs[2];
  #pragma unroll
  for (int i = 0; i < 2; ++i){
    int tt = qs*8 + 4*i + w;       // 0..39
    int mode = tt >> 1, ah = tt & 1;
    modes[i] = mode; ahs[i] = ah;
    int qrow = t*cKN + mode*cN + s*cNS + ah*16 + col;
    const f32x4* qp = (const f32x4*)Q + (size_t)qrow*32 + head*8;
    f32x4 qa = qp[g], qb = qp[4+g];     // dims 4g..4g+3, 16+4g..16+4g+3
    union { unsigned short u[8]; bf16x8 v; } uh, ul;
    #pragma unroll
    for (int m = 0; m < 4; ++m){
      float x0 = qa[m]*scl;
      uh.u[m] = f2h(x0);
      ul.u[m] = f2h(x0 - hif(x0));
      float x1 = qb[m]*scl;
      uh.u[4+m] = f2h(x1);
      ul.u[4+m] = f2h(x1 - hif(x1));
    }
    Qh[i] = uh.v; Ql[i] = ul.v;
  }

  // staging indices
  int kk = tid >> 3, f4 = tid & 7;                 // K: key kk, dims 4*f4..+3
  int kwi = (((kk>>4)*4 + (f4&3))*16 + (kk&15))*8 + (f4>>2)*4;
  int vd = tid & 31, quad = tid >> 5;              // V: dim vd, keys base..+3
  int vkey = (quad>>2)*16 + (quad&3)*4;
  int vwi = (((vd>>4)*4 + (quad&3))*16 + (vd&15))*8 + (quad>>2)*4;

  const size_t cstepK = (size_t)cN*32;             // float4 per chunk (one mode)
  const size_t cstepV = (size_t)cN*128;            // float per chunk
  const float4* kptr = (const float4*)Kx + ((size_t)(t*cKN + s*cNS + kk))*32 + head*8 + f4;
  const float*  vptr = V + ((size_t)(t*cKN + s*cNS + vkey))*128 + head*32 + vd;

  float4 kv; float vm0, vm1, vm2, vm3;
  kv = *kptr; kptr += cstepK;
  vm0 = vptr[0]; vm1 = vptr[128]; vm2 = vptr[256]; vm3 = vptr[384]; vptr += cstepV;
  {
    unsigned int h0 = (unsigned int)f2h(kv.x) | ((unsigned int)f2h(kv.y)<<16);
    unsigned int h1 = (unsigned int)f2h(kv.z) | ((unsigned int)f2h(kv.w)<<16);
    float r0 = kv.x-hif(kv.x), r1 = kv.y-hif(kv.y), r2 = kv.z-hif(kv.z), r3 = kv.w-hif(kv.w);
    unsigned int l0 = (unsigned int)f2h(r0) | ((unsigned int)f2h(r1)<<16);
    unsigned int l1 = (unsigned int)f2h(r2) | ((unsigned int)f2h(r3)<<16);
    *(uint2*)&KLh[0][kwi] = make_uint2(h0,h1);
    *(uint2*)&KLl[0][kwi] = make_uint2(l0,l1);
    unsigned int vh0 = (unsigned int)f2h(vm0) | ((unsigned int)f2h(vm1)<<16);
    unsigned int vh1 = (unsigned int)f2h(vm2) | ((unsigned int)f2h(vm3)<<16);
    float s0 = vm0-hif(vm0), s1 = vm1-hif(vm1), s2 = vm2-hif(vm2), s3 = vm3-hif(vm3);
    unsigned int vl0 = (unsigned int)f2h(s0) | ((unsigned int)f2h(s1)<<16);
    unsigned int vl1 = (unsigned int)f2h(s2) | ((unsigned int)f2h(s3)<<16);
    *(uint2*)&VLh[0][vwi] = make_uint2(vh0,vh1);
    *(uint2*)&VLl[0][vwi] = make_uint2(vl0,vl1);
  }
  __syncthreads();

  const f32x4 Z = {0.f, 0.f, 0.f, 0.f};
  f32x4 O[2][2] = {{Z, Z}, {Z, Z}};
  float lac[2] = {0.f, 0.f};

  for (int ch = 0; ch < 20; ++ch){
    int par = ch & 1;
    if (ch < 19){
      kv = *kptr; kptr += cstepK;
      vm0 = vptr[0]; vm1 = vptr[128]; vm2 = vptr[256]; vm3 = vptr[384]; vptr += cstepV;
    }
    // fragment reads (shared across this wave's tiles)
    bf16x8 KAh0 = *(const bf16x8*)&KLh[par][( g      *16 + col)*8];
    bf16x8 KAl0 = *(const bf16x8*)&KLl[par][( g      *16 + col)*8];
    bf16x8 KAh1 = *(const bf16x8*)&KLh[par][((4 + g) *16 + col)*8];
    bf16x8 KAl1 = *(const bf16x8*)&KLl[par][((4 + g) *16 + col)*8];
    bf16x8 VBh0 = *(const bf16x8*)&VLh[par][( g      *16 + col)*8];
    bf16x8 VBl0 = *(const bf16x8*)&VLl[par][( g      *16 + col)*8];
    bf16x8 VBh1 = *(const bf16x8*)&VLh[par][((4 + g) *16 + col)*8];
    bf16x8 VBl1 = *(const bf16x8*)&VLl[par][((4 + g) *16 + col)*8];
    #pragma unroll
    for (int i = 0; i < 2; ++i){
      f32x4 sa = Z, sb = Z;
      sa = __builtin_amdgcn_mfma_f32_16x16x32_bf16(KAl0, Qh[i], sa, 0, 0, 0);
      sa = __builtin_amdgcn_mfma_f32_16x16x32_bf16(KAh0, Ql[i], sa, 0, 0, 0);
      sa = __builtin_amdgcn_mfma_f32_16x16x32_bf16(KAh0, Qh[i], sa, 0, 0, 0);
      sb = __builtin_amdgcn_mfma_f32_16x16x32_bf16(KAl1, Qh[i], sb, 0, 0, 0);
      sb = __builtin_amdgcn_mfma_f32_16x16x32_bf16(KAh1, Ql[i], sb, 0, 0, 0);
      sb = __builtin_amdgcn_mfma_f32_16x16x32_bf16(KAh1, Qh[i], sb, 0, 0, 0);
      unsigned int mw = ahs[i] ? mw1 : mw0;
      float p[8];
      #pragma unroll
      for (int r = 0; r < 4; ++r){
        float e0 = __expf(sa[r]);
        float e1 = __expf(sb[r]);
        p[r]   = ((mw >> (4*g + r)) & 1)        ? e0 : 0.f;
        p[4+r] = ((mw >> (16 + 4*g + r)) & 1)   ? e1 : 0.f;
      }
      lac[i] += ((p[0]+p[1])+(p[2]+p[3])) + ((p[4]+p[5])+(p[6]+p[7]));
      union { unsigned short u[8]; bf16x8 v; } Ph, Pl;
      #pragma unroll
      for (int e = 0; e < 8; ++e){
        Ph.u[e] = f2h(p[e]);
        Pl.u[e] = f2h(p[e] - hif(p[e]));
      }
      O[i][0] = __builtin_amdgcn_mfma_f32_16x16x32_bf16(Pl.v, VBh0, O[i][0], 0, 0, 0);
      O[i][0] = __builtin_amdgcn_mfma_f32_16x16x32_bf16(Ph.v, VBl0, O[i][0], 0, 0, 0);
      O[i][0] = __builtin_amdgcn_mfma_f32_16x16x32_bf16(Ph.v, VBh0, O[i][0], 0, 0, 0);
      O[i][1] = __builtin_amdgcn_mfma_f32_16x16x32_bf16(Pl.v, VBh1, O[i][1], 0, 0, 0);
      O[i][1] = __builtin_amdgcn_mfma_f32_16x16x32_bf16(Ph.v, VBl1, O[i][1], 0, 0, 0);
      O[i][1] = __builtin_amdgcn_mfma_f32_16x16x32_bf16(Ph.v, VBh1, O[i][1], 0, 0, 0);
    }
    __syncthreads();   // all frag reads of [par] done
    if (ch < 19){
      int nb = 1 - par;
      unsigned int h0 = (unsigned int)f2h(kv.x) | ((unsigned int)f2h(kv.y)<<16);
      unsigned int h1 = (unsigned int)f2h(kv.z) | ((unsigned int)f2h(kv.w)<<16);
      float r0 = kv.x-hif(kv.x), r1 = kv.y-hif(kv.y), r2 = kv.z-hif(kv.z), r3 = kv.w-hif(kv.w);
      unsigned int l0 = (unsigned int)f2h(r0) | ((unsigned int)f2h(r1)<<16);
      unsigned int l1 = (unsigned int)f2h(r2) | ((unsigned int)f2h(r3)<<16);
      *(uint2*)&KLh[nb][kwi] = make_uint2(h0,h1);
      *(uint2*)&KLl[nb][kwi] = make_uint2(l0,l1);
      unsigned int vh0 = (unsigned int)f2h(vm0) | ((unsigned int)f2h(vm1)<<16);
      unsigned int vh1 = (unsigned int)f2h(vm2) | ((unsigned int)f2h(vm3)<<16);
      float s0 = vm0-hif(vm0), s1 = vm1-hif(vm1), s2 = vm2-hif(vm2), s3 = vm3-hif(vm3);
      unsigned int vl0 = (unsigned int)f2h(s0) | ((unsigned int)f2h(s1)<<16);
      unsigned int vl1 = (unsigned int)f2h(s2) | ((unsigned int)f2h(s3)<<16);
      *(uint2*)&VLh[nb][vwi] = make_uint2(vh0,vh1);
      *(uint2*)&VLl[nb][vwi] = make_uint2(vl0,vl1);
    }
    __syncthreads();   // next buffer visible
  }

  // epilogue: row denominators + normalized writes
  #pragma unroll
  for (int i = 0; i < 2; ++i){
    float lsum = lac[i];
    lsum += __shfl_xor(lsum, 16);
    lsum += __shfl_xor(lsum, 32);
    int base = t*cKN + modes[i]*cN + s*cNS + ahs[i]*16;
    #pragma unroll
    for (int r = 0; r < 4; ++r){
      float lq = __shfl(lsum, 4*g + r);
      float rinv = 1.f / lq;
      float* cp = ctx + (size_t)(base + 4*g + r)*cH + head*cHD;
      cp[col]      = O[i][0][r] * rinv;
      cp[col+16]   = O[i][1][r] * rinv;
    }
  }
}

extern "C" void kernel_launch(void* const* d_in, const int* in_sizes, int n_in,
                              void* d_out, int out_size, void* d_ws, size_t ws_size,
                              hipStream_t stream){
  (void)in_sizes; (void)n_in; (void)out_size; (void)ws_size;

  int*   flagp = (int*)d_ws;
  float* conv  = (float*)d_ws + 64;
  float* big   = (float*)d_ws + 978112;

  const float* ge_f   = conv + 0;
  const float* hs_f   = conv + 196608;
  const float* cn_f   = conv + 212992;
  const float* sv_f   = conv + 229376;
  const float* mx_f   = conv + 229632;
  const float* mhpW_f = conv + 229888;
  const float* mhpb_f = conv + 557568;
  const float* mhpg_f = conv + 560128;
  const float* mhpbe_f= conv + 562688;
  const float* l1Wih_f= conv + 565248;
  const float* l1Whh_f= conv + 630784;
  const float* l1b_f  = conv + 696320;
  const float* l2Wih_f= conv + 696832;
  const float* l2Whh_f= conv + 762368;
  const float* l2b_f  = conv + 827904;
  const float* Wq_f   = conv + 828416;
  const float* bq_f   = conv + 844800;
  const float* Wk_f   = conv + 844928;
  const float* bk_f   = conv + 861312;
  const float* Wv_f   = conv + 861440;
  const float* bv_f   = conv + 877824;
  const float* Wo1_f  = conv + 877952;
  const float* bo1_f  = conv + 910720;
  const float* Wo2_f  = conv + 910976;
  const float* bo2_f  = conv + 943744;
  const float* locW1_f= conv + 943872;
  const float* locb1_f= conv + 960256;
  const float* locg_f = conv + 960384;
  const float* locbe_f= conv + 960512;
  const float* locW2_f= conv + 960640;
  const float* locb2_f= conv + 960896;
  const float* sclW1_f= conv + 960960;
  const float* sclb1_f= conv + 977344;
  const float* sclg_f = conv + 977472;
  const float* sclbe_f= conv + 977600;
  const float* sclW2_f= conv + 977728;
  const float* sclb2_f= conv + 977984;

  const size_t SLOT = (size_t)cT*cKN*cH;
  float* geb = big;
  float* o1b = big + SLOT;
  float* Qb  = big + 2*SLOT;
  float* Kb  = big + 3*SLOT;
  float* Vb  = big + 4*SLOT;
  float* locsc = big + 5*SLOT;
  unsigned char* maskb = (unsigned char*)(locsc + (size_t)cT*cKN*2);
  float* t1 = Qb;        // spans slots 2-3 (Q/K dead after attn)
  float* social = Vb;    // overlays V after attention

  // LSTM weight fragments overlay the mhp_W region (dead after k_mhp)
  unsigned short* wfrag = (unsigned short*)(conv + 229888);
  // QKV/Wo fragments overlay dead f32 weight regions (biases preserved):
  //  uA = l1Wih..l1Whh span: Wq@0, Wk@32768, Wv@65536, Wo1@98304 (229376 ushorts < 262144)
  //  uB = l2Wih span: Wo2@0 (131072 ushorts = exactly the l2Wih span)
  unsigned short* uA = (unsigned short*)(conv + 565248);
  unsigned short* uB = (unsigned short*)(conv + 696832);

  Ptrs ptrs;
  for (int i = 0; i < 37; ++i) ptrs.p[i] = d_in[i];

  k_detect<<<1, 64, 0, stream>>>((const unsigned short*)d_in[0], flagp, (unsigned int*)d_out);
  k_convert<<<(CONV_TOTAL+255)/256, 256, 0, stream>>>(ptrs, flagp, conv);
  k_mhp<<<cT*cN/2, 256, 0, stream>>>(ge_f, mhpW_f, mhpb_f, mhpg_f, mhpbe_f, geb);
  k_wprep<<<128, 256, 0, stream>>>(l1Wih_f, l1Whh_f, l2Wih_f, l2Whh_f, wfrag);
  k_wprep2<<<56, 256, 0, stream>>>(Wq_f, Wk_f, Wv_f, Wo1_f, Wo2_f, uA, uB);
  k_lstm_mfma<<<160, 512, 0, stream>>>(geb, o1b, hs_f, cn_f, (const float*)0,
                                       wfrag + 0, wfrag + 131072, l1b_f, 1);
  k_heads<<<cT*cKN/4, 256, 0, stream>>>(o1b, locW1_f,locb1_f,locg_f,locbe_f,locW2_f,locb2_f,
                                        sclW1_f,sclb1_f,sclg_f,sclbe_f,sclW2_f,sclb2_f,
                                        d_out, 0, locsc, mx_f, sv_f, flagp);
  k_mask<<<cS*cT, 256, 0, stream>>>(locsc, maskb);
  k_gemm3<<<cT*cKN/16, 256, 0, stream>>>(o1b, uA, bq_f, bk_f, bv_f, Qb, Kb, Vb);
  {
    dim3 ag(5, 4, cS*cT);
    k_attn<<<ag, 256, 0, stream>>>(Qb, Kb, Vb, maskb, o1b);   // ctx overlays out1
  }
  k_gemm<4><<<cT*cKN/16, 256, 0, stream>>>(o1b, uA + 98304, bo1_f, t1, 16, 256, 1, 32768);
  k_gemm<8><<<cT*cKN/16, 256, 0, stream>>>(t1, uB, bo2_f, social, 8, 128, 0, 32768);
  k_lstm_mfma<<<160, 512, 0, stream>>>(geb, o1b, hs_f, cn_f, social,
                                       wfrag + 262144, wfrag + 393216, l2b_f, 2);
  k_heads<<<cT*cKN/4, 256, 0, stream>>>(o1b, locW1_f,locb1_f,locg_f,locbe_f,locW2_f,locb2_f,
                                        sclW1_f,sclb1_f,sclg_f,sclbe_f,sclW2_f,sclb2_f,
                                        d_out, 2, (float*)0, mx_f, sv_f, flagp);
}

// Round 10
// 632.872 us; speedup vs baseline: 1.2306x; 1.0279x over previous
//
#include <hip/hip_runtime.h>
#include <hip/hip_bf16.h>

typedef __hip_bfloat16 bf16_t;

static const int cT  = 12;    // future steps
static const int cN  = 128;   // agents
static const int cH  = 128;   // hidden
static const int cK  = 20;    // modes
static const int cKN = 2560;  // cK*cN
static const int cS  = 4;     // batch split
static const int cNS = 32;    // agents per scene
static const int cL  = 640;   // cK*cNS attention length
static const int cHD = 32;    // head dim

#define CONV_TOTAL 977986

__constant__ int c_off[38] = {0,196608,212992,229376,229632,229888,557568,560128,562688,
  565248,630784,696320,696832,762368,827904,828416,844800,844928,861312,861440,877824,
  877952,910720,910976,943744,943872,960256,960384,960512,960640,960896,960960,977344,
  977472,977600,977728,977984,977986};
__constant__ int c_len[37] = {196608,16384,16384,256,256,327680,2560,2560,2560,
  65536,65536,512,65536,65536,512,16384,128,16384,128,16384,128,
  32768,256,32768,128,16384,128,128,128,256,2,16384,128,128,128,256,2};

struct Ptrs { const void* p[37]; };

typedef __attribute__((ext_vector_type(4))) float f32x4;
typedef __attribute__((ext_vector_type(8))) __bf16 bf16x8;

__device__ __forceinline__ float sigm(float x){ return 1.f/(1.f+expf(-x)); }
__device__ __forceinline__ unsigned short f2h(float x){ return (unsigned short)(__float_as_uint(x)>>16); }
__device__ __forceinline__ float hif(float x){ return __uint_as_float(__float_as_uint(x)&0xFFFF0000u); }

// dtype sniffing + NaN canary
__global__ __launch_bounds__(256) void k_detect(const unsigned short* ge_u16, int* flagp, unsigned int* outw){
  __shared__ int cnt;
  if (threadIdx.x == 0) cnt = 0;
  __syncthreads();
  int ok = 0;
  for (int i = threadIdx.x; i < 128; i += 64){
    unsigned short u = ge_u16[2*i];
    int ex = (u >> 7) & 0xFF;
    if (ex >= 100 && ex <= 140) ok++;
  }
  atomicAdd(&cnt, ok);
  __syncthreads();
  if (threadIdx.x == 0){
    *flagp = (cnt >= 96) ? 1 : 0;
    outw[0] = 0x7FC07FC0u;
  }
}

// convert all 37 inputs to fp32 into the conv region
__global__ __launch_bounds__(256) void k_convert(Ptrs ptrs, const int* flagp, float* dst){
  int g = blockIdx.x*256 + threadIdx.x;
  if (g >= CONV_TOTAL) return;
  int flag = *flagp;
  int seg = 0;
  while (seg < 36 && g >= c_off[seg+1]) ++seg;
  int local = g - c_off[seg];
  if (local >= c_len[seg]) return;
  float v;
  if (flag) v = __bfloat162float(((const bf16_t*)ptrs.p[seg])[local]);
  else      v = ((const float*)ptrs.p[seg])[local];
  dst[g] = v;
}

// round-16: preconvert mhp_W [128][2560] into fragment order (NT=160, KF=4).
// Output (655360 ushorts = 1.31 MB) lives in the Qb slot (dead until k_gemm3).
__global__ __launch_bounds__(256) void k_wprep3(const float* W, unsigned short* out){
  int idx = blockIdx.x*256 + threadIdx.x;   // 40960 = 160 tiles * 4 s * 64 l
  int l = idx & 63;
  int rest = idx >> 6;
  int s = rest & 3;
  int n = rest >> 2;                        // 0..159
  int g = l >> 4, c16 = l & 15;
  unsigned short hi[8], lo[8];
  #pragma unroll
  for (int e = 0; e < 8; ++e){
    int k = 32*s + 16*(e>>2) + 4*g + (e&3);
    float v = W[k*2560 + 16*n + c16];
    hi[e] = f2h(v); lo[e] = f2h(v - hif(v));
  }
  size_t base = (size_t)idx*8;              // == ((n*4+s)*64+l)*8
  *(uint4*)&out[base]          = *(const uint4*)hi;
  *(uint4*)&out[base + 327680] = *(const uint4*)lo;
}

// round-16: LN_2560 + relu + permute pass over the MFMA-produced y.
// One block per row; reduction tree + epilogue cloned from the old k_mhp.
__global__ __launch_bounds__(256) void k_mhp_ln(const float* y, const float* g,
                      const float* be, float* out){
  int row = blockIdx.x;                     // 0..1535 (= t*128+nn)
  int tid = threadIdx.x;
  __shared__ float red[256];
  float v[10];
  const float* yr = y + (size_t)row*2560;
  #pragma unroll
  for (int m = 0; m < 10; ++m) v[m] = yr[tid + 256*m];
  float ps = 0.f;
  #pragma unroll
  for (int m = 0; m < 10; ++m) ps += v[m];
  red[tid] = ps; __syncthreads();
  for (int s2 = 128; s2 > 0; s2 >>= 1){
    if (tid < s2) red[tid] += red[tid+s2];
    __syncthreads();
  }
  float mean = red[0]*(1.f/2560.f);
  __syncthreads();
  float pv = 0.f;
  #pragma unroll
  for (int m = 0; m < 10; ++m){ float d = v[m]-mean; pv += d*d; }
  red[tid] = pv; __syncthreads();
  for (int s2 = 128; s2 > 0; s2 >>= 1){
    if (tid < s2) red[tid] += red[tid+s2];
    __syncthreads();
  }
  float inv = rsqrtf(red[0]*(1.f/2560.f) + 1e-5f);
  int t = row >> 7, nn = row & 127;
  #pragma unroll
  for (int m = 0; m < 10; ++m){
    int col = tid + 256*m;
    float z = (v[m]-mean)*inv*g[col] + be[col];
    z = fmaxf(z, 0.f);
    int k = col >> 7, hh2 = col & 127;
    out[((t*cKN) + k*cN + nn)*cH + hh2] = z;
  }
}

// preconvert the 4 LSTM weight matrices [128][512] into fragment-ordered
// split-bf16 arrays (per mat: 65536 hi + 65536 lo ushorts,
// layout ((n*4+s)*64+l)*8+e with k = 32s + 16(e>>2) + 4g + (e&3), col=16n+(l&15)).
// Output overlays the dead mhp_W region. One-time, ~10us.
// NOTE: must launch AFTER k_wprep3 has read mhp_W.
__global__ __launch_bounds__(256) void k_wprep(const float* w0, const float* w1,
    const float* w2, const float* w3, unsigned short* out){
  int idx = blockIdx.x*256 + threadIdx.x;   // 32768 total
  int m = idx >> 13;
  int rest = idx & 8191;
  int n = rest >> 8;
  int s = (rest >> 6) & 3;
  int l = rest & 63;
  int g = l >> 4, c16 = l & 15;
  const float* W = (m==0) ? w0 : ((m==1) ? w1 : ((m==2) ? w2 : w3));
  unsigned short hi[8], lo[8];
  #pragma unroll
  for (int e = 0; e < 8; ++e){
    int k = 32*s + 16*(e>>2) + 4*g + (e&3);
    float v = W[k*512 + 16*n + c16];
    hi[e] = f2h(v); lo[e] = f2h(v - hif(v));
  }
  size_t base = (size_t)m*131072 + (size_t)((n*4 + s)*64 + l)*8;
  *(uint4*)&out[base]         = *(const uint4*)hi;
  *(uint4*)&out[base + 65536] = *(const uint4*)lo;
}

// preconvert Wq/Wk/Wv/Wo1/Wo2 into the same fragment order (generalized N, KF).
// Outputs overlay dead f32 weight regions; live biases are NOT overwritten.
__global__ __launch_bounds__(256) void k_wprep2(const float* wq, const float* wk,
    const float* wv, const float* wo1, const float* wo2,
    unsigned short* outA, unsigned short* outB){
  int idx = blockIdx.x*256 + threadIdx.x;   // 14336 total
  if (idx >= 14336) return;
  const float* W; int KF, N, local, half; unsigned short* out; size_t off;
  if (idx < 2048)      { W=wq;  KF=4; N=128; off=0;      local=idx;       half=16384; out=outA; }
  else if (idx < 4096) { W=wk;  KF=4; N=128; off=32768;  local=idx-2048;  half=16384; out=outA; }
  else if (idx < 6144) { W=wv;  KF=4; N=128; off=65536;  local=idx-4096;  half=16384; out=outA; }
  else if (idx < 10240){ W=wo1; KF=4; N=256; off=98304;  local=idx-6144;  half=32768; out=outA; }
  else                 { W=wo2; KF=8; N=128; off=0;      local=idx-10240; half=32768; out=outB; }
  int l = local & 63;
  int rest = local >> 6;
  int s = rest & (KF-1);
  int n = (KF == 8) ? (rest >> 3) : (rest >> 2);
  int g = l >> 4, c16 = l & 15;
  unsigned short hi[8], lo[8];
  #pragma unroll
  for (int e = 0; e < 8; ++e){
    int k = 32*s + 16*(e>>2) + 4*g + (e&3);
    float v = W[k*N + 16*n + c16];
    hi[e] = f2h(v); lo[e] = f2h(v - hif(v));
  }
  size_t base = off + (size_t)local*8;
  *(uint4*)&out[base]        = *(const uint4*)hi;
  *(uint4*)&out[base + half] = *(const uint4*)lo;
}

// MFMA LSTM (R9 verified version, unchanged).
__global__ __launch_bounds__(512) void k_lstm_mfma(const float* ge, float* outh,
    const float* hs0, const float* cn0, const float* soc,
    const unsigned short* wfA, const unsigned short* wfB,
    const float* bias, int phase){
  int r0 = blockIdx.x * 16;
  int tid = threadIdx.x;
  int w = tid >> 6, l = tid & 63;
  int g = l >> 4, c16 = l & 15;
  int scol = w*16 + c16;                 // state col owned by this lane
  __shared__ unsigned short HFh[2][4][64][8], HFl[2][4][64][8];   // 16 KB
  int ps = scol >> 5, prem = scol & 31;
  int pgf = (prem >> 2) & 3;
  int pe  = ((prem >> 4) << 2) + (prem & 3);
  float c[4], h[4];
  #pragma unroll
  for (int r = 0; r < 4; ++r){
    int nn = (r0 + 4*g + r) & 127;
    c[r] = cn0[nn*cH + scol];
    h[r] = hs0[nn*cH + scol];
  }
  float bias_t[4];
  #pragma unroll
  for (int tt = 0; tt < 4; ++tt) bias_t[tt] = bias[tt*128 + scol];

  f32x4 xr[8];
  float socr[4] = {0.f, 0.f, 0.f, 0.f};
  {
    const f32x4* gp = (const f32x4*)ge + ((size_t)(r0 + c16))*32;
    #pragma unroll
    for (int s = 0; s < 4; ++s){ xr[2*s] = gp[8*s + g]; xr[2*s+1] = gp[8*s + 4 + g]; }
    if (phase == 2){
      #pragma unroll
      for (int r = 0; r < 4; ++r)
        socr[r] = soc[(size_t)(r0 + 4*g + r)*cH + scol];
    }
  }

  for (int t = 0; t < cT; ++t){
    int b = t & 1;
    if (phase == 2){
      #pragma unroll
      for (int r = 0; r < 4; ++r){
        c[r] += socr[r];
        h[r] += tanhf(c[r]);
      }
    }
    #pragma unroll
    for (int r = 0; r < 4; ++r){
      HFh[b][ps][pgf*16 + 4*g + r][pe] = f2h(h[r]);
      HFl[b][ps][pgf*16 + 4*g + r][pe] = f2h(h[r] - hif(h[r]));
    }
    bf16x8 xh[4], xl[4];
    #pragma unroll
    for (int s = 0; s < 4; ++s){
      union { unsigned short u[8]; bf16x8 v; } uh, ul;
      #pragma unroll
      for (int m2 = 0; m2 < 4; ++m2){
        float a0 = xr[2*s][m2], b0 = xr[2*s+1][m2];
        uh.u[m2]   = f2h(a0); ul.u[m2]   = f2h(a0 - hif(a0));
        uh.u[4+m2] = f2h(b0); ul.u[4+m2] = f2h(b0 - hif(b0));
      }
      xh[s] = uh.v; xl[s] = ul.v;
    }
    if (t < cT-1){
      const f32x4* gp = (const f32x4*)ge + ((size_t)(t+1)*cKN + r0 + c16)*32;
      #pragma unroll
      for (int s = 0; s < 4; ++s){ xr[2*s] = gp[8*s + g]; xr[2*s+1] = gp[8*s + 4 + g]; }
      if (phase == 2){
        #pragma unroll
        for (int r = 0; r < 4; ++r)
          socr[r] = soc[(size_t)(t+1)*cKN*cH + (size_t)(r0 + 4*g + r)*cH + scol];
      }
    }
    __syncthreads();                      // HF[b] visible (single barrier/step)
    bf16x8 hh[4], hl[4];
    #pragma unroll
    for (int s = 0; s < 4; ++s){
      hh[s] = *(const bf16x8*)&HFh[b][s][l][0];
      hl[s] = *(const bf16x8*)&HFl[b][s][l][0];
    }
    f32x4 a4[4];
    #pragma unroll
    for (int tt = 0; tt < 4; ++tt){
      f32x4 acc = {bias_t[tt], bias_t[tt], bias_t[tt], bias_t[tt]};
      a4[tt] = acc;
    }
    {
      bf16x8 cAh, cAl, cBh, cBl, nAh, nAl, nBh, nBl;
      {
        size_t fo = (size_t)((w*4 + 0)*64 + l)*8;   // tt=0, s=0
        cAh = *(const bf16x8*)&wfA[fo];
        cAl = *(const bf16x8*)&wfA[65536 + fo];
        cBh = *(const bf16x8*)&wfB[fo];
        cBl = *(const bf16x8*)&wfB[65536 + fo];
      }
      #pragma unroll
      for (int j = 0; j < 16; ++j){
        int s = j >> 2, tt = j & 3;
        if (j < 15){
          int j2 = j + 1;
          int s2 = j2 >> 2, tt2 = j2 & 3;
          size_t fo = (size_t)(((w + 8*tt2)*4 + s2)*64 + l)*8;
          nAh = *(const bf16x8*)&wfA[fo];
          nAl = *(const bf16x8*)&wfA[65536 + fo];
          nBh = *(const bf16x8*)&wfB[fo];
          nBl = *(const bf16x8*)&wfB[65536 + fo];
        }
        f32x4 acc = a4[tt];
        acc = __builtin_amdgcn_mfma_f32_16x16x32_bf16(xl[s], cAh, acc, 0, 0, 0);
        acc = __builtin_amdgcn_mfma_f32_16x16x32_bf16(xh[s], cAl, acc, 0, 0, 0);
        acc = __builtin_amdgcn_mfma_f32_16x16x32_bf16(xh[s], cAh, acc, 0, 0, 0);
        acc = __builtin_amdgcn_mfma_f32_16x16x32_bf16(hl[s], cBh, acc, 0, 0, 0);
        acc = __builtin_amdgcn_mfma_f32_16x16x32_bf16(hh[s], cBl, acc, 0, 0, 0);
        acc = __builtin_amdgcn_mfma_f32_16x16x32_bf16(hh[s], cBh, acc, 0, 0, 0);
        a4[tt] = acc;
        cAh = nAh; cAl = nAl; cBh = nBh; cBl = nBl;
      }
    }
    #pragma unroll
    for (int r = 0; r < 4; ++r){
      float ig = sigm(a4[0][r]), fg = sigm(a4[1][r]);
      float gg = tanhf(a4[2][r]), og = sigm(a4[3][r]);
      c[r] = fg*c[r] + ig*gg;
      h[r] = og*tanhf(c[r]);
      outh[(size_t)t*cKN*cH + (size_t)(r0 + 4*g + r)*cH + scol] = h[r];
    }
  }
}

// generic MFMA GEMM (validated). block = 16 rows, 4 independent waves;
// wave wv owns n-tiles {wv, wv+4, ...}. Split-bf16 3-mfma products.
template<int KF>
__global__ __launch_bounds__(256) void k_gemm(const float* x, const unsigned short* wf,
    const float* bias, float* out, int NT, int N, int relu, int half){
  int r0 = blockIdx.x * 16;
  int tid = threadIdx.x;
  int wv = tid >> 6, l = tid & 63;
  int g = l >> 4, c16 = l & 15;
  bf16x8 xh[KF], xl[KF];
  const f32x4* gp = (const f32x4*)x + (size_t)(r0 + c16)*(KF*8);
  #pragma unroll
  for (int s = 0; s < KF; ++s){
    f32x4 qa = gp[8*s + g], qb = gp[8*s + 4 + g];
    union { unsigned short u[8]; bf16x8 v; } uh, ul;
    #pragma unroll
    for (int m2 = 0; m2 < 4; ++m2){
      float a0 = qa[m2], b0 = qb[m2];
      uh.u[m2]   = f2h(a0); ul.u[m2]   = f2h(a0 - hif(a0));
      uh.u[4+m2] = f2h(b0); ul.u[4+m2] = f2h(b0 - hif(b0));
    }
    xh[s] = uh.v; xl[s] = ul.v;
  }
  for (int nt = wv; nt < NT; nt += 4){
    float bb = bias[nt*16 + c16];
    f32x4 acc = {bb, bb, bb, bb};
    #pragma unroll
    for (int s = 0; s < KF; ++s){
      const unsigned short* fb = wf + (size_t)((nt*KF + s)*64 + l)*8;
      bf16x8 Wh = *(const bf16x8*)fb;
      bf16x8 Wl = *(const bf16x8*)(fb + half);
      acc = __builtin_amdgcn_mfma_f32_16x16x32_bf16(xl[s], Wh, acc, 0, 0, 0);
      acc = __builtin_amdgcn_mfma_f32_16x16x32_bf16(xh[s], Wl, acc, 0, 0, 0);
      acc = __builtin_amdgcn_mfma_f32_16x16x32_bf16(xh[s], Wh, acc, 0, 0, 0);
    }
    if (relu){
      #pragma unroll
      for (int r = 0; r < 4; ++r) acc[r] = fmaxf(acc[r], 0.f);
    }
    #pragma unroll
    for (int r = 0; r < 4; ++r)
      out[(size_t)(r0 + 4*g + r)*N + nt*16 + c16] = acc[r];
  }
}

// fused QKV MFMA GEMM (NT=24: tiles 0-7 Q, 8-15 K, 16-23 V).
__global__ __launch_bounds__(256) void k_gemm3(const float* x, const unsigned short* wf,
    const float* bq, const float* bk, const float* bv,
    float* Q, float* K2, float* V){
  int r0 = blockIdx.x * 16;
  int tid = threadIdx.x;
  int wv = tid >> 6, l = tid & 63;
  int g = l >> 4, c16 = l & 15;
  bf16x8 xh[4], xl[4];
  const f32x4* gp = (const f32x4*)x + (size_t)(r0 + c16)*32;
  #pragma unroll
  for (int s = 0; s < 4; ++s){
    f32x4 qa = gp[8*s + g], qb = gp[8*s + 4 + g];
    union { unsigned short u[8]; bf16x8 v; } uh, ul;
    #pragma unroll
    for (int m2 = 0; m2 < 4; ++m2){
      float a0 = qa[m2], b0 = qb[m2];
      uh.u[m2]   = f2h(a0); ul.u[m2]   = f2h(a0 - hif(a0));
      uh.u[4+m2] = f2h(b0); ul.u[4+m2] = f2h(b0 - hif(b0));
    }
    xh[s] = uh.v; xl[s] = ul.v;
  }
  for (int nt = wv; nt < 24; nt += 4){
    int m = nt >> 3, n = nt & 7;
    const float* bias = (m==0) ? bq : ((m==1) ? bk : bv);
    float* out = (m==0) ? Q : ((m==1) ? K2 : V);
    float bb = bias[n*16 + c16];
    f32x4 acc = {bb, bb, bb, bb};
    const unsigned short* base = wf + (size_t)m*32768;
    #pragma unroll
    for (int s = 0; s < 4; ++s){
      const unsigned short* fb = base + (size_t)((n*4 + s)*64 + l)*8;
      bf16x8 Wh = *(const bf16x8*)fb;
      bf16x8 Wl = *(const bf16x8*)(fb + 16384);
      acc = __builtin_amdgcn_mfma_f32_16x16x32_bf16(xl[s], Wh, acc, 0, 0, 0);
      acc = __builtin_amdgcn_mfma_f32_16x16x32_bf16(xh[s], Wl, acc, 0, 0, 0);
      acc = __builtin_amdgcn_mfma_f32_16x16x32_bf16(xh[s], Wh, acc, 0, 0, 0);
    }
    #pragma unroll
    for (int r = 0; r < 4; ++r)
      out[(size_t)(r0 + 4*g + r)*cH + n*16 + c16] = acc[r];
  }
}

// round-16: loc & scale heads, ROWS 4 -> 16. R9 analysis: at ROWS=4 each
// block streams W1 for both heads (128 KB) per 4 rows -> 2 GB total from L2;
// at ROWS=16, wave = (head, 8 rows): same weight loads amortized over 4x rows
// (0.5 GB), per-row shuffle cost unchanged. Epilogue row-at-a-time from the
// verified original.
__global__ __launch_bounds__(256) void k_heads(const float* x,
  const float* lW1, const float* lb1, const float* lg, const float* lbe, const float* lW2, const float* lb2v,
  const float* sW1, const float* sb1, const float* sg, const float* sbe, const float* sW2, const float* sb2v,
  void* outv, int q0, float* locsc, const float* maxv, const float* svp, const int* flagp){
  const int ROWS = 16;
  int r0 = blockIdx.x*ROWS;
  __shared__ float xs[ROWS][cH];
  int tid = threadIdx.x;
  for (int p = tid; p < ROWS*32; p += 256){
    int rr = p>>5, u4 = p&31;
    ((float4*)&xs[rr][0])[u4] = ((const float4*)x)[(size_t)(r0+rr)*32 + u4];
  }
  __syncthreads();
  int wv = tid >> 6, lane = tid & 63;
  int head = wv & 1;
  int rbase = (wv >> 1)*8;               // this wave's 8 rows
  const float* W1 = head ? sW1 : lW1;
  const float* b1 = head ? sb1 : lb1;
  const float* gv = head ? sg  : lg;
  const float* be = head ? sbe : lbe;
  const float* W2 = head ? sW2 : lW2;
  const float* b2 = head ? sb2v: lb2v;
  int j0 = lane, j1 = lane + 64;
  float b10 = b1[j0], b11 = b1[j1];
  float a0[8], a1[8];
  #pragma unroll
  for (int r = 0; r < 8; ++r){ a0[r] = b10; a1[r] = b11; }
  for (int i = 0; i < cH; ++i){
    float w0 = W1[i*cH + j0], w1 = W1[i*cH + j1];
    #pragma unroll
    for (int r = 0; r < 8; ++r){
      float xv = xs[rbase + r][i];
      a0[r] += xv*w0; a1[r] += xv*w1;
    }
  }
  float g0 = gv[j0], g1 = gv[j1], be0 = be[j0], be1 = be[j1];
  float w2a0 = W2[j0*2+0], w2a1 = W2[j0*2+1];
  float w2b0 = W2[j1*2+0], w2b1 = W2[j1*2+1];
  int flag = *flagp;
  float bias0 = b2[0], bias1 = b2[1];
  for (int r = 0; r < 8; ++r){
    float s = a0[r] + a1[r];
    #pragma unroll
    for (int off = 1; off < 64; off <<= 1) s += __shfl_xor(s, off);
    float mean = s*(1.f/128.f);
    float d0 = a0[r]-mean, d1 = a1[r]-mean;
    float vv = d0*d0 + d1*d1;
    #pragma unroll
    for (int off = 1; off < 64; off <<= 1) vv += __shfl_xor(vv, off);
    float inv = rsqrtf(vv*(1.f/128.f) + 1e-5f);
    float z0 = fmaxf(d0*inv*g0 + be0, 0.f);
    float z1 = fmaxf(d1*inv*g1 + be1, 0.f);
    float o0 = z0*w2a0 + z1*w2b0;
    float o1 = z0*w2a1 + z1*w2b1;
    #pragma unroll
    for (int off = 1; off < 64; off <<= 1){
      o0 += __shfl_xor(o0, off);
      o1 += __shfl_xor(o1, off);
    }
    if (lane == 0){
      int rg = r0 + rbase + r;
      int t = rg / cKN, rem = rg - t*cKN;
      int k = rem >> 7, nn = rem & 127;
      float u0 = o0 + bias0, u1 = o1 + bias1;
      if (head == 0){
        size_t oi = (((size_t)q0*cK + k)*cN + nn)*(cT*2) + t*2;
        if (flag){ ((bf16_t*)outv)[oi] = __float2bfloat16(u0); ((bf16_t*)outv)[oi+1] = __float2bfloat16(u1); }
        else     { ((float*)outv)[oi] = u0; ((float*)outv)[oi+1] = u1; }
        if (locsc){
          locsc[((size_t)t*cKN + rem)*2 + 0] = u0*maxv[nn*2+0] + svp[nn*2+0];
          locsc[((size_t)t*cKN + rem)*2 + 1] = u1*maxv[nn*2+1] + svp[nn*2+1];
        }
      } else {
        float e0 = (u0 > 0.f ? u0 : expm1f(u0)) + 1.001f;
        float e1 = (u1 > 0.f ? u1 : expm1f(u1)) + 1.001f;
        size_t oi = (((size_t)(q0+1)*cK + k)*cN + nn)*(cT*2) + t*2;
        if (flag){ ((bf16_t*)outv)[oi] = __float2bfloat16(e0); ((bf16_t*)outv)[oi+1] = __float2bfloat16(e1); }
        else     { ((float*)outv)[oi] = e0; ((float*)outv)[oi+1] = e1; }
      }
    }
  }
}

__global__ __launch_bounds__(256) void k_mask(const float* locsc, unsigned char* m){
  int st = blockIdx.x;
  int s = st / cT, t = st - s*cT;
  __shared__ float lx[cK][cNS], ly[cK][cNS];
  int tid = threadIdx.x;
  for (int p = tid; p < cK*cNS; p += 256){
    int k = p >> 5, i = p & 31;
    int row = t*cKN + k*cN + s*cNS + i;
    lx[k][i] = locsc[row*2+0];
    ly[k][i] = locsc[row*2+1];
  }
  __syncthreads();
  for (int p = tid; p < 1024; p += 256){
    int i = p >> 5, j = p & 31;
    bool any = false;
    for (int k = 0; k < cK; ++k){
      float dx = fabsf(lx[k][i]-lx[k][j]);
      float dy = fabsf(ly[k][i]-ly[k][j]);
      any = any || ((dx < 10.f) && (dy < 10.f));
    }
    m[st*1024 + p] = any ? 1 : 0;
  }
}

// MFMA attention (validated). Split-bf16 3-mfma products; QK^T = mfma(A=K, B=Q)
// with k-map k=16(e>>2)+4g+(e&3); PV A-frag = lane's own S-accumulator.
// No-max softmax. K/V staged to LDS in fragment order.
__global__ __launch_bounds__(256) void k_attn(const float* Q, const float* Kx, const float* V,
                       const unsigned char* msk, float* ctx){
  int qs   = blockIdx.x;        // 0..4 : group of 8 q-tiles (2 per wave)
  int head = blockIdx.y;        // 0..3
  int st   = blockIdx.z;        // s*cT + t
  int s = st / cT, t = st - s*cT;
  __shared__ unsigned short KLh[2][1024], KLl[2][1024], VLh[2][1024], VLl[2][1024]; // 16 KB
  int tid = threadIdx.x;
  int w = tid >> 6, lane = tid & 63;
  int g = lane >> 4, col = lane & 15;
  const float scl = 0.17677669529663687f;   // 1/sqrt(32)

  unsigned int mw0 = 0, mw1 = 0;
  {
    const unsigned int* mr0 = (const unsigned int*)(msk + st*1024 + col*32);
    const unsigned int* mr1 = (const unsigned int*)(msk + st*1024 + (16+col)*32);
    #pragma unroll
    for (int j2 = 0; j2 < 8; ++j2){
      mw0 |= (((mr0[j2] * 0x01020408u) >> 24) & 0xFu) << (4*j2);
      mw1 |= (((mr1[j2] * 0x01020408u) >> 24) & 0xFu) << (4*j2);
    }
  }

  bf16x8 Qh[2], Ql[2];
  int modes[2], ahs[2];
  #pragma unroll
  for (int i = 0; i < 2; ++i){
    int tt = qs*8 + 4*i + w;       // 0..39
    int mode = tt >> 1, ah = tt & 1;
    modes[i] = mode; ahs[i] = ah;
    int qrow = t*cKN + mode*cN + s*cNS + ah*16 + col;
    const f32x4* qp = (const f32x4*)Q + (size_t)qrow*32 + head*8;
    f32x4 qa = qp[g], qb = qp[4+g];
    union { unsigned short u[8]; bf16x8 v; } uh, ul;
    #pragma unroll
    for (int m = 0; m < 4; ++m){
      float x0 = qa[m]*scl;
      uh.u[m] = f2h(x0);
      ul.u[m] = f2h(x0 - hif(x0));
      float x1 = qb[m]*scl;
      uh.u[4+m] = f2h(x1);
      ul.u[4+m] = f2h(x1 - hif(x1));
    }
    Qh[i] = uh.v; Ql[i] = ul.v;
  }

  int kk = tid >> 3, f4 = tid & 7;
  int kwi = (((kk>>4)*4 + (f4&3))*16 + (kk&15))*8 + (f4>>2)*4;
  int vd = tid & 31, quad = tid >> 5;
  int vkey = (quad>>2)*16 + (quad&3)*4;
  int vwi = (((vd>>4)*4 + (quad&3))*16 + (vd&15))*8 + (quad>>2)*4;

  const size_t cstepK = (size_t)cN*32;
  const size_t cstepV = (size_t)cN*128;
  const float4* kptr = (const float4*)Kx + ((size_t)(t*cKN + s*cNS + kk))*32 + head*8 + f4;
  const float*  vptr = V + ((size_t)(t*cKN + s*cNS + vkey))*128 + head*32 + vd;

  float4 kv; float vm0, vm1, vm2, vm3;
  kv = *kptr; kptr += cstepK;
  vm0 = vptr[0]; vm1 = vptr[128]; vm2 = vptr[256]; vm3 = vptr[384]; vptr += cstepV;
  {
    unsigned int h0 = (unsigned int)f2h(kv.x) | ((unsigned int)f2h(kv.y)<<16);
    unsigned int h1 = (unsigned int)f2h(kv.z) | ((unsigned int)f2h(kv.w)<<16);
    float r0 = kv.x-hif(kv.x), r1 = kv.y-hif(kv.y), r2 = kv.z-hif(kv.z), r3 = kv.w-hif(kv.w);
    unsigned int l0 = (unsigned int)f2h(r0) | ((unsigned int)f2h(r1)<<16);
    unsigned int l1 = (unsigned int)f2h(r2) | ((unsigned int)f2h(r3)<<16);
    *(uint2*)&KLh[0][kwi] = make_uint2(h0,h1);
    *(uint2*)&KLl[0][kwi] = make_uint2(l0,l1);
    unsigned int vh0 = (unsigned int)f2h(vm0) | ((unsigned int)f2h(vm1)<<16);
    unsigned int vh1 = (unsigned int)f2h(vm2) | ((unsigned int)f2h(vm3)<<16);
    float s0 = vm0-hif(vm0), s1 = vm1-hif(vm1), s2 = vm2-hif(vm2), s3 = vm3-hif(vm3);
    unsigned int vl0 = (unsigned int)f2h(s0) | ((unsigned int)f2h(s1)<<16);
    unsigned int vl1 = (unsigned int)f2h(s2) | ((unsigned int)f2h(s3)<<16);
    *(uint2*)&VLh[0][vwi] = make_uint2(vh0,vh1);
    *(uint2*)&VLl[0][vwi] = make_uint2(vl0,vl1);
  }
  __syncthreads();

  const f32x4 Z = {0.f, 0.f, 0.f, 0.f};
  f32x4 O[2][2] = {{Z, Z}, {Z, Z}};
  float lac[2] = {0.f, 0.f};

  for (int ch = 0; ch < 20; ++ch){
    int par = ch & 1;
    if (ch < 19){
      kv = *kptr; kptr += cstepK;
      vm0 = vptr[0]; vm1 = vptr[128]; vm2 = vptr[256]; vm3 = vptr[384]; vptr += cstepV;
    }
    bf16x8 KAh0 = *(const bf16x8*)&KLh[par][( g      *16 + col)*8];
    bf16x8 KAl0 = *(const bf16x8*)&KLl[par][( g      *16 + col)*8];
    bf16x8 KAh1 = *(const bf16x8*)&KLh[par][((4 + g) *16 + col)*8];
    bf16x8 KAl1 = *(const bf16x8*)&KLl[par][((4 + g) *16 + col)*8];
    bf16x8 VBh0 = *(const bf16x8*)&VLh[par][( g      *16 + col)*8];
    bf16x8 VBl0 = *(const bf16x8*)&VLl[par][( g      *16 + col)*8];
    bf16x8 VBh1 = *(const bf16x8*)&VLh[par][((4 + g) *16 + col)*8];
    bf16x8 VBl1 = *(const bf16x8*)&VLl[par][((4 + g) *16 + col)*8];
    #pragma unroll
    for (int i = 0; i < 2; ++i){
      f32x4 sa = Z, sb = Z;
      sa = __builtin_amdgcn_mfma_f32_16x16x32_bf16(KAl0, Qh[i], sa, 0, 0, 0);
      sa = __builtin_amdgcn_mfma_f32_16x16x32_bf16(KAh0, Ql[i], sa, 0, 0, 0);
      sa = __builtin_amdgcn_mfma_f32_16x16x32_bf16(KAh0, Qh[i], sa, 0, 0, 0);
      sb = __builtin_amdgcn_mfma_f32_16x16x32_bf16(KAl1, Qh[i], sb, 0, 0, 0);
      sb = __builtin_amdgcn_mfma_f32_16x16x32_bf16(KAh1, Ql[i], sb, 0, 0, 0);
      sb = __builtin_amdgcn_mfma_f32_16x16x32_bf16(KAh1, Qh[i], sb, 0, 0, 0);
      unsigned int mw = ahs[i] ? mw1 : mw0;
      float p[8];
      #pragma unroll
      for (int r = 0; r < 4; ++r){
        float e0 = __expf(sa[r]);
        float e1 = __expf(sb[r]);
        p[r]   = ((mw >> (4*g + r)) & 1)        ? e0 : 0.f;
        p[4+r] = ((mw >> (16 + 4*g + r)) & 1)   ? e1 : 0.f;
      }
      lac[i] += ((p[0]+p[1])+(p[2]+p[3])) + ((p[4]+p[5])+(p[6]+p[7]));
      union { unsigned short u[8]; bf16x8 v; } Ph, Pl;
      #pragma unroll
      for (int e = 0; e < 8; ++e){
        Ph.u[e] = f2h(p[e]);
        Pl.u[e] = f2h(p[e] - hif(p[e]));
      }
      O[i][0] = __builtin_amdgcn_mfma_f32_16x16x32_bf16(Pl.v, VBh0, O[i][0], 0, 0, 0);
      O[i][0] = __builtin_amdgcn_mfma_f32_16x16x32_bf16(Ph.v, VBl0, O[i][0], 0, 0, 0);
      O[i][0] = __builtin_amdgcn_mfma_f32_16x16x32_bf16(Ph.v, VBh0, O[i][0], 0, 0, 0);
      O[i][1] = __builtin_amdgcn_mfma_f32_16x16x32_bf16(Pl.v, VBh1, O[i][1], 0, 0, 0);
      O[i][1] = __builtin_amdgcn_mfma_f32_16x16x32_bf16(Ph.v, VBl1, O[i][1], 0, 0, 0);
      O[i][1] = __builtin_amdgcn_mfma_f32_16x16x32_bf16(Ph.v, VBh1, O[i][1], 0, 0, 0);
    }
    __syncthreads();   // all frag reads of [par] done
    if (ch < 19){
      int nb = 1 - par;
      unsigned int h0 = (unsigned int)f2h(kv.x) | ((unsigned int)f2h(kv.y)<<16);
      unsigned int h1 = (unsigned int)f2h(kv.z) | ((unsigned int)f2h(kv.w)<<16);
      float r0 = kv.x-hif(kv.x), r1 = kv.y-hif(kv.y), r2 = kv.z-hif(kv.z), r3 = kv.w-hif(kv.w);
      unsigned int l0 = (unsigned int)f2h(r0) | ((unsigned int)f2h(r1)<<16);
      unsigned int l1 = (unsigned int)f2h(r2) | ((unsigned int)f2h(r3)<<16);
      *(uint2*)&KLh[nb][kwi] = make_uint2(h0,h1);
      *(uint2*)&KLl[nb][kwi] = make_uint2(l0,l1);
      unsigned int vh0 = (unsigned int)f2h(vm0) | ((unsigned int)f2h(vm1)<<16);
      unsigned int vh1 = (unsigned int)f2h(vm2) | ((unsigned int)f2h(vm3)<<16);
      float s0 = vm0-hif(vm0), s1 = vm1-hif(vm1), s2 = vm2-hif(vm2), s3 = vm3-hif(vm3);
      unsigned int vl0 = (unsigned int)f2h(s0) | ((unsigned int)f2h(s1)<<16);
      unsigned int vl1 = (unsigned int)f2h(s2) | ((unsigned int)f2h(s3)<<16);
      *(uint2*)&VLh[nb][vwi] = make_uint2(vh0,vh1);
      *(uint2*)&VLl[nb][vwi] = make_uint2(vl0,vl1);
    }
    __syncthreads();   // next buffer visible
  }

  #pragma unroll
  for (int i = 0; i < 2; ++i){
    float lsum = lac[i];
    lsum += __shfl_xor(lsum, 16);
    lsum += __shfl_xor(lsum, 32);
    int base = t*cKN + modes[i]*cN + s*cNS + ahs[i]*16;
    #pragma unroll
    for (int r = 0; r < 4; ++r){
      float lq = __shfl(lsum, 4*g + r);
      float rinv = 1.f / lq;
      float* cp = ctx + (size_t)(base + 4*g + r)*cH + head*cHD;
      cp[col]      = O[i][0][r] * rinv;
      cp[col+16]   = O[i][1][r] * rinv;
    }
  }
}

extern "C" void kernel_launch(void* const* d_in, const int* in_sizes, int n_in,
                              void* d_out, int out_size, void* d_ws, size_t ws_size,
                              hipStream_t stream){
  (void)in_sizes; (void)n_in; (void)out_size; (void)ws_size;

  int*   flagp = (int*)d_ws;
  float* conv  = (float*)d_ws + 64;
  float* big   = (float*)d_ws + 978112;

  const float* ge_f   = conv + 0;
  const float* hs_f   = conv + 196608;
  const float* cn_f   = conv + 212992;
  const float* sv_f   = conv + 229376;
  const float* mx_f   = conv + 229632;
  const float* mhpW_f = conv + 229888;
  const float* mhpb_f = conv + 557568;
  const float* mhpg_f = conv + 560128;
  const float* mhpbe_f= conv + 562688;
  const float* l1Wih_f= conv + 565248;
  const float* l1Whh_f= conv + 630784;
  const float* l1b_f  = conv + 696320;
  const float* l2Wih_f= conv + 696832;
  const float* l2Whh_f= conv + 762368;
  const float* l2b_f  = conv + 827904;
  const float* Wq_f   = conv + 828416;
  const float* bq_f   = conv + 844800;
  const float* Wk_f   = conv + 844928;
  const float* bk_f   = conv + 861312;
  const float* Wv_f   = conv + 861440;
  const float* bv_f   = conv + 877824;
  const float* Wo1_f  = conv + 877952;
  const float* bo1_f  = conv + 910720;
  const float* Wo2_f  = conv + 910976;
  const float* bo2_f  = conv + 943744;
  const float* locW1_f= conv + 943872;
  const float* locb1_f= conv + 960256;
  const float* locg_f = conv + 960384;
  const float* locbe_f= conv + 960512;
  const float* locW2_f= conv + 960640;
  const float* locb2_f= conv + 960896;
  const float* sclW1_f= conv + 960960;
  const float* sclb1_f= conv + 977344;
  const float* sclg_f = conv + 977472;
  const float* sclbe_f= conv + 977600;
  const float* sclW2_f= conv + 977728;
  const float* sclb2_f= conv + 977984;

  const size_t SLOT = (size_t)cT*cKN*cH;
  float* geb = big;
  float* o1b = big + SLOT;
  float* Qb  = big + 2*SLOT;
  float* Kb  = big + 3*SLOT;
  float* Vb  = big + 4*SLOT;
  float* locsc = big + 5*SLOT;
  unsigned char* maskb = (unsigned char*)(locsc + (size_t)cT*cKN*2);
  float* t1 = Qb;        // spans slots 2-3 (Q/K dead after attn)
  float* social = Vb;    // overlays V after attention

  // LSTM weight fragments overlay the mhp_W region (dead after k_wprep3+mhp gemm)
  unsigned short* wfrag = (unsigned short*)(conv + 229888);
  unsigned short* uA = (unsigned short*)(conv + 565248);
  unsigned short* uB = (unsigned short*)(conv + 696832);
  // mhp weight fragments + raw-y temp live in Qb/Kb slots (dead until k_gemm3)
  unsigned short* mfrag = (unsigned short*)(big + 2*SLOT);
  float* ytmp = big + 3*SLOT;    // 1536*2560 = exactly one SLOT

  Ptrs ptrs;
  for (int i = 0; i < 37; ++i) ptrs.p[i] = d_in[i];

  k_detect<<<1, 64, 0, stream>>>((const unsigned short*)d_in[0], flagp, (unsigned int*)d_out);
  k_convert<<<(CONV_TOTAL+255)/256, 256, 0, stream>>>(ptrs, flagp, conv);
  k_wprep3<<<160, 256, 0, stream>>>(mhpW_f, mfrag);
  k_gemm<4><<<96, 256, 0, stream>>>(ge_f, mfrag, mhpb_f, ytmp, 160, 2560, 0, 327680);
  k_mhp_ln<<<1536, 256, 0, stream>>>(ytmp, mhpg_f, mhpbe_f, geb);
  k_wprep<<<128, 256, 0, stream>>>(l1Wih_f, l1Whh_f, l2Wih_f, l2Whh_f, wfrag);
  k_wprep2<<<56, 256, 0, stream>>>(Wq_f, Wk_f, Wv_f, Wo1_f, Wo2_f, uA, uB);
  k_lstm_mfma<<<160, 512, 0, stream>>>(geb, o1b, hs_f, cn_f, (const float*)0,
                                       wfrag + 0, wfrag + 131072, l1b_f, 1);
  k_heads<<<cT*cKN/16, 256, 0, stream>>>(o1b, locW1_f,locb1_f,locg_f,locbe_f,locW2_f,locb2_f,
                                        sclW1_f,sclb1_f,sclg_f,sclbe_f,sclW2_f,sclb2_f,
                                        d_out, 0, locsc, mx_f, sv_f, flagp);
  k_mask<<<cS*cT, 256, 0, stream>>>(locsc, maskb);
  k_gemm3<<<cT*cKN/16, 256, 0, stream>>>(o1b, uA, bq_f, bk_f, bv_f, Qb, Kb, Vb);
  {
    dim3 ag(5, 4, cS*cT);
    k_attn<<<ag, 256, 0, stream>>>(Qb, Kb, Vb, maskb, o1b);   // ctx overlays out1
  }
  k_gemm<4><<<cT*cKN/16, 256, 0, stream>>>(o1b, uA + 98304, bo1_f, t1, 16, 256, 1, 32768);
  k_gemm<8><<<cT*cKN/16, 256, 0, stream>>>(t1, uB, bo2_f, social, 8, 128, 0, 32768);
  k_lstm_mfma<<<160, 512, 0, stream>>>(geb, o1b, hs_f, cn_f, social,
                                       wfrag + 262144, wfrag + 393216, l2b_f, 2);
  k_heads<<<cT*cKN/16, 256, 0, stream>>>(o1b, locW1_f,locb1_f,locg_f,locbe_f,locW2_f,locb2_f,
                                        sclW1_f,sclb1_f,sclg_f,sclbe_f,sclW2_f,sclb2_f,
                                        d_out, 2, (float*)0, mx_f, sv_f, flagp);
}

// Round 11
// 584.723 us; speedup vs baseline: 1.3320x; 1.0823x over previous
//
#include <hip/hip_runtime.h>
#include <hip/hip_bf16.h>

typedef __hip_bfloat16 bf16_t;

static const int cT  = 12;    // future steps
static const int cN  = 128;   // agents
static const int cH  = 128;   // hidden
static const int cK  = 20;    // modes
static const int cKN = 2560;  // cK*cN
static const int cS  = 4;     // batch split
static const int cNS = 32;    // agents per scene
static const int cL  = 640;   // cK*cNS attention length
static const int cHD = 32;    // head dim

#define CONV_TOTAL 977986

__constant__ int c_off[38] = {0,196608,212992,229376,229632,229888,557568,560128,562688,
  565248,630784,696320,696832,762368,827904,828416,844800,844928,861312,861440,877824,
  877952,910720,910976,943744,943872,960256,960384,960512,960640,960896,960960,977344,
  977472,977600,977728,977984,977986};
__constant__ int c_len[37] = {196608,16384,16384,256,256,327680,2560,2560,2560,
  65536,65536,512,65536,65536,512,16384,128,16384,128,16384,128,
  32768,256,32768,128,16384,128,128,128,256,2,16384,128,128,128,256,2};

struct Ptrs { const void* p[37]; };

typedef __attribute__((ext_vector_type(4))) float f32x4;
typedef __attribute__((ext_vector_type(8))) __bf16 bf16x8;

__device__ __forceinline__ float sigm(float x){ return 1.f/(1.f+expf(-x)); }
__device__ __forceinline__ unsigned short f2h(float x){ return (unsigned short)(__float_as_uint(x)>>16); }
__device__ __forceinline__ float hif(float x){ return __uint_as_float(__float_as_uint(x)&0xFFFF0000u); }

// dtype sniffing + NaN canary
__global__ __launch_bounds__(256) void k_detect(const unsigned short* ge_u16, int* flagp, unsigned int* outw){
  __shared__ int cnt;
  if (threadIdx.x == 0) cnt = 0;
  __syncthreads();
  int ok = 0;
  for (int i = threadIdx.x; i < 128; i += 64){
    unsigned short u = ge_u16[2*i];
    int ex = (u >> 7) & 0xFF;
    if (ex >= 100 && ex <= 140) ok++;
  }
  atomicAdd(&cnt, ok);
  __syncthreads();
  if (threadIdx.x == 0){
    *flagp = (cnt >= 96) ? 1 : 0;
    outw[0] = 0x7FC07FC0u;
  }
}

// convert all 37 inputs to fp32 into the conv region
__global__ __launch_bounds__(256) void k_convert(Ptrs ptrs, const int* flagp, float* dst){
  int g = blockIdx.x*256 + threadIdx.x;
  if (g >= CONV_TOTAL) return;
  int flag = *flagp;
  int seg = 0;
  while (seg < 36 && g >= c_off[seg+1]) ++seg;
  int local = g - c_off[seg];
  if (local >= c_len[seg]) return;
  float v;
  if (flag) v = __bfloat162float(((const bf16_t*)ptrs.p[seg])[local]);
  else      v = ((const float*)ptrs.p[seg])[local];
  dst[g] = v;
}

// preconvert mhp_W [128][2560] into fragment order (NT=160, KF=4).
// Output (655360 ushorts = 1.31 MB) lives in the Qb slot (dead until k_gemm3).
__global__ __launch_bounds__(256) void k_wprep3(const float* W, unsigned short* out){
  int idx = blockIdx.x*256 + threadIdx.x;   // 40960 = 160 tiles * 4 s * 64 l
  int l = idx & 63;
  int rest = idx >> 6;
  int s = rest & 3;
  int n = rest >> 2;                        // 0..159
  int g = l >> 4, c16 = l & 15;
  unsigned short hi[8], lo[8];
  #pragma unroll
  for (int e = 0; e < 8; ++e){
    int k = 32*s + 16*(e>>2) + 4*g + (e&3);
    float v = W[k*2560 + 16*n + c16];
    hi[e] = f2h(v); lo[e] = f2h(v - hif(v));
  }
  size_t base = (size_t)idx*8;              // == ((n*4+s)*64+l)*8
  *(uint4*)&out[base]          = *(const uint4*)hi;
  *(uint4*)&out[base + 327680] = *(const uint4*)lo;
}

// LN_2560 + relu + permute pass over the MFMA-produced y.
__global__ __launch_bounds__(256) void k_mhp_ln(const float* y, const float* g,
                      const float* be, float* out){
  int row = blockIdx.x;                     // 0..1535 (= t*128+nn)
  int tid = threadIdx.x;
  __shared__ float red[256];
  float v[10];
  const float* yr = y + (size_t)row*2560;
  #pragma unroll
  for (int m = 0; m < 10; ++m) v[m] = yr[tid + 256*m];
  float ps = 0.f;
  #pragma unroll
  for (int m = 0; m < 10; ++m) ps += v[m];
  red[tid] = ps; __syncthreads();
  for (int s2 = 128; s2 > 0; s2 >>= 1){
    if (tid < s2) red[tid] += red[tid+s2];
    __syncthreads();
  }
  float mean = red[0]*(1.f/2560.f);
  __syncthreads();
  float pv = 0.f;
  #pragma unroll
  for (int m = 0; m < 10; ++m){ float d = v[m]-mean; pv += d*d; }
  red[tid] = pv; __syncthreads();
  for (int s2 = 128; s2 > 0; s2 >>= 1){
    if (tid < s2) red[tid] += red[tid+s2];
    __syncthreads();
  }
  float inv = rsqrtf(red[0]*(1.f/2560.f) + 1e-5f);
  int t = row >> 7, nn = row & 127;
  #pragma unroll
  for (int m = 0; m < 10; ++m){
    int col = tid + 256*m;
    float z = (v[m]-mean)*inv*g[col] + be[col];
    z = fmaxf(z, 0.f);
    int k = col >> 7, hh2 = col & 127;
    out[((t*cKN) + k*cN + nn)*cH + hh2] = z;
  }
}

// preconvert the 4 LSTM weight matrices [128][512] into fragment-ordered
// split-bf16 arrays. Output overlays the dead mhp_W region.
// NOTE: must launch AFTER k_wprep3 has read mhp_W.
__global__ __launch_bounds__(256) void k_wprep(const float* w0, const float* w1,
    const float* w2, const float* w3, unsigned short* out){
  int idx = blockIdx.x*256 + threadIdx.x;   // 32768 total
  int m = idx >> 13;
  int rest = idx & 8191;
  int n = rest >> 8;
  int s = (rest >> 6) & 3;
  int l = rest & 63;
  int g = l >> 4, c16 = l & 15;
  const float* W = (m==0) ? w0 : ((m==1) ? w1 : ((m==2) ? w2 : w3));
  unsigned short hi[8], lo[8];
  #pragma unroll
  for (int e = 0; e < 8; ++e){
    int k = 32*s + 16*(e>>2) + 4*g + (e&3);
    float v = W[k*512 + 16*n + c16];
    hi[e] = f2h(v); lo[e] = f2h(v - hif(v));
  }
  size_t base = (size_t)m*131072 + (size_t)((n*4 + s)*64 + l)*8;
  *(uint4*)&out[base]         = *(const uint4*)hi;
  *(uint4*)&out[base + 65536] = *(const uint4*)lo;
}

// preconvert Wq/Wk/Wv/Wo1/Wo2 into fragment order (generalized N, KF).
__global__ __launch_bounds__(256) void k_wprep2(const float* wq, const float* wk,
    const float* wv, const float* wo1, const float* wo2,
    unsigned short* outA, unsigned short* outB){
  int idx = blockIdx.x*256 + threadIdx.x;   // 14336 total
  if (idx >= 14336) return;
  const float* W; int KF, N, local, half; unsigned short* out; size_t off;
  if (idx < 2048)      { W=wq;  KF=4; N=128; off=0;      local=idx;       half=16384; out=outA; }
  else if (idx < 4096) { W=wk;  KF=4; N=128; off=32768;  local=idx-2048;  half=16384; out=outA; }
  else if (idx < 6144) { W=wv;  KF=4; N=128; off=65536;  local=idx-4096;  half=16384; out=outA; }
  else if (idx < 10240){ W=wo1; KF=4; N=256; off=98304;  local=idx-6144;  half=32768; out=outA; }
  else                 { W=wo2; KF=8; N=128; off=0;      local=idx-10240; half=32768; out=outB; }
  int l = local & 63;
  int rest = local >> 6;
  int s = rest & (KF-1);
  int n = (KF == 8) ? (rest >> 3) : (rest >> 2);
  int g = l >> 4, c16 = l & 15;
  unsigned short hi[8], lo[8];
  #pragma unroll
  for (int e = 0; e < 8; ++e){
    int k = 32*s + 16*(e>>2) + 4*g + (e&3);
    float v = W[k*N + 16*n + c16];
    hi[e] = f2h(v); lo[e] = f2h(v - hif(v));
  }
  size_t base = off + (size_t)local*8;
  *(uint4*)&out[base]        = *(const uint4*)hi;
  *(uint4*)&out[base + half] = *(const uint4*)lo;
}

// MFMA LSTM (R9 verified version, unchanged).
__global__ __launch_bounds__(512) void k_lstm_mfma(const float* ge, float* outh,
    const float* hs0, const float* cn0, const float* soc,
    const unsigned short* wfA, const unsigned short* wfB,
    const float* bias, int phase){
  int r0 = blockIdx.x * 16;
  int tid = threadIdx.x;
  int w = tid >> 6, l = tid & 63;
  int g = l >> 4, c16 = l & 15;
  int scol = w*16 + c16;                 // state col owned by this lane
  __shared__ unsigned short HFh[2][4][64][8], HFl[2][4][64][8];   // 16 KB
  int ps = scol >> 5, prem = scol & 31;
  int pgf = (prem >> 2) & 3;
  int pe  = ((prem >> 4) << 2) + (prem & 3);
  float c[4], h[4];
  #pragma unroll
  for (int r = 0; r < 4; ++r){
    int nn = (r0 + 4*g + r) & 127;
    c[r] = cn0[nn*cH + scol];
    h[r] = hs0[nn*cH + scol];
  }
  float bias_t[4];
  #pragma unroll
  for (int tt = 0; tt < 4; ++tt) bias_t[tt] = bias[tt*128 + scol];

  f32x4 xr[8];
  float socr[4] = {0.f, 0.f, 0.f, 0.f};
  {
    const f32x4* gp = (const f32x4*)ge + ((size_t)(r0 + c16))*32;
    #pragma unroll
    for (int s = 0; s < 4; ++s){ xr[2*s] = gp[8*s + g]; xr[2*s+1] = gp[8*s + 4 + g]; }
    if (phase == 2){
      #pragma unroll
      for (int r = 0; r < 4; ++r)
        socr[r] = soc[(size_t)(r0 + 4*g + r)*cH + scol];
    }
  }

  for (int t = 0; t < cT; ++t){
    int b = t & 1;
    if (phase == 2){
      #pragma unroll
      for (int r = 0; r < 4; ++r){
        c[r] += socr[r];
        h[r] += tanhf(c[r]);
      }
    }
    #pragma unroll
    for (int r = 0; r < 4; ++r){
      HFh[b][ps][pgf*16 + 4*g + r][pe] = f2h(h[r]);
      HFl[b][ps][pgf*16 + 4*g + r][pe] = f2h(h[r] - hif(h[r]));
    }
    bf16x8 xh[4], xl[4];
    #pragma unroll
    for (int s = 0; s < 4; ++s){
      union { unsigned short u[8]; bf16x8 v; } uh, ul;
      #pragma unroll
      for (int m2 = 0; m2 < 4; ++m2){
        float a0 = xr[2*s][m2], b0 = xr[2*s+1][m2];
        uh.u[m2]   = f2h(a0); ul.u[m2]   = f2h(a0 - hif(a0));
        uh.u[4+m2] = f2h(b0); ul.u[4+m2] = f2h(b0 - hif(b0));
      }
      xh[s] = uh.v; xl[s] = ul.v;
    }
    if (t < cT-1){
      const f32x4* gp = (const f32x4*)ge + ((size_t)(t+1)*cKN + r0 + c16)*32;
      #pragma unroll
      for (int s = 0; s < 4; ++s){ xr[2*s] = gp[8*s + g]; xr[2*s+1] = gp[8*s + 4 + g]; }
      if (phase == 2){
        #pragma unroll
        for (int r = 0; r < 4; ++r)
          socr[r] = soc[(size_t)(t+1)*cKN*cH + (size_t)(r0 + 4*g + r)*cH + scol];
      }
    }
    __syncthreads();                      // HF[b] visible (single barrier/step)
    bf16x8 hh[4], hl[4];
    #pragma unroll
    for (int s = 0; s < 4; ++s){
      hh[s] = *(const bf16x8*)&HFh[b][s][l][0];
      hl[s] = *(const bf16x8*)&HFl[b][s][l][0];
    }
    f32x4 a4[4];
    #pragma unroll
    for (int tt = 0; tt < 4; ++tt){
      f32x4 acc = {bias_t[tt], bias_t[tt], bias_t[tt], bias_t[tt]};
      a4[tt] = acc;
    }
    {
      bf16x8 cAh, cAl, cBh, cBl, nAh, nAl, nBh, nBl;
      {
        size_t fo = (size_t)((w*4 + 0)*64 + l)*8;   // tt=0, s=0
        cAh = *(const bf16x8*)&wfA[fo];
        cAl = *(const bf16x8*)&wfA[65536 + fo];
        cBh = *(const bf16x8*)&wfB[fo];
        cBl = *(const bf16x8*)&wfB[65536 + fo];
      }
      #pragma unroll
      for (int j = 0; j < 16; ++j){
        int s = j >> 2, tt = j & 3;
        if (j < 15){
          int j2 = j + 1;
          int s2 = j2 >> 2, tt2 = j2 & 3;
          size_t fo = (size_t)(((w + 8*tt2)*4 + s2)*64 + l)*8;
          nAh = *(const bf16x8*)&wfA[fo];
          nAl = *(const bf16x8*)&wfA[65536 + fo];
          nBh = *(const bf16x8*)&wfB[fo];
          nBl = *(const bf16x8*)&wfB[65536 + fo];
        }
        f32x4 acc = a4[tt];
        acc = __builtin_amdgcn_mfma_f32_16x16x32_bf16(xl[s], cAh, acc, 0, 0, 0);
        acc = __builtin_amdgcn_mfma_f32_16x16x32_bf16(xh[s], cAl, acc, 0, 0, 0);
        acc = __builtin_amdgcn_mfma_f32_16x16x32_bf16(xh[s], cAh, acc, 0, 0, 0);
        acc = __builtin_amdgcn_mfma_f32_16x16x32_bf16(hl[s], cBh, acc, 0, 0, 0);
        acc = __builtin_amdgcn_mfma_f32_16x16x32_bf16(hh[s], cBl, acc, 0, 0, 0);
        acc = __builtin_amdgcn_mfma_f32_16x16x32_bf16(hh[s], cBh, acc, 0, 0, 0);
        a4[tt] = acc;
        cAh = nAh; cAl = nAl; cBh = nBh; cBl = nBl;
      }
    }
    #pragma unroll
    for (int r = 0; r < 4; ++r){
      float ig = sigm(a4[0][r]), fg = sigm(a4[1][r]);
      float gg = tanhf(a4[2][r]), og = sigm(a4[3][r]);
      c[r] = fg*c[r] + ig*gg;
      h[r] = og*tanhf(c[r]);
      outh[(size_t)t*cKN*cH + (size_t)(r0 + 4*g + r)*cH + scol] = h[r];
    }
  }
}

// generic MFMA GEMM with NT chunking via blockIdx.y (round-17: the mhp GEMM
// at 96 blocks was 0.375 blocks/CU -> occupancy-starved; splitting the n-tile
// range over gridDim.y multiplies blocks without duplicating weight traffic).
template<int KF>
__global__ __launch_bounds__(256) void k_gemm(const float* x, const unsigned short* wf,
    const float* bias, float* out, int NT, int N, int relu, int half, int ntc){
  int r0 = blockIdx.x * 16;
  int nt0 = blockIdx.y * ntc;
  int ntEnd = nt0 + ntc; if (ntEnd > NT) ntEnd = NT;
  int tid = threadIdx.x;
  int wv = tid >> 6, l = tid & 63;
  int g = l >> 4, c16 = l & 15;
  bf16x8 xh[KF], xl[KF];
  const f32x4* gp = (const f32x4*)x + (size_t)(r0 + c16)*(KF*8);
  #pragma unroll
  for (int s = 0; s < KF; ++s){
    f32x4 qa = gp[8*s + g], qb = gp[8*s + 4 + g];
    union { unsigned short u[8]; bf16x8 v; } uh, ul;
    #pragma unroll
    for (int m2 = 0; m2 < 4; ++m2){
      float a0 = qa[m2], b0 = qb[m2];
      uh.u[m2]   = f2h(a0); ul.u[m2]   = f2h(a0 - hif(a0));
      uh.u[4+m2] = f2h(b0); ul.u[4+m2] = f2h(b0 - hif(b0));
    }
    xh[s] = uh.v; xl[s] = ul.v;
  }
  for (int nt = nt0 + wv; nt < ntEnd; nt += 4){
    float bb = bias[nt*16 + c16];
    f32x4 acc = {bb, bb, bb, bb};
    #pragma unroll
    for (int s = 0; s < KF; ++s){
      const unsigned short* fb = wf + (size_t)((nt*KF + s)*64 + l)*8;
      bf16x8 Wh = *(const bf16x8*)fb;
      bf16x8 Wl = *(const bf16x8*)(fb + half);
      acc = __builtin_amdgcn_mfma_f32_16x16x32_bf16(xl[s], Wh, acc, 0, 0, 0);
      acc = __builtin_amdgcn_mfma_f32_16x16x32_bf16(xh[s], Wl, acc, 0, 0, 0);
      acc = __builtin_amdgcn_mfma_f32_16x16x32_bf16(xh[s], Wh, acc, 0, 0, 0);
    }
    if (relu){
      #pragma unroll
      for (int r = 0; r < 4; ++r) acc[r] = fmaxf(acc[r], 0.f);
    }
    #pragma unroll
    for (int r = 0; r < 4; ++r)
      out[(size_t)(r0 + 4*g + r)*N + nt*16 + c16] = acc[r];
  }
}

// fused QKV MFMA GEMM (NT=24: tiles 0-7 Q, 8-15 K, 16-23 V).
__global__ __launch_bounds__(256) void k_gemm3(const float* x, const unsigned short* wf,
    const float* bq, const float* bk, const float* bv,
    float* Q, float* K2, float* V){
  int r0 = blockIdx.x * 16;
  int tid = threadIdx.x;
  int wv = tid >> 6, l = tid & 63;
  int g = l >> 4, c16 = l & 15;
  bf16x8 xh[4], xl[4];
  const f32x4* gp = (const f32x4*)x + (size_t)(r0 + c16)*32;
  #pragma unroll
  for (int s = 0; s < 4; ++s){
    f32x4 qa = gp[8*s + g], qb = gp[8*s + 4 + g];
    union { unsigned short u[8]; bf16x8 v; } uh, ul;
    #pragma unroll
    for (int m2 = 0; m2 < 4; ++m2){
      float a0 = qa[m2], b0 = qb[m2];
      uh.u[m2]   = f2h(a0); ul.u[m2]   = f2h(a0 - hif(a0));
      uh.u[4+m2] = f2h(b0); ul.u[4+m2] = f2h(b0 - hif(b0));
    }
    xh[s] = uh.v; xl[s] = ul.v;
  }
  for (int nt = wv; nt < 24; nt += 4){
    int m = nt >> 3, n = nt & 7;
    const float* bias = (m==0) ? bq : ((m==1) ? bk : bv);
    float* out = (m==0) ? Q : ((m==1) ? K2 : V);
    float bb = bias[n*16 + c16];
    f32x4 acc = {bb, bb, bb, bb};
    const unsigned short* base = wf + (size_t)m*32768;
    #pragma unroll
    for (int s = 0; s < 4; ++s){
      const unsigned short* fb = base + (size_t)((n*4 + s)*64 + l)*8;
      bf16x8 Wh = *(const bf16x8*)fb;
      bf16x8 Wl = *(const bf16x8*)(fb + 16384);
      acc = __builtin_amdgcn_mfma_f32_16x16x32_bf16(xl[s], Wh, acc, 0, 0, 0);
      acc = __builtin_amdgcn_mfma_f32_16x16x32_bf16(xh[s], Wl, acc, 0, 0, 0);
      acc = __builtin_amdgcn_mfma_f32_16x16x32_bf16(xh[s], Wh, acc, 0, 0, 0);
    }
    #pragma unroll
    for (int r = 0; r < 4; ++r)
      out[(size_t)(r0 + 4*g + r)*cH + n*16 + c16] = acc[r];
  }
}

// round-17: fused Wo1+relu+Wo2. Phase A: each wave computes 4 of the 16
// wo1 n-tiles; results (D-layout) are written split-bf16 into a 16KB LDS
// fragment buffer using the lstm-validated producer mapping (scol -> ps =
// scol>>5 in 0..7, pgf, pe; row = block row). Phase B: barrier, each wave
// reads KF=8 A-frags (HF[s][l][0..7]) and computes 2 wo2 n-tiles. Kills the
// 31MB t1 write + 31MB read and one launch; numerics identical (t1 was f32,
// wo2 re-split it to the same hi/lo pair).
__global__ __launch_bounds__(256) void k_wo12(const float* x, const unsigned short* wf1,
    const float* b1, const unsigned short* wf2, const float* b2, float* out){
  int r0 = blockIdx.x * 16;
  int tid = threadIdx.x;
  int wv = tid >> 6, l = tid & 63;
  int g = l >> 4, c16 = l & 15;
  __shared__ unsigned short HFh[8][64][8], HFl[8][64][8];   // 16 KB
  bf16x8 xh[4], xl[4];
  const f32x4* gp = (const f32x4*)x + (size_t)(r0 + c16)*32;
  #pragma unroll
  for (int s = 0; s < 4; ++s){
    f32x4 qa = gp[8*s + g], qb = gp[8*s + 4 + g];
    union { unsigned short u[8]; bf16x8 v; } uh, ul;
    #pragma unroll
    for (int m2 = 0; m2 < 4; ++m2){
      float a0 = qa[m2], b0v = qb[m2];
      uh.u[m2]   = f2h(a0);  ul.u[m2]   = f2h(a0 - hif(a0));
      uh.u[4+m2] = f2h(b0v); ul.u[4+m2] = f2h(b0v - hif(b0v));
    }
    xh[s] = uh.v; xl[s] = ul.v;
  }
  // Phase A: wo1 (+relu), tiles {wv, wv+4, wv+8, wv+12}
  #pragma unroll
  for (int q = 0; q < 4; ++q){
    int nt = wv + 4*q;
    float bb = b1[nt*16 + c16];
    f32x4 acc = {bb, bb, bb, bb};
    #pragma unroll
    for (int s = 0; s < 4; ++s){
      const unsigned short* fb = wf1 + (size_t)((nt*4 + s)*64 + l)*8;
      bf16x8 Wh = *(const bf16x8*)fb;
      bf16x8 Wl = *(const bf16x8*)(fb + 32768);
      acc = __builtin_amdgcn_mfma_f32_16x16x32_bf16(xl[s], Wh, acc, 0, 0, 0);
      acc = __builtin_amdgcn_mfma_f32_16x16x32_bf16(xh[s], Wl, acc, 0, 0, 0);
      acc = __builtin_amdgcn_mfma_f32_16x16x32_bf16(xh[s], Wh, acc, 0, 0, 0);
    }
    int scol = nt*16 + c16;
    int ps = scol >> 5, prem = scol & 31;
    int pgf = (prem >> 2) & 3;
    int pe  = ((prem >> 4) << 2) + (prem & 3);
    #pragma unroll
    for (int r = 0; r < 4; ++r){
      float z = fmaxf(acc[r], 0.f);
      HFh[ps][pgf*16 + 4*g + r][pe] = f2h(z);
      HFl[ps][pgf*16 + 4*g + r][pe] = f2h(z - hif(z));
    }
  }
  __syncthreads();
  // Phase B: wo2 (KF=8) from LDS fragments, tiles {wv, wv+4}
  bf16x8 yh[8], yl[8];
  #pragma unroll
  for (int s = 0; s < 8; ++s){
    yh[s] = *(const bf16x8*)&HFh[s][l][0];
    yl[s] = *(const bf16x8*)&HFl[s][l][0];
  }
  #pragma unroll
  for (int q = 0; q < 2; ++q){
    int nt = wv + 4*q;
    float bb = b2[nt*16 + c16];
    f32x4 acc = {bb, bb, bb, bb};
    #pragma unroll
    for (int s = 0; s < 8; ++s){
      const unsigned short* fb = wf2 + (size_t)((nt*8 + s)*64 + l)*8;
      bf16x8 Wh = *(const bf16x8*)fb;
      bf16x8 Wl = *(const bf16x8*)(fb + 32768);
      acc = __builtin_amdgcn_mfma_f32_16x16x32_bf16(yl[s], Wh, acc, 0, 0, 0);
      acc = __builtin_amdgcn_mfma_f32_16x16x32_bf16(yh[s], Wl, acc, 0, 0, 0);
      acc = __builtin_amdgcn_mfma_f32_16x16x32_bf16(yh[s], Wh, acc, 0, 0, 0);
    }
    #pragma unroll
    for (int r = 0; r < 4; ++r)
      out[(size_t)(r0 + 4*g + r)*cH + nt*16 + c16] = acc[r];
  }
}

// loc & scale heads, ROWS=16 (R10 verified).
__global__ __launch_bounds__(256) void k_heads(const float* x,
  const float* lW1, const float* lb1, const float* lg, const float* lbe, const float* lW2, const float* lb2v,
  const float* sW1, const float* sb1, const float* sg, const float* sbe, const float* sW2, const float* sb2v,
  void* outv, int q0, float* locsc, const float* maxv, const float* svp, const int* flagp){
  const int ROWS = 16;
  int r0 = blockIdx.x*ROWS;
  __shared__ float xs[ROWS][cH];
  int tid = threadIdx.x;
  for (int p = tid; p < ROWS*32; p += 256){
    int rr = p>>5, u4 = p&31;
    ((float4*)&xs[rr][0])[u4] = ((const float4*)x)[(size_t)(r0+rr)*32 + u4];
  }
  __syncthreads();
  int wv = tid >> 6, lane = tid & 63;
  int head = wv & 1;
  int rbase = (wv >> 1)*8;               // this wave's 8 rows
  const float* W1 = head ? sW1 : lW1;
  const float* b1 = head ? sb1 : lb1;
  const float* gv = head ? sg  : lg;
  const float* be = head ? sbe : lbe;
  const float* W2 = head ? sW2 : lW2;
  const float* b2 = head ? sb2v: lb2v;
  int j0 = lane, j1 = lane + 64;
  float b10 = b1[j0], b11 = b1[j1];
  float a0[8], a1[8];
  #pragma unroll
  for (int r = 0; r < 8; ++r){ a0[r] = b10; a1[r] = b11; }
  for (int i = 0; i < cH; ++i){
    float w0 = W1[i*cH + j0], w1 = W1[i*cH + j1];
    #pragma unroll
    for (int r = 0; r < 8; ++r){
      float xv = xs[rbase + r][i];
      a0[r] += xv*w0; a1[r] += xv*w1;
    }
  }
  float g0 = gv[j0], g1 = gv[j1], be0 = be[j0], be1 = be[j1];
  float w2a0 = W2[j0*2+0], w2a1 = W2[j0*2+1];
  float w2b0 = W2[j1*2+0], w2b1 = W2[j1*2+1];
  int flag = *flagp;
  float bias0 = b2[0], bias1 = b2[1];
  for (int r = 0; r < 8; ++r){
    float s = a0[r] + a1[r];
    #pragma unroll
    for (int off = 1; off < 64; off <<= 1) s += __shfl_xor(s, off);
    float mean = s*(1.f/128.f);
    float d0 = a0[r]-mean, d1 = a1[r]-mean;
    float vv = d0*d0 + d1*d1;
    #pragma unroll
    for (int off = 1; off < 64; off <<= 1) vv += __shfl_xor(vv, off);
    float inv = rsqrtf(vv*(1.f/128.f) + 1e-5f);
    float z0 = fmaxf(d0*inv*g0 + be0, 0.f);
    float z1 = fmaxf(d1*inv*g1 + be1, 0.f);
    float o0 = z0*w2a0 + z1*w2b0;
    float o1 = z0*w2a1 + z1*w2b1;
    #pragma unroll
    for (int off = 1; off < 64; off <<= 1){
      o0 += __shfl_xor(o0, off);
      o1 += __shfl_xor(o1, off);
    }
    if (lane == 0){
      int rg = r0 + rbase + r;
      int t = rg / cKN, rem = rg - t*cKN;
      int k = rem >> 7, nn = rem & 127;
      float u0 = o0 + bias0, u1 = o1 + bias1;
      if (head == 0){
        size_t oi = (((size_t)q0*cK + k)*cN + nn)*(cT*2) + t*2;
        if (flag){ ((bf16_t*)outv)[oi] = __float2bfloat16(u0); ((bf16_t*)outv)[oi+1] = __float2bfloat16(u1); }
        else     { ((float*)outv)[oi] = u0; ((float*)outv)[oi+1] = u1; }
        if (locsc){
          locsc[((size_t)t*cKN + rem)*2 + 0] = u0*maxv[nn*2+0] + svp[nn*2+0];
          locsc[((size_t)t*cKN + rem)*2 + 1] = u1*maxv[nn*2+1] + svp[nn*2+1];
        }
      } else {
        float e0 = (u0 > 0.f ? u0 : expm1f(u0)) + 1.001f;
        float e1 = (u1 > 0.f ? u1 : expm1f(u1)) + 1.001f;
        size_t oi = (((size_t)(q0+1)*cK + k)*cN + nn)*(cT*2) + t*2;
        if (flag){ ((bf16_t*)outv)[oi] = __float2bfloat16(e0); ((bf16_t*)outv)[oi+1] = __float2bfloat16(e1); }
        else     { ((float*)outv)[oi] = e0; ((float*)outv)[oi+1] = e1; }
      }
    }
  }
}

__global__ __launch_bounds__(256) void k_mask(const float* locsc, unsigned char* m){
  int st = blockIdx.x;
  int s = st / cT, t = st - s*cT;
  __shared__ float lx[cK][cNS], ly[cK][cNS];
  int tid = threadIdx.x;
  for (int p = tid; p < cK*cNS; p += 256){
    int k = p >> 5, i = p & 31;
    int row = t*cKN + k*cN + s*cNS + i;
    lx[k][i] = locsc[row*2+0];
    ly[k][i] = locsc[row*2+1];
  }
  __syncthreads();
  for (int p = tid; p < 1024; p += 256){
    int i = p >> 5, j = p & 31;
    bool any = false;
    for (int k = 0; k < cK; ++k){
      float dx = fabsf(lx[k][i]-lx[k][j]);
      float dy = fabsf(ly[k][i]-ly[k][j]);
      any = any || ((dx < 10.f) && (dy < 10.f));
    }
    m[st*1024 + p] = any ? 1 : 0;
  }
}

// MFMA attention (validated, unchanged).
__global__ __launch_bounds__(256) void k_attn(const float* Q, const float* Kx, const float* V,
                       const unsigned char* msk, float* ctx){
  int qs   = blockIdx.x;        // 0..4 : group of 8 q-tiles (2 per wave)
  int head = blockIdx.y;        // 0..3
  int st   = blockIdx.z;        // s*cT + t
  int s = st / cT, t = st - s*cT;
  __shared__ unsigned short KLh[2][1024], KLl[2][1024], VLh[2][1024], VLl[2][1024]; // 16 KB
  int tid = threadIdx.x;
  int w = tid >> 6, lane = tid & 63;
  int g = lane >> 4, col = lane & 15;
  const float scl = 0.17677669529663687f;   // 1/sqrt(32)

  unsigned int mw0 = 0, mw1 = 0;
  {
    const unsigned int* mr0 = (const unsigned int*)(msk + st*1024 + col*32);
    const unsigned int* mr1 = (const unsigned int*)(msk + st*1024 + (16+col)*32);
    #pragma unroll
    for (int j2 = 0; j2 < 8; ++j2){
      mw0 |= (((mr0[j2] * 0x01020408u) >> 24) & 0xFu) << (4*j2);
      mw1 |= (((mr1[j2] * 0x01020408u) >> 24) & 0xFu) << (4*j2);
    }
  }

  bf16x8 Qh[2], Ql[2];
  int modes[2], ahs[2];
  #pragma unroll
  for (int i = 0; i < 2; ++i){
    int tt = qs*8 + 4*i + w;       // 0..39
    int mode = tt >> 1, ah = tt & 1;
    modes[i] = mode; ahs[i] = ah;
    int qrow = t*cKN + mode*cN + s*cNS + ah*16 + col;
    const f32x4* qp = (const f32x4*)Q + (size_t)qrow*32 + head*8;
    f32x4 qa = qp[g], qb = qp[4+g];
    union { unsigned short u[8]; bf16x8 v; } uh, ul;
    #pragma unroll
    for (int m = 0; m < 4; ++m){
      float x0 = qa[m]*scl;
      uh.u[m] = f2h(x0);
      ul.u[m] = f2h(x0 - hif(x0));
      float x1 = qb[m]*scl;
      uh.u[4+m] = f2h(x1);
      ul.u[4+m] = f2h(x1 - hif(x1));
    }
    Qh[i] = uh.v; Ql[i] = ul.v;
  }

  int kk = tid >> 3, f4 = tid & 7;
  int kwi = (((kk>>4)*4 + (f4&3))*16 + (kk&15))*8 + (f4>>2)*4;
  int vd = tid & 31, quad = tid >> 5;
  int vkey = (quad>>2)*16 + (quad&3)*4;
  int vwi = (((vd>>4)*4 + (quad&3))*16 + (vd&15))*8 + (quad>>2)*4;

  const size_t cstepK = (size_t)cN*32;
  const size_t cstepV = (size_t)cN*128;
  const float4* kptr = (const float4*)Kx + ((size_t)(t*cKN + s*cNS + kk))*32 + head*8 + f4;
  const float*  vptr = V + ((size_t)(t*cKN + s*cNS + vkey))*128 + head*32 + vd;

  float4 kv; float vm0, vm1, vm2, vm3;
  kv = *kptr; kptr += cstepK;
  vm0 = vptr[0]; vm1 = vptr[128]; vm2 = vptr[256]; vm3 = vptr[384]; vptr += cstepV;
  {
    unsigned int h0 = (unsigned int)f2h(kv.x) | ((unsigned int)f2h(kv.y)<<16);
    unsigned int h1 = (unsigned int)f2h(kv.z) | ((unsigned int)f2h(kv.w)<<16);
    float r0 = kv.x-hif(kv.x), r1 = kv.y-hif(kv.y), r2 = kv.z-hif(kv.z), r3 = kv.w-hif(kv.w);
    unsigned int l0 = (unsigned int)f2h(r0) | ((unsigned int)f2h(r1)<<16);
    unsigned int l1 = (unsigned int)f2h(r2) | ((unsigned int)f2h(r3)<<16);
    *(uint2*)&KLh[0][kwi] = make_uint2(h0,h1);
    *(uint2*)&KLl[0][kwi] = make_uint2(l0,l1);
    unsigned int vh0 = (unsigned int)f2h(vm0) | ((unsigned int)f2h(vm1)<<16);
    unsigned int vh1 = (unsigned int)f2h(vm2) | ((unsigned int)f2h(vm3)<<16);
    float s0 = vm0-hif(vm0), s1 = vm1-hif(vm1), s2 = vm2-hif(vm2), s3 = vm3-hif(vm3);
    unsigned int vl0 = (unsigned int)f2h(s0) | ((unsigned int)f2h(s1)<<16);
    unsigned int vl1 = (unsigned int)f2h(s2) | ((unsigned int)f2h(s3)<<16);
    *(uint2*)&VLh[0][vwi] = make_uint2(vh0,vh1);
    *(uint2*)&VLl[0][vwi] = make_uint2(vl0,vl1);
  }
  __syncthreads();

  const f32x4 Z = {0.f, 0.f, 0.f, 0.f};
  f32x4 O[2][2] = {{Z, Z}, {Z, Z}};
  float lac[2] = {0.f, 0.f};

  for (int ch = 0; ch < 20; ++ch){
    int par = ch & 1;
    if (ch < 19){
      kv = *kptr; kptr += cstepK;
      vm0 = vptr[0]; vm1 = vptr[128]; vm2 = vptr[256]; vm3 = vptr[384]; vptr += cstepV;
    }
    bf16x8 KAh0 = *(const bf16x8*)&KLh[par][( g      *16 + col)*8];
    bf16x8 KAl0 = *(const bf16x8*)&KLl[par][( g      *16 + col)*8];
    bf16x8 KAh1 = *(const bf16x8*)&KLh[par][((4 + g) *16 + col)*8];
    bf16x8 KAl1 = *(const bf16x8*)&KLl[par][((4 + g) *16 + col)*8];
    bf16x8 VBh0 = *(const bf16x8*)&VLh[par][( g      *16 + col)*8];
    bf16x8 VBl0 = *(const bf16x8*)&VLl[par][( g      *16 + col)*8];
    bf16x8 VBh1 = *(const bf16x8*)&VLh[par][((4 + g) *16 + col)*8];
    bf16x8 VBl1 = *(const bf16x8*)&VLl[par][((4 + g) *16 + col)*8];
    #pragma unroll
    for (int i = 0; i < 2; ++i){
      f32x4 sa = Z, sb = Z;
      sa = __builtin_amdgcn_mfma_f32_16x16x32_bf16(KAl0, Qh[i], sa, 0, 0, 0);
      sa = __builtin_amdgcn_mfma_f32_16x16x32_bf16(KAh0, Ql[i], sa, 0, 0, 0);
      sa = __builtin_amdgcn_mfma_f32_16x16x32_bf16(KAh0, Qh[i], sa, 0, 0, 0);
      sb = __builtin_amdgcn_mfma_f32_16x16x32_bf16(KAl1, Qh[i], sb, 0, 0, 0);
      sb = __builtin_amdgcn_mfma_f32_16x16x32_bf16(KAh1, Ql[i], sb, 0, 0, 0);
      sb = __builtin_amdgcn_mfma_f32_16x16x32_bf16(KAh1, Qh[i], sb, 0, 0, 0);
      unsigned int mw = ahs[i] ? mw1 : mw0;
      float p[8];
      #pragma unroll
      for (int r = 0; r < 4; ++r){
        float e0 = __expf(sa[r]);
        float e1 = __expf(sb[r]);
        p[r]   = ((mw >> (4*g + r)) & 1)        ? e0 : 0.f;
        p[4+r] = ((mw >> (16 + 4*g + r)) & 1)   ? e1 : 0.f;
      }
      lac[i] += ((p[0]+p[1])+(p[2]+p[3])) + ((p[4]+p[5])+(p[6]+p[7]));
      union { unsigned short u[8]; bf16x8 v; } Ph, Pl;
      #pragma unroll
      for (int e = 0; e < 8; ++e){
        Ph.u[e] = f2h(p[e]);
        Pl.u[e] = f2h(p[e] - hif(p[e]));
      }
      O[i][0] = __builtin_amdgcn_mfma_f32_16x16x32_bf16(Pl.v, VBh0, O[i][0], 0, 0, 0);
      O[i][0] = __builtin_amdgcn_mfma_f32_16x16x32_bf16(Ph.v, VBl0, O[i][0], 0, 0, 0);
      O[i][0] = __builtin_amdgcn_mfma_f32_16x16x32_bf16(Ph.v, VBh0, O[i][0], 0, 0, 0);
      O[i][1] = __builtin_amdgcn_mfma_f32_16x16x32_bf16(Pl.v, VBh1, O[i][1], 0, 0, 0);
      O[i][1] = __builtin_amdgcn_mfma_f32_16x16x32_bf16(Ph.v, VBl1, O[i][1], 0, 0, 0);
      O[i][1] = __builtin_amdgcn_mfma_f32_16x16x32_bf16(Ph.v, VBh1, O[i][1], 0, 0, 0);
    }
    __syncthreads();   // all frag reads of [par] done
    if (ch < 19){
      int nb = 1 - par;
      unsigned int h0 = (unsigned int)f2h(kv.x) | ((unsigned int)f2h(kv.y)<<16);
      unsigned int h1 = (unsigned int)f2h(kv.z) | ((unsigned int)f2h(kv.w)<<16);
      float r0 = kv.x-hif(kv.x), r1 = kv.y-hif(kv.y), r2 = kv.z-hif(kv.z), r3 = kv.w-hif(kv.w);
      unsigned int l0 = (unsigned int)f2h(r0) | ((unsigned int)f2h(r1)<<16);
      unsigned int l1 = (unsigned int)f2h(r2) | ((unsigned int)f2h(r3)<<16);
      *(uint2*)&KLh[nb][kwi] = make_uint2(h0,h1);
      *(uint2*)&KLl[nb][kwi] = make_uint2(l0,l1);
      unsigned int vh0 = (unsigned int)f2h(vm0) | ((unsigned int)f2h(vm1)<<16);
      unsigned int vh1 = (unsigned int)f2h(vm2) | ((unsigned int)f2h(vm3)<<16);
      float s0 = vm0-hif(vm0), s1 = vm1-hif(vm1), s2 = vm2-hif(vm2), s3 = vm3-hif(vm3);
      unsigned int vl0 = (unsigned int)f2h(s0) | ((unsigned int)f2h(s1)<<16);
      unsigned int vl1 = (unsigned int)f2h(s2) | ((unsigned int)f2h(s3)<<16);
      *(uint2*)&VLh[nb][vwi] = make_uint2(vh0,vh1);
      *(uint2*)&VLl[nb][vwi] = make_uint2(vl0,vl1);
    }
    __syncthreads();   // next buffer visible
  }

  #pragma unroll
  for (int i = 0; i < 2; ++i){
    float lsum = lac[i];
    lsum += __shfl_xor(lsum, 16);
    lsum += __shfl_xor(lsum, 32);
    int base = t*cKN + modes[i]*cN + s*cNS + ahs[i]*16;
    #pragma unroll
    for (int r = 0; r < 4; ++r){
      float lq = __shfl(lsum, 4*g + r);
      float rinv = 1.f / lq;
      float* cp = ctx + (size_t)(base + 4*g + r)*cH + head*cHD;
      cp[col]      = O[i][0][r] * rinv;
      cp[col+16]   = O[i][1][r] * rinv;
    }
  }
}

extern "C" void kernel_launch(void* const* d_in, const int* in_sizes, int n_in,
                              void* d_out, int out_size, void* d_ws, size_t ws_size,
                              hipStream_t stream){
  (void)in_sizes; (void)n_in; (void)out_size; (void)ws_size;

  int*   flagp = (int*)d_ws;
  float* conv  = (float*)d_ws + 64;
  float* big   = (float*)d_ws + 978112;

  const float* ge_f   = conv + 0;
  const float* hs_f   = conv + 196608;
  const float* cn_f   = conv + 212992;
  const float* sv_f   = conv + 229376;
  const float* mx_f   = conv + 229632;
  const float* mhpW_f = conv + 229888;
  const float* mhpb_f = conv + 557568;
  const float* mhpg_f = conv + 560128;
  const float* mhpbe_f= conv + 562688;
  const float* l1Wih_f= conv + 565248;
  const float* l1Whh_f= conv + 630784;
  const float* l1b_f  = conv + 696320;
  const float* l2Wih_f= conv + 696832;
  const float* l2Whh_f= conv + 762368;
  const float* l2b_f  = conv + 827904;
  const float* Wq_f   = conv + 828416;
  const float* bq_f   = conv + 844800;
  const float* Wk_f   = conv + 844928;
  const float* bk_f   = conv + 861312;
  const float* Wv_f   = conv + 861440;
  const float* bv_f   = conv + 877824;
  const float* Wo1_f  = conv + 877952;
  const float* bo1_f  = conv + 910720;
  const float* Wo2_f  = conv + 910976;
  const float* bo2_f  = conv + 943744;
  const float* locW1_f= conv + 943872;
  const float* locb1_f= conv + 960256;
  const float* locg_f = conv + 960384;
  const float* locbe_f= conv + 960512;
  const float* locW2_f= conv + 960640;
  const float* locb2_f= conv + 960896;
  const float* sclW1_f= conv + 960960;
  const float* sclb1_f= conv + 977344;
  const float* sclg_f = conv + 977472;
  const float* sclbe_f= conv + 977600;
  const float* sclW2_f= conv + 977728;
  const float* sclb2_f= conv + 977984;

  const size_t SLOT = (size_t)cT*cKN*cH;
  float* geb = big;
  float* o1b = big + SLOT;
  float* Qb  = big + 2*SLOT;
  float* Kb  = big + 3*SLOT;
  float* Vb  = big + 4*SLOT;
  float* locsc = big + 5*SLOT;
  unsigned char* maskb = (unsigned char*)(locsc + (size_t)cT*cKN*2);
  float* social = Vb;    // overlays V after attention

  // LSTM weight fragments overlay the mhp_W region (dead after k_wprep3)
  unsigned short* wfrag = (unsigned short*)(conv + 229888);
  unsigned short* uA = (unsigned short*)(conv + 565248);
  unsigned short* uB = (unsigned short*)(conv + 696832);
  // mhp weight fragments + raw-y temp live in Qb/Kb slots (dead until k_gemm3)
  unsigned short* mfrag = (unsigned short*)(big + 2*SLOT);
  float* ytmp = big + 3*SLOT;    // 1536*2560 = exactly one SLOT

  Ptrs ptrs;
  for (int i = 0; i < 37; ++i) ptrs.p[i] = d_in[i];

  k_detect<<<1, 64, 0, stream>>>((const unsigned short*)d_in[0], flagp, (unsigned int*)d_out);
  k_convert<<<(CONV_TOTAL+255)/256, 256, 0, stream>>>(ptrs, flagp, conv);
  k_wprep3<<<160, 256, 0, stream>>>(mhpW_f, mfrag);
  {
    dim3 mg(96, 5);   // 480 blocks, 32 n-tiles each
    k_gemm<4><<<mg, 256, 0, stream>>>(ge_f, mfrag, mhpb_f, ytmp, 160, 2560, 0, 327680, 32);
  }
  k_mhp_ln<<<1536, 256, 0, stream>>>(ytmp, mhpg_f, mhpbe_f, geb);
  k_wprep<<<128, 256, 0, stream>>>(l1Wih_f, l1Whh_f, l2Wih_f, l2Whh_f, wfrag);
  k_wprep2<<<56, 256, 0, stream>>>(Wq_f, Wk_f, Wv_f, Wo1_f, Wo2_f, uA, uB);
  k_lstm_mfma<<<160, 512, 0, stream>>>(geb, o1b, hs_f, cn_f, (const float*)0,
                                       wfrag + 0, wfrag + 131072, l1b_f, 1);
  k_heads<<<cT*cKN/16, 256, 0, stream>>>(o1b, locW1_f,locb1_f,locg_f,locbe_f,locW2_f,locb2_f,
                                        sclW1_f,sclb1_f,sclg_f,sclbe_f,sclW2_f,sclb2_f,
                                        d_out, 0, locsc, mx_f, sv_f, flagp);
  k_mask<<<cS*cT, 256, 0, stream>>>(locsc, maskb);
  k_gemm3<<<cT*cKN/16, 256, 0, stream>>>(o1b, uA, bq_f, bk_f, bv_f, Qb, Kb, Vb);
  {
    dim3 ag(5, 4, cS*cT);
    k_attn<<<ag, 256, 0, stream>>>(Qb, Kb, Vb, maskb, o1b);   // ctx overlays out1
  }
  k_wo12<<<cT*cKN/16, 256, 0, stream>>>(o1b, uA + 98304, bo1_f, uB, bo2_f, social);
  k_lstm_mfma<<<160, 512, 0, stream>>>(geb, o1b, hs_f, cn_f, social,
                                       wfrag + 262144, wfrag + 393216, l2b_f, 2);
  k_heads<<<cT*cKN/16, 256, 0, stream>>>(o1b, locW1_f,locb1_f,locg_f,locbe_f,locW2_f,locb2_f,
                                        sclW1_f,sclb1_f,sclg_f,sclbe_f,sclW2_f,sclb2_f,
                                        d_out, 2, (float*)0, mx_f, sv_f, flagp);
}

// Round 12
// 560.847 us; speedup vs baseline: 1.3887x; 1.0426x over previous
//
#include <hip/hip_runtime.h>
#include <hip/hip_bf16.h>

typedef __hip_bfloat16 bf16_t;

static const int cT  = 12;    // future steps
static const int cN  = 128;   // agents
static const int cH  = 128;   // hidden
static const int cK  = 20;    // modes
static const int cKN = 2560;  // cK*cN
static const int cS  = 4;     // batch split
static const int cNS = 32;    // agents per scene
static const int cL  = 640;   // cK*cNS attention length
static const int cHD = 32;    // head dim

#define CONV_TOTAL 977986

__constant__ int c_off[38] = {0,196608,212992,229376,229632,229888,557568,560128,562688,
  565248,630784,696320,696832,762368,827904,828416,844800,844928,861312,861440,877824,
  877952,910720,910976,943744,943872,960256,960384,960512,960640,960896,960960,977344,
  977472,977600,977728,977984,977986};
__constant__ int c_len[37] = {196608,16384,16384,256,256,327680,2560,2560,2560,
  65536,65536,512,65536,65536,512,16384,128,16384,128,16384,128,
  32768,256,32768,128,16384,128,128,128,256,2,16384,128,128,128,256,2};

struct Ptrs { const void* p[37]; };

typedef __attribute__((ext_vector_type(4))) float f32x4;
typedef __attribute__((ext_vector_type(8))) __bf16 bf16x8;

__device__ __forceinline__ float sigm(float x){ return 1.f/(1.f+expf(-x)); }
__device__ __forceinline__ unsigned short f2h(float x){ return (unsigned short)(__float_as_uint(x)>>16); }
__device__ __forceinline__ float hif(float x){ return __uint_as_float(__float_as_uint(x)&0xFFFF0000u); }

// dtype sniffing + NaN canary
__global__ __launch_bounds__(256) void k_detect(const unsigned short* ge_u16, int* flagp, unsigned int* outw){
  __shared__ int cnt;
  if (threadIdx.x == 0) cnt = 0;
  __syncthreads();
  int ok = 0;
  for (int i = threadIdx.x; i < 128; i += 64){
    unsigned short u = ge_u16[2*i];
    int ex = (u >> 7) & 0xFF;
    if (ex >= 100 && ex <= 140) ok++;
  }
  atomicAdd(&cnt, ok);
  __syncthreads();
  if (threadIdx.x == 0){
    *flagp = (cnt >= 96) ? 1 : 0;
    outw[0] = 0x7FC07FC0u;
  }
}

// convert all 37 inputs to fp32 into the conv region
__global__ __launch_bounds__(256) void k_convert(Ptrs ptrs, const int* flagp, float* dst){
  int g = blockIdx.x*256 + threadIdx.x;
  if (g >= CONV_TOTAL) return;
  int flag = *flagp;
  int seg = 0;
  while (seg < 36 && g >= c_off[seg+1]) ++seg;
  int local = g - c_off[seg];
  if (local >= c_len[seg]) return;
  float v;
  if (flag) v = __bfloat162float(((const bf16_t*)ptrs.p[seg])[local]);
  else      v = ((const float*)ptrs.p[seg])[local];
  dst[g] = v;
}

// preconvert mhp_W [128][2560] into fragment order (NT=160, KF=4).
__global__ __launch_bounds__(256) void k_wprep3(const float* W, unsigned short* out){
  int idx = blockIdx.x*256 + threadIdx.x;   // 40960 = 160 tiles * 4 s * 64 l
  int l = idx & 63;
  int rest = idx >> 6;
  int s = rest & 3;
  int n = rest >> 2;                        // 0..159
  int g = l >> 4, c16 = l & 15;
  unsigned short hi[8], lo[8];
  #pragma unroll
  for (int e = 0; e < 8; ++e){
    int k = 32*s + 16*(e>>2) + 4*g + (e&3);
    float v = W[k*2560 + 16*n + c16];
    hi[e] = f2h(v); lo[e] = f2h(v - hif(v));
  }
  size_t base = (size_t)idx*8;              // == ((n*4+s)*64+l)*8
  *(uint4*)&out[base]          = *(const uint4*)hi;
  *(uint4*)&out[base + 327680] = *(const uint4*)lo;
}

// LN_2560 + relu + permute pass over the MFMA-produced y.
__global__ __launch_bounds__(256) void k_mhp_ln(const float* y, const float* g,
                      const float* be, float* out){
  int row = blockIdx.x;                     // 0..1535 (= t*128+nn)
  int tid = threadIdx.x;
  __shared__ float red[256];
  float v[10];
  const float* yr = y + (size_t)row*2560;
  #pragma unroll
  for (int m = 0; m < 10; ++m) v[m] = yr[tid + 256*m];
  float ps = 0.f;
  #pragma unroll
  for (int m = 0; m < 10; ++m) ps += v[m];
  red[tid] = ps; __syncthreads();
  for (int s2 = 128; s2 > 0; s2 >>= 1){
    if (tid < s2) red[tid] += red[tid+s2];
    __syncthreads();
  }
  float mean = red[0]*(1.f/2560.f);
  __syncthreads();
  float pv = 0.f;
  #pragma unroll
  for (int m = 0; m < 10; ++m){ float d = v[m]-mean; pv += d*d; }
  red[tid] = pv; __syncthreads();
  for (int s2 = 128; s2 > 0; s2 >>= 1){
    if (tid < s2) red[tid] += red[tid+s2];
    __syncthreads();
  }
  float inv = rsqrtf(red[0]*(1.f/2560.f) + 1e-5f);
  int t = row >> 7, nn = row & 127;
  #pragma unroll
  for (int m = 0; m < 10; ++m){
    int col = tid + 256*m;
    float z = (v[m]-mean)*inv*g[col] + be[col];
    z = fmaxf(z, 0.f);
    int k = col >> 7, hh2 = col & 127;
    out[((t*cKN) + k*cN + nn)*cH + hh2] = z;
  }
}

// preconvert the 4 LSTM weight matrices into fragment order.
// NOTE: must launch AFTER k_wprep3 has read mhp_W.
__global__ __launch_bounds__(256) void k_wprep(const float* w0, const float* w1,
    const float* w2, const float* w3, unsigned short* out){
  int idx = blockIdx.x*256 + threadIdx.x;   // 32768 total
  int m = idx >> 13;
  int rest = idx & 8191;
  int n = rest >> 8;
  int s = (rest >> 6) & 3;
  int l = rest & 63;
  int g = l >> 4, c16 = l & 15;
  const float* W = (m==0) ? w0 : ((m==1) ? w1 : ((m==2) ? w2 : w3));
  unsigned short hi[8], lo[8];
  #pragma unroll
  for (int e = 0; e < 8; ++e){
    int k = 32*s + 16*(e>>2) + 4*g + (e&3);
    float v = W[k*512 + 16*n + c16];
    hi[e] = f2h(v); lo[e] = f2h(v - hif(v));
  }
  size_t base = (size_t)m*131072 + (size_t)((n*4 + s)*64 + l)*8;
  *(uint4*)&out[base]         = *(const uint4*)hi;
  *(uint4*)&out[base + 65536] = *(const uint4*)lo;
}

// preconvert Wq/Wk/Wv/Wo1/Wo2 + locW1/sclW1 into fragment order.
// uA layout (ushorts): Wq@0, Wk@32768, Wv@65536, Wo1@98304(+32768x2),
// locW1@163840, sclW1@196608 (ends 229376 <= 262144; l1b untouched).
// Must run AFTER k_wprep (uA overlays l1Wih/l1Whh which wprep reads).
__global__ __launch_bounds__(256) void k_wprep2(const float* wq, const float* wk,
    const float* wv, const float* wo1, const float* wo2,
    const float* lw1, const float* sw1,
    unsigned short* outA, unsigned short* outB){
  int idx = blockIdx.x*256 + threadIdx.x;   // 18432 total
  if (idx >= 18432) return;
  const float* W; int KF, N, local, half; unsigned short* out; size_t off;
  if (idx < 2048)      { W=wq;  KF=4; N=128; off=0;      local=idx;       half=16384; out=outA; }
  else if (idx < 4096) { W=wk;  KF=4; N=128; off=32768;  local=idx-2048;  half=16384; out=outA; }
  else if (idx < 6144) { W=wv;  KF=4; N=128; off=65536;  local=idx-4096;  half=16384; out=outA; }
  else if (idx < 10240){ W=wo1; KF=4; N=256; off=98304;  local=idx-6144;  half=32768; out=outA; }
  else if (idx < 14336){ W=wo2; KF=8; N=128; off=0;      local=idx-10240; half=32768; out=outB; }
  else if (idx < 16384){ W=lw1; KF=4; N=128; off=163840; local=idx-14336; half=16384; out=outA; }
  else                 { W=sw1; KF=4; N=128; off=196608; local=idx-16384; half=16384; out=outA; }
  int l = local & 63;
  int rest = local >> 6;
  int s = rest & (KF-1);
  int n = (KF == 8) ? (rest >> 3) : (rest >> 2);
  int g = l >> 4, c16 = l & 15;
  unsigned short hi[8], lo[8];
  #pragma unroll
  for (int e = 0; e < 8; ++e){
    int k = 32*s + 16*(e>>2) + 4*g + (e&3);
    float v = W[k*N + 16*n + c16];
    hi[e] = f2h(v); lo[e] = f2h(v - hif(v));
  }
  size_t base = off + (size_t)local*8;
  *(uint4*)&out[base]        = *(const uint4*)hi;
  *(uint4*)&out[base + half] = *(const uint4*)lo;
}

// MFMA LSTM (R9 verified version, unchanged; frozen).
__global__ __launch_bounds__(512) void k_lstm_mfma(const float* ge, float* outh,
    const float* hs0, const float* cn0, const float* soc,
    const unsigned short* wfA, const unsigned short* wfB,
    const float* bias, int phase){
  int r0 = blockIdx.x * 16;
  int tid = threadIdx.x;
  int w = tid >> 6, l = tid & 63;
  int g = l >> 4, c16 = l & 15;
  int scol = w*16 + c16;                 // state col owned by this lane
  __shared__ unsigned short HFh[2][4][64][8], HFl[2][4][64][8];   // 16 KB
  int ps = scol >> 5, prem = scol & 31;
  int pgf = (prem >> 2) & 3;
  int pe  = ((prem >> 4) << 2) + (prem & 3);
  float c[4], h[4];
  #pragma unroll
  for (int r = 0; r < 4; ++r){
    int nn = (r0 + 4*g + r) & 127;
    c[r] = cn0[nn*cH + scol];
    h[r] = hs0[nn*cH + scol];
  }
  float bias_t[4];
  #pragma unroll
  for (int tt = 0; tt < 4; ++tt) bias_t[tt] = bias[tt*128 + scol];

  f32x4 xr[8];
  float socr[4] = {0.f, 0.f, 0.f, 0.f};
  {
    const f32x4* gp = (const f32x4*)ge + ((size_t)(r0 + c16))*32;
    #pragma unroll
    for (int s = 0; s < 4; ++s){ xr[2*s] = gp[8*s + g]; xr[2*s+1] = gp[8*s + 4 + g]; }
    if (phase == 2){
      #pragma unroll
      for (int r = 0; r < 4; ++r)
        socr[r] = soc[(size_t)(r0 + 4*g + r)*cH + scol];
    }
  }

  for (int t = 0; t < cT; ++t){
    int b = t & 1;
    if (phase == 2){
      #pragma unroll
      for (int r = 0; r < 4; ++r){
        c[r] += socr[r];
        h[r] += tanhf(c[r]);
      }
    }
    #pragma unroll
    for (int r = 0; r < 4; ++r){
      HFh[b][ps][pgf*16 + 4*g + r][pe] = f2h(h[r]);
      HFl[b][ps][pgf*16 + 4*g + r][pe] = f2h(h[r] - hif(h[r]));
    }
    bf16x8 xh[4], xl[4];
    #pragma unroll
    for (int s = 0; s < 4; ++s){
      union { unsigned short u[8]; bf16x8 v; } uh, ul;
      #pragma unroll
      for (int m2 = 0; m2 < 4; ++m2){
        float a0 = xr[2*s][m2], b0 = xr[2*s+1][m2];
        uh.u[m2]   = f2h(a0); ul.u[m2]   = f2h(a0 - hif(a0));
        uh.u[4+m2] = f2h(b0); ul.u[4+m2] = f2h(b0 - hif(b0));
      }
      xh[s] = uh.v; xl[s] = ul.v;
    }
    if (t < cT-1){
      const f32x4* gp = (const f32x4*)ge + ((size_t)(t+1)*cKN + r0 + c16)*32;
      #pragma unroll
      for (int s = 0; s < 4; ++s){ xr[2*s] = gp[8*s + g]; xr[2*s+1] = gp[8*s + 4 + g]; }
      if (phase == 2){
        #pragma unroll
        for (int r = 0; r < 4; ++r)
          socr[r] = soc[(size_t)(t+1)*cKN*cH + (size_t)(r0 + 4*g + r)*cH + scol];
      }
    }
    __syncthreads();                      // HF[b] visible (single barrier/step)
    bf16x8 hh[4], hl[4];
    #pragma unroll
    for (int s = 0; s < 4; ++s){
      hh[s] = *(const bf16x8*)&HFh[b][s][l][0];
      hl[s] = *(const bf16x8*)&HFl[b][s][l][0];
    }
    f32x4 a4[4];
    #pragma unroll
    for (int tt = 0; tt < 4; ++tt){
      f32x4 acc = {bias_t[tt], bias_t[tt], bias_t[tt], bias_t[tt]};
      a4[tt] = acc;
    }
    {
      bf16x8 cAh, cAl, cBh, cBl, nAh, nAl, nBh, nBl;
      {
        size_t fo = (size_t)((w*4 + 0)*64 + l)*8;   // tt=0, s=0
        cAh = *(const bf16x8*)&wfA[fo];
        cAl = *(const bf16x8*)&wfA[65536 + fo];
        cBh = *(const bf16x8*)&wfB[fo];
        cBl = *(const bf16x8*)&wfB[65536 + fo];
      }
      #pragma unroll
      for (int j = 0; j < 16; ++j){
        int s = j >> 2, tt = j & 3;
        if (j < 15){
          int j2 = j + 1;
          int s2 = j2 >> 2, tt2 = j2 & 3;
          size_t fo = (size_t)(((w + 8*tt2)*4 + s2)*64 + l)*8;
          nAh = *(const bf16x8*)&wfA[fo];
          nAl = *(const bf16x8*)&wfA[65536 + fo];
          nBh = *(const bf16x8*)&wfB[fo];
          nBl = *(const bf16x8*)&wfB[65536 + fo];
        }
        f32x4 acc = a4[tt];
        acc = __builtin_amdgcn_mfma_f32_16x16x32_bf16(xl[s], cAh, acc, 0, 0, 0);
        acc = __builtin_amdgcn_mfma_f32_16x16x32_bf16(xh[s], cAl, acc, 0, 0, 0);
        acc = __builtin_amdgcn_mfma_f32_16x16x32_bf16(xh[s], cAh, acc, 0, 0, 0);
        acc = __builtin_amdgcn_mfma_f32_16x16x32_bf16(hl[s], cBh, acc, 0, 0, 0);
        acc = __builtin_amdgcn_mfma_f32_16x16x32_bf16(hh[s], cBl, acc, 0, 0, 0);
        acc = __builtin_amdgcn_mfma_f32_16x16x32_bf16(hh[s], cBh, acc, 0, 0, 0);
        a4[tt] = acc;
        cAh = nAh; cAl = nAl; cBh = nBh; cBl = nBl;
      }
    }
    #pragma unroll
    for (int r = 0; r < 4; ++r){
      float ig = sigm(a4[0][r]), fg = sigm(a4[1][r]);
      float gg = tanhf(a4[2][r]), og = sigm(a4[3][r]);
      c[r] = fg*c[r] + ig*gg;
      h[r] = og*tanhf(c[r]);
      outh[(size_t)t*cKN*cH + (size_t)(r0 + 4*g + r)*cH + scol] = h[r];
    }
  }
}

// generic MFMA GEMM with NT chunking via blockIdx.y.
template<int KF>
__global__ __launch_bounds__(256) void k_gemm(const float* x, const unsigned short* wf,
    const float* bias, float* out, int NT, int N, int relu, int half, int ntc){
  int r0 = blockIdx.x * 16;
  int nt0 = blockIdx.y * ntc;
  int ntEnd = nt0 + ntc; if (ntEnd > NT) ntEnd = NT;
  int tid = threadIdx.x;
  int wv = tid >> 6, l = tid & 63;
  int g = l >> 4, c16 = l & 15;
  bf16x8 xh[KF], xl[KF];
  const f32x4* gp = (const f32x4*)x + (size_t)(r0 + c16)*(KF*8);
  #pragma unroll
  for (int s = 0; s < KF; ++s){
    f32x4 qa = gp[8*s + g], qb = gp[8*s + 4 + g];
    union { unsigned short u[8]; bf16x8 v; } uh, ul;
    #pragma unroll
    for (int m2 = 0; m2 < 4; ++m2){
      float a0 = qa[m2], b0 = qb[m2];
      uh.u[m2]   = f2h(a0); ul.u[m2]   = f2h(a0 - hif(a0));
      uh.u[4+m2] = f2h(b0); ul.u[4+m2] = f2h(b0 - hif(b0));
    }
    xh[s] = uh.v; xl[s] = ul.v;
  }
  for (int nt = nt0 + wv; nt < ntEnd; nt += 4){
    float bb = bias[nt*16 + c16];
    f32x4 acc = {bb, bb, bb, bb};
    #pragma unroll
    for (int s = 0; s < KF; ++s){
      const unsigned short* fb = wf + (size_t)((nt*KF + s)*64 + l)*8;
      bf16x8 Wh = *(const bf16x8*)fb;
      bf16x8 Wl = *(const bf16x8*)(fb + half);
      acc = __builtin_amdgcn_mfma_f32_16x16x32_bf16(xl[s], Wh, acc, 0, 0, 0);
      acc = __builtin_amdgcn_mfma_f32_16x16x32_bf16(xh[s], Wl, acc, 0, 0, 0);
      acc = __builtin_amdgcn_mfma_f32_16x16x32_bf16(xh[s], Wh, acc, 0, 0, 0);
    }
    if (relu){
      #pragma unroll
      for (int r = 0; r < 4; ++r) acc[r] = fmaxf(acc[r], 0.f);
    }
    #pragma unroll
    for (int r = 0; r < 4; ++r)
      out[(size_t)(r0 + 4*g + r)*N + nt*16 + c16] = acc[r];
  }
}

// fused QKV MFMA GEMM (NT=24: tiles 0-7 Q, 8-15 K, 16-23 V).
__global__ __launch_bounds__(256) void k_gemm3(const float* x, const unsigned short* wf,
    const float* bq, const float* bk, const float* bv,
    float* Q, float* K2, float* V){
  int r0 = blockIdx.x * 16;
  int tid = threadIdx.x;
  int wv = tid >> 6, l = tid & 63;
  int g = l >> 4, c16 = l & 15;
  bf16x8 xh[4], xl[4];
  const f32x4* gp = (const f32x4*)x + (size_t)(r0 + c16)*32;
  #pragma unroll
  for (int s = 0; s < 4; ++s){
    f32x4 qa = gp[8*s + g], qb = gp[8*s + 4 + g];
    union { unsigned short u[8]; bf16x8 v; } uh, ul;
    #pragma unroll
    for (int m2 = 0; m2 < 4; ++m2){
      float a0 = qa[m2], b0 = qb[m2];
      uh.u[m2]   = f2h(a0); ul.u[m2]   = f2h(a0 - hif(a0));
      uh.u[4+m2] = f2h(b0); ul.u[4+m2] = f2h(b0 - hif(b0));
    }
    xh[s] = uh.v; xl[s] = ul.v;
  }
  for (int nt = wv; nt < 24; nt += 4){
    int m = nt >> 3, n = nt & 7;
    const float* bias = (m==0) ? bq : ((m==1) ? bk : bv);
    float* out = (m==0) ? Q : ((m==1) ? K2 : V);
    float bb = bias[n*16 + c16];
    f32x4 acc = {bb, bb, bb, bb};
    const unsigned short* base = wf + (size_t)m*32768;
    #pragma unroll
    for (int s = 0; s < 4; ++s){
      const unsigned short* fb = base + (size_t)((n*4 + s)*64 + l)*8;
      bf16x8 Wh = *(const bf16x8*)fb;
      bf16x8 Wl = *(const bf16x8*)(fb + 16384);
      acc = __builtin_amdgcn_mfma_f32_16x16x32_bf16(xl[s], Wh, acc, 0, 0, 0);
      acc = __builtin_amdgcn_mfma_f32_16x16x32_bf16(xh[s], Wl, acc, 0, 0, 0);
      acc = __builtin_amdgcn_mfma_f32_16x16x32_bf16(xh[s], Wh, acc, 0, 0, 0);
    }
    #pragma unroll
    for (int r = 0; r < 4; ++r)
      out[(size_t)(r0 + 4*g + r)*cH + n*16 + c16] = acc[r];
  }
}

// round-18: heads W1 GEMM via MFMA (clone of k_gemm3 pattern). NT=16:
// tiles 0-7 = loc W1, 8-15 = scl W1. Output y[row][256] (loc cols 0-127,
// scl cols 128-255) into the dead Qb..Kb span.
__global__ __launch_bounds__(256) void k_heads_gemm(const float* x, const unsigned short* wf,
    const float* bl, const float* bs, float* y){
  int r0 = blockIdx.x * 16;
  int tid = threadIdx.x;
  int wv = tid >> 6, l = tid & 63;
  int g = l >> 4, c16 = l & 15;
  bf16x8 xh[4], xl[4];
  const f32x4* gp = (const f32x4*)x + (size_t)(r0 + c16)*32;
  #pragma unroll
  for (int s = 0; s < 4; ++s){
    f32x4 qa = gp[8*s + g], qb = gp[8*s + 4 + g];
    union { unsigned short u[8]; bf16x8 v; } uh, ul;
    #pragma unroll
    for (int m2 = 0; m2 < 4; ++m2){
      float a0 = qa[m2], b0 = qb[m2];
      uh.u[m2]   = f2h(a0); ul.u[m2]   = f2h(a0 - hif(a0));
      uh.u[4+m2] = f2h(b0); ul.u[4+m2] = f2h(b0 - hif(b0));
    }
    xh[s] = uh.v; xl[s] = ul.v;
  }
  for (int nt = wv; nt < 16; nt += 4){
    int m = nt >> 3, n = nt & 7;
    const float* bias = m ? bs : bl;
    float bb = bias[n*16 + c16];
    f32x4 acc = {bb, bb, bb, bb};
    const unsigned short* base = wf + (size_t)m*32768;
    #pragma unroll
    for (int s = 0; s < 4; ++s){
      const unsigned short* fb = base + (size_t)((n*4 + s)*64 + l)*8;
      bf16x8 Wh = *(const bf16x8*)fb;
      bf16x8 Wl = *(const bf16x8*)(fb + 16384);
      acc = __builtin_amdgcn_mfma_f32_16x16x32_bf16(xl[s], Wh, acc, 0, 0, 0);
      acc = __builtin_amdgcn_mfma_f32_16x16x32_bf16(xh[s], Wl, acc, 0, 0, 0);
      acc = __builtin_amdgcn_mfma_f32_16x16x32_bf16(xh[s], Wh, acc, 0, 0, 0);
    }
    #pragma unroll
    for (int r = 0; r < 4; ++r)
      y[(size_t)(r0 + 4*g + r)*256 + m*128 + n*16 + c16] = acc[r];
  }
}

// round-18: heads LN + W2 + epilogue (reduction chains + output indexing
// from the verified scalar k_heads). Wave = 1 row/iter (both heads), 8
// rows/wave, 32 rows/block, 960 blocks.
__global__ __launch_bounds__(256) void k_heads_ln(const float* y,
  const float* lg, const float* lbe, const float* lW2, const float* lb2v,
  const float* sg, const float* sbe, const float* sW2, const float* sb2v,
  void* outv, int q0, float* locsc, const float* maxv, const float* svp, const int* flagp){
  int tid = threadIdx.x;
  int wv = tid >> 6, lane = tid & 63;
  int j0 = lane, j1 = lane + 64;
  float lg0 = lg[j0], lg1 = lg[j1], lbe0 = lbe[j0], lbe1 = lbe[j1];
  float sg0 = sg[j0], sg1 = sg[j1], sbe0 = sbe[j0], sbe1 = sbe[j1];
  float lw2a0 = lW2[j0*2+0], lw2a1 = lW2[j0*2+1];
  float lw2b0 = lW2[j1*2+0], lw2b1 = lW2[j1*2+1];
  float sw2a0 = sW2[j0*2+0], sw2a1 = sW2[j0*2+1];
  float sw2b0 = sW2[j1*2+0], sw2b1 = sW2[j1*2+1];
  int flag = *flagp;
  float lb20 = lb2v[0], lb21 = lb2v[1], sb20 = sb2v[0], sb21 = sb2v[1];
  for (int r = 0; r < 8; ++r){
    int rg = blockIdx.x*32 + wv*8 + r;
    const float* yr = y + (size_t)rg*256;
    float a0 = yr[j0], a1 = yr[j1];           // loc
    float c0 = yr[128+j0], c1 = yr[128+j1];   // scl
    float sl = a0 + a1, ss = c0 + c1;
    #pragma unroll
    for (int off = 1; off < 64; off <<= 1){
      sl += __shfl_xor(sl, off);
      ss += __shfl_xor(ss, off);
    }
    float ml = sl*(1.f/128.f), ms = ss*(1.f/128.f);
    float d0 = a0-ml, d1 = a1-ml, e0v = c0-ms, e1v = c1-ms;
    float vl = d0*d0 + d1*d1, vs = e0v*e0v + e1v*e1v;
    #pragma unroll
    for (int off = 1; off < 64; off <<= 1){
      vl += __shfl_xor(vl, off);
      vs += __shfl_xor(vs, off);
    }
    float il = rsqrtf(vl*(1.f/128.f) + 1e-5f);
    float is = rsqrtf(vs*(1.f/128.f) + 1e-5f);
    float z0 = fmaxf(d0*il*lg0 + lbe0, 0.f);
    float z1 = fmaxf(d1*il*lg1 + lbe1, 0.f);
    float y0 = fmaxf(e0v*is*sg0 + sbe0, 0.f);
    float y1 = fmaxf(e1v*is*sg1 + sbe1, 0.f);
    float o0 = z0*lw2a0 + z1*lw2b0;
    float o1 = z0*lw2a1 + z1*lw2b1;
    float p0 = y0*sw2a0 + y1*sw2b0;
    float p1 = y0*sw2a1 + y1*sw2b1;
    #pragma unroll
    for (int off = 1; off < 64; off <<= 1){
      o0 += __shfl_xor(o0, off);
      o1 += __shfl_xor(o1, off);
      p0 += __shfl_xor(p0, off);
      p1 += __shfl_xor(p1, off);
    }
    if (lane == 0){
      int t = rg / cKN, rem = rg - t*cKN;
      int k = rem >> 7, nn = rem & 127;
      float u0 = o0 + lb20, u1 = o1 + lb21;
      {
        size_t oi = (((size_t)q0*cK + k)*cN + nn)*(cT*2) + t*2;
        if (flag){ ((bf16_t*)outv)[oi] = __float2bfloat16(u0); ((bf16_t*)outv)[oi+1] = __float2bfloat16(u1); }
        else     { ((float*)outv)[oi] = u0; ((float*)outv)[oi+1] = u1; }
        if (locsc){
          locsc[((size_t)t*cKN + rem)*2 + 0] = u0*maxv[nn*2+0] + svp[nn*2+0];
          locsc[((size_t)t*cKN + rem)*2 + 1] = u1*maxv[nn*2+1] + svp[nn*2+1];
        }
      }
      {
        float w0 = p0 + sb20, w1 = p1 + sb21;
        float e0 = (w0 > 0.f ? w0 : expm1f(w0)) + 1.001f;
        float e1 = (w1 > 0.f ? w1 : expm1f(w1)) + 1.001f;
        size_t oi = (((size_t)(q0+1)*cK + k)*cN + nn)*(cT*2) + t*2;
        if (flag){ ((bf16_t*)outv)[oi] = __float2bfloat16(e0); ((bf16_t*)outv)[oi+1] = __float2bfloat16(e1); }
        else     { ((float*)outv)[oi] = e0; ((float*)outv)[oi+1] = e1; }
      }
    }
  }
}

__global__ __launch_bounds__(256) void k_mask(const float* locsc, unsigned char* m){
  int st = blockIdx.x;
  int s = st / cT, t = st - s*cT;
  __shared__ float lx[cK][cNS], ly[cK][cNS];
  int tid = threadIdx.x;
  for (int p = tid; p < cK*cNS; p += 256){
    int k = p >> 5, i = p & 31;
    int row = t*cKN + k*cN + s*cNS + i;
    lx[k][i] = locsc[row*2+0];
    ly[k][i] = locsc[row*2+1];
  }
  __syncthreads();
  for (int p = tid; p < 1024; p += 256){
    int i = p >> 5, j = p & 31;
    bool any = false;
    for (int k = 0; k < cK; ++k){
      float dx = fabsf(lx[k][i]-lx[k][j]);
      float dy = fabsf(ly[k][i]-ly[k][j]);
      any = any || ((dx < 10.f) && (dy < 10.f));
    }
    m[st*1024 + p] = any ? 1 : 0;
  }
}

// round-17: fused Wo1+relu+Wo2 (validated).
__global__ __launch_bounds__(256) void k_wo12(const float* x, const unsigned short* wf1,
    const float* b1, const unsigned short* wf2, const float* b2, float* out){
  int r0 = blockIdx.x * 16;
  int tid = threadIdx.x;
  int wv = tid >> 6, l = tid & 63;
  int g = l >> 4, c16 = l & 15;
  __shared__ unsigned short HFh[8][64][8], HFl[8][64][8];   // 16 KB
  bf16x8 xh[4], xl[4];
  const f32x4* gp = (const f32x4*)x + (size_t)(r0 + c16)*32;
  #pragma unroll
  for (int s = 0; s < 4; ++s){
    f32x4 qa = gp[8*s + g], qb = gp[8*s + 4 + g];
    union { unsigned short u[8]; bf16x8 v; } uh, ul;
    #pragma unroll
    for (int m2 = 0; m2 < 4; ++m2){
      float a0 = qa[m2], b0v = qb[m2];
      uh.u[m2]   = f2h(a0);  ul.u[m2]   = f2h(a0 - hif(a0));
      uh.u[4+m2] = f2h(b0v); ul.u[4+m2] = f2h(b0v - hif(b0v));
    }
    xh[s] = uh.v; xl[s] = ul.v;
  }
  // Phase A: wo1 (+relu), tiles {wv, wv+4, wv+8, wv+12}
  #pragma unroll
  for (int q = 0; q < 4; ++q){
    int nt = wv + 4*q;
    float bb = b1[nt*16 + c16];
    f32x4 acc = {bb, bb, bb, bb};
    #pragma unroll
    for (int s = 0; s < 4; ++s){
      const unsigned short* fb = wf1 + (size_t)((nt*4 + s)*64 + l)*8;
      bf16x8 Wh = *(const bf16x8*)fb;
      bf16x8 Wl = *(const bf16x8*)(fb + 32768);
      acc = __builtin_amdgcn_mfma_f32_16x16x32_bf16(xl[s], Wh, acc, 0, 0, 0);
      acc = __builtin_amdgcn_mfma_f32_16x16x32_bf16(xh[s], Wl, acc, 0, 0, 0);
      acc = __builtin_amdgcn_mfma_f32_16x16x32_bf16(xh[s], Wh, acc, 0, 0, 0);
    }
    int scol = nt*16 + c16;
    int ps = scol >> 5, prem = scol & 31;
    int pgf = (prem >> 2) & 3;
    int pe  = ((prem >> 4) << 2) + (prem & 3);
    #pragma unroll
    for (int r = 0; r < 4; ++r){
      float z = fmaxf(acc[r], 0.f);
      HFh[ps][pgf*16 + 4*g + r][pe] = f2h(z);
      HFl[ps][pgf*16 + 4*g + r][pe] = f2h(z - hif(z));
    }
  }
  __syncthreads();
  // Phase B: wo2 (KF=8) from LDS fragments, tiles {wv, wv+4}
  bf16x8 yh[8], yl[8];
  #pragma unroll
  for (int s = 0; s < 8; ++s){
    yh[s] = *(const bf16x8*)&HFh[s][l][0];
    yl[s] = *(const bf16x8*)&HFl[s][l][0];
  }
  #pragma unroll
  for (int q = 0; q < 2; ++q){
    int nt = wv + 4*q;
    float bb = b2[nt*16 + c16];
    f32x4 acc = {bb, bb, bb, bb};
    #pragma unroll
    for (int s = 0; s < 8; ++s){
      const unsigned short* fb = wf2 + (size_t)((nt*8 + s)*64 + l)*8;
      bf16x8 Wh = *(const bf16x8*)fb;
      bf16x8 Wl = *(const bf16x8*)(fb + 32768);
      acc = __builtin_amdgcn_mfma_f32_16x16x32_bf16(yl[s], Wh, acc, 0, 0, 0);
      acc = __builtin_amdgcn_mfma_f32_16x16x32_bf16(yh[s], Wl, acc, 0, 0, 0);
      acc = __builtin_amdgcn_mfma_f32_16x16x32_bf16(yh[s], Wh, acc, 0, 0, 0);
    }
    #pragma unroll
    for (int r = 0; r < 4; ++r)
      out[(size_t)(r0 + 4*g + r)*cH + nt*16 + c16] = acc[r];
  }
}

// MFMA attention (validated, unchanged).
__global__ __launch_bounds__(256) void k_attn(const float* Q, const float* Kx, const float* V,
                       const unsigned char* msk, float* ctx){
  int qs   = blockIdx.x;        // 0..4 : group of 8 q-tiles (2 per wave)
  int head = blockIdx.y;        // 0..3
  int st   = blockIdx.z;        // s*cT + t
  int s = st / cT, t = st - s*cT;
  __shared__ unsigned short KLh[2][1024], KLl[2][1024], VLh[2][1024], VLl[2][1024]; // 16 KB
  int tid = threadIdx.x;
  int w = tid >> 6, lane = tid & 63;
  int g = lane >> 4, col = lane & 15;
  const float scl = 0.17677669529663687f;   // 1/sqrt(32)

  unsigned int mw0 = 0, mw1 = 0;
  {
    const unsigned int* mr0 = (const unsigned int*)(msk + st*1024 + col*32);
    const unsigned int* mr1 = (const unsigned int*)(msk + st*1024 + (16+col)*32);
    #pragma unroll
    for (int j2 = 0; j2 < 8; ++j2){
      mw0 |= (((mr0[j2] * 0x01020408u) >> 24) & 0xFu) << (4*j2);
      mw1 |= (((mr1[j2] * 0x01020408u) >> 24) & 0xFu) << (4*j2);
    }
  }

  bf16x8 Qh[2], Ql[2];
  int modes[2], ahs[2];
  #pragma unroll
  for (int i = 0; i < 2; ++i){
    int tt = qs*8 + 4*i + w;       // 0..39
    int mode = tt >> 1, ah = tt & 1;
    modes[i] = mode; ahs[i] = ah;
    int qrow = t*cKN + mode*cN + s*cNS + ah*16 + col;
    const f32x4* qp = (const f32x4*)Q + (size_t)qrow*32 + head*8;
    f32x4 qa = qp[g], qb = qp[4+g];
    union { unsigned short u[8]; bf16x8 v; } uh, ul;
    #pragma unroll
    for (int m = 0; m < 4; ++m){
      float x0 = qa[m]*scl;
      uh.u[m] = f2h(x0);
      ul.u[m] = f2h(x0 - hif(x0));
      float x1 = qb[m]*scl;
      uh.u[4+m] = f2h(x1);
      ul.u[4+m] = f2h(x1 - hif(x1));
    }
    Qh[i] = uh.v; Ql[i] = ul.v;
  }

  int kk = tid >> 3, f4 = tid & 7;
  int kwi = (((kk>>4)*4 + (f4&3))*16 + (kk&15))*8 + (f4>>2)*4;
  int vd = tid & 31, quad = tid >> 5;
  int vkey = (quad>>2)*16 + (quad&3)*4;
  int vwi = (((vd>>4)*4 + (quad&3))*16 + (vd&15))*8 + (quad>>2)*4;

  const size_t cstepK = (size_t)cN*32;
  const size_t cstepV = (size_t)cN*128;
  const float4* kptr = (const float4*)Kx + ((size_t)(t*cKN + s*cNS + kk))*32 + head*8 + f4;
  const float*  vptr = V + ((size_t)(t*cKN + s*cNS + vkey))*128 + head*32 + vd;

  float4 kv; float vm0, vm1, vm2, vm3;
  kv = *kptr; kptr += cstepK;
  vm0 = vptr[0]; vm1 = vptr[128]; vm2 = vptr[256]; vm3 = vptr[384]; vptr += cstepV;
  {
    unsigned int h0 = (unsigned int)f2h(kv.x) | ((unsigned int)f2h(kv.y)<<16);
    unsigned int h1 = (unsigned int)f2h(kv.z) | ((unsigned int)f2h(kv.w)<<16);
    float r0 = kv.x-hif(kv.x), r1 = kv.y-hif(kv.y), r2 = kv.z-hif(kv.z), r3 = kv.w-hif(kv.w);
    unsigned int l0 = (unsigned int)f2h(r0) | ((unsigned int)f2h(r1)<<16);
    unsigned int l1 = (unsigned int)f2h(r2) | ((unsigned int)f2h(r3)<<16);
    *(uint2*)&KLh[0][kwi] = make_uint2(h0,h1);
    *(uint2*)&KLl[0][kwi] = make_uint2(l0,l1);
    unsigned int vh0 = (unsigned int)f2h(vm0) | ((unsigned int)f2h(vm1)<<16);
    unsigned int vh1 = (unsigned int)f2h(vm2) | ((unsigned int)f2h(vm3)<<16);
    float s0 = vm0-hif(vm0), s1 = vm1-hif(vm1), s2 = vm2-hif(vm2), s3 = vm3-hif(vm3);
    unsigned int vl0 = (unsigned int)f2h(s0) | ((unsigned int)f2h(s1)<<16);
    unsigned int vl1 = (unsigned int)f2h(s2) | ((unsigned int)f2h(s3)<<16);
    *(uint2*)&VLh[0][vwi] = make_uint2(vh0,vh1);
    *(uint2*)&VLl[0][vwi] = make_uint2(vl0,vl1);
  }
  __syncthreads();

  const f32x4 Z = {0.f, 0.f, 0.f, 0.f};
  f32x4 O[2][2] = {{Z, Z}, {Z, Z}};
  float lac[2] = {0.f, 0.f};

  for (int ch = 0; ch < 20; ++ch){
    int par = ch & 1;
    if (ch < 19){
      kv = *kptr; kptr += cstepK;
      vm0 = vptr[0]; vm1 = vptr[128]; vm2 = vptr[256]; vm3 = vptr[384]; vptr += cstepV;
    }
    bf16x8 KAh0 = *(const bf16x8*)&KLh[par][( g      *16 + col)*8];
    bf16x8 KAl0 = *(const bf16x8*)&KLl[par][( g      *16 + col)*8];
    bf16x8 KAh1 = *(const bf16x8*)&KLh[par][((4 + g) *16 + col)*8];
    bf16x8 KAl1 = *(const bf16x8*)&KLl[par][((4 + g) *16 + col)*8];
    bf16x8 VBh0 = *(const bf16x8*)&VLh[par][( g      *16 + col)*8];
    bf16x8 VBl0 = *(const bf16x8*)&VLl[par][( g      *16 + col)*8];
    bf16x8 VBh1 = *(const bf16x8*)&VLh[par][((4 + g) *16 + col)*8];
    bf16x8 VBl1 = *(const bf16x8*)&VLl[par][((4 + g) *16 + col)*8];
    #pragma unroll
    for (int i = 0; i < 2; ++i){
      f32x4 sa = Z, sb = Z;
      sa = __builtin_amdgcn_mfma_f32_16x16x32_bf16(KAl0, Qh[i], sa, 0, 0, 0);
      sa = __builtin_amdgcn_mfma_f32_16x16x32_bf16(KAh0, Ql[i], sa, 0, 0, 0);
      sa = __builtin_amdgcn_mfma_f32_16x16x32_bf16(KAh0, Qh[i], sa, 0, 0, 0);
      sb = __builtin_amdgcn_mfma_f32_16x16x32_bf16(KAl1, Qh[i], sb, 0, 0, 0);
      sb = __builtin_amdgcn_mfma_f32_16x16x32_bf16(KAh1, Ql[i], sb, 0, 0, 0);
      sb = __builtin_amdgcn_mfma_f32_16x16x32_bf16(KAh1, Qh[i], sb, 0, 0, 0);
      unsigned int mw = ahs[i] ? mw1 : mw0;
      float p[8];
      #pragma unroll
      for (int r = 0; r < 4; ++r){
        float e0 = __expf(sa[r]);
        float e1 = __expf(sb[r]);
        p[r]   = ((mw >> (4*g + r)) & 1)        ? e0 : 0.f;
        p[4+r] = ((mw >> (16 + 4*g + r)) & 1)   ? e1 : 0.f;
      }
      lac[i] += ((p[0]+p[1])+(p[2]+p[3])) + ((p[4]+p[5])+(p[6]+p[7]));
      union { unsigned short u[8]; bf16x8 v; } Ph, Pl;
      #pragma unroll
      for (int e = 0; e < 8; ++e){
        Ph.u[e] = f2h(p[e]);
        Pl.u[e] = f2h(p[e] - hif(p[e]));
      }
      O[i][0] = __builtin_amdgcn_mfma_f32_16x16x32_bf16(Pl.v, VBh0, O[i][0], 0, 0, 0);
      O[i][0] = __builtin_amdgcn_mfma_f32_16x16x32_bf16(Ph.v, VBl0, O[i][0], 0, 0, 0);
      O[i][0] = __builtin_amdgcn_mfma_f32_16x16x32_bf16(Ph.v, VBh0, O[i][0], 0, 0, 0);
      O[i][1] = __builtin_amdgcn_mfma_f32_16x16x32_bf16(Pl.v, VBh1, O[i][1], 0, 0, 0);
      O[i][1] = __builtin_amdgcn_mfma_f32_16x16x32_bf16(Ph.v, VBl1, O[i][1], 0, 0, 0);
      O[i][1] = __builtin_amdgcn_mfma_f32_16x16x32_bf16(Ph.v, VBh1, O[i][1], 0, 0, 0);
    }
    __syncthreads();   // all frag reads of [par] done
    if (ch < 19){
      int nb = 1 - par;
      unsigned int h0 = (unsigned int)f2h(kv.x) | ((unsigned int)f2h(kv.y)<<16);
      unsigned int h1 = (unsigned int)f2h(kv.z) | ((unsigned int)f2h(kv.w)<<16);
      float r0 = kv.x-hif(kv.x), r1 = kv.y-hif(kv.y), r2 = kv.z-hif(kv.z), r3 = kv.w-hif(kv.w);
      unsigned int l0 = (unsigned int)f2h(r0) | ((unsigned int)f2h(r1)<<16);
      unsigned int l1 = (unsigned int)f2h(r2) | ((unsigned int)f2h(r3)<<16);
      *(uint2*)&KLh[nb][kwi] = make_uint2(h0,h1);
      *(uint2*)&KLl[nb][kwi] = make_uint2(l0,l1);
      unsigned int vh0 = (unsigned int)f2h(vm0) | ((unsigned int)f2h(vm1)<<16);
      unsigned int vh1 = (unsigned int)f2h(vm2) | ((unsigned int)f2h(vm3)<<16);
      float s0 = vm0-hif(vm0), s1 = vm1-hif(vm1), s2 = vm2-hif(vm2), s3 = vm3-hif(vm3);
      unsigned int vl0 = (unsigned int)f2h(s0) | ((unsigned int)f2h(s1)<<16);
      unsigned int vl1 = (unsigned int)f2h(s2) | ((unsigned int)f2h(s3)<<16);
      *(uint2*)&VLh[nb][vwi] = make_uint2(vh0,vh1);
      *(uint2*)&VLl[nb][vwi] = make_uint2(vl0,vl1);
    }
    __syncthreads();   // next buffer visible
  }

  #pragma unroll
  for (int i = 0; i < 2; ++i){
    float lsum = lac[i];
    lsum += __shfl_xor(lsum, 16);
    lsum += __shfl_xor(lsum, 32);
    int base = t*cKN + modes[i]*cN + s*cNS + ahs[i]*16;
    #pragma unroll
    for (int r = 0; r < 4; ++r){
      float lq = __shfl(lsum, 4*g + r);
      float rinv = 1.f / lq;
      float* cp = ctx + (size_t)(base + 4*g + r)*cH + head*cHD;
      cp[col]      = O[i][0][r] * rinv;
      cp[col+16]   = O[i][1][r] * rinv;
    }
  }
}

extern "C" void kernel_launch(void* const* d_in, const int* in_sizes, int n_in,
                              void* d_out, int out_size, void* d_ws, size_t ws_size,
                              hipStream_t stream){
  (void)in_sizes; (void)n_in; (void)out_size; (void)ws_size;

  int*   flagp = (int*)d_ws;
  float* conv  = (float*)d_ws + 64;
  float* big   = (float*)d_ws + 978112;

  const float* ge_f   = conv + 0;
  const float* hs_f   = conv + 196608;
  const float* cn_f   = conv + 212992;
  const float* sv_f   = conv + 229376;
  const float* mx_f   = conv + 229632;
  const float* mhpW_f = conv + 229888;
  const float* mhpb_f = conv + 557568;
  const float* mhpg_f = conv + 560128;
  const float* mhpbe_f= conv + 562688;
  const float* l1Wih_f= conv + 565248;
  const float* l1Whh_f= conv + 630784;
  const float* l1b_f  = conv + 696320;
  const float* l2Wih_f= conv + 696832;
  const float* l2Whh_f= conv + 762368;
  const float* l2b_f  = conv + 827904;
  const float* Wq_f   = conv + 828416;
  const float* bq_f   = conv + 844800;
  const float* Wk_f   = conv + 844928;
  const float* bk_f   = conv + 861312;
  const float* Wv_f   = conv + 861440;
  const float* bv_f   = conv + 877824;
  const float* Wo1_f  = conv + 877952;
  const float* bo1_f  = conv + 910720;
  const float* Wo2_f  = conv + 910976;
  const float* bo2_f  = conv + 943744;
  const float* locW1_f= conv + 943872;
  const float* locb1_f= conv + 960256;
  const float* locg_f = conv + 960384;
  const float* locbe_f= conv + 960512;
  const float* locW2_f= conv + 960640;
  const float* locb2_f= conv + 960896;
  const float* sclW1_f= conv + 960960;
  const float* sclb1_f= conv + 977344;
  const float* sclg_f = conv + 977472;
  const float* sclbe_f= conv + 977600;
  const float* sclW2_f= conv + 977728;
  const float* sclb2_f= conv + 977984;

  const size_t SLOT = (size_t)cT*cKN*cH;
  float* geb = big;
  float* o1b = big + SLOT;
  float* Qb  = big + 2*SLOT;
  float* Kb  = big + 3*SLOT;
  float* Vb  = big + 4*SLOT;
  float* locsc = big + 5*SLOT;
  unsigned char* maskb = (unsigned char*)(locsc + (size_t)cT*cKN*2);
  float* social = Vb;    // overlays V after attention

  unsigned short* wfrag = (unsigned short*)(conv + 229888);
  unsigned short* uA = (unsigned short*)(conv + 565248);
  unsigned short* uB = (unsigned short*)(conv + 696832);
  unsigned short* mfrag = (unsigned short*)(big + 2*SLOT);
  float* ytmp = big + 3*SLOT;    // mhp raw-y: 1536*2560 = one SLOT
  float* yhd  = big + 2*SLOT;    // heads raw-y: 30720*256 = two SLOTs (Qb..Kb)

  Ptrs ptrs;
  for (int i = 0; i < 37; ++i) ptrs.p[i] = d_in[i];

  k_detect<<<1, 64, 0, stream>>>((const unsigned short*)d_in[0], flagp, (unsigned int*)d_out);
  k_convert<<<(CONV_TOTAL+255)/256, 256, 0, stream>>>(ptrs, flagp, conv);
  k_wprep3<<<160, 256, 0, stream>>>(mhpW_f, mfrag);
  {
    dim3 mg(96, 5);   // 480 blocks, 32 n-tiles each
    k_gemm<4><<<mg, 256, 0, stream>>>(ge_f, mfrag, mhpb_f, ytmp, 160, 2560, 0, 327680, 32);
  }
  k_mhp_ln<<<1536, 256, 0, stream>>>(ytmp, mhpg_f, mhpbe_f, geb);
  k_wprep<<<128, 256, 0, stream>>>(l1Wih_f, l1Whh_f, l2Wih_f, l2Whh_f, wfrag);
  k_wprep2<<<72, 256, 0, stream>>>(Wq_f, Wk_f, Wv_f, Wo1_f, Wo2_f, locW1_f, sclW1_f, uA, uB);
  k_lstm_mfma<<<160, 512, 0, stream>>>(geb, o1b, hs_f, cn_f, (const float*)0,
                                       wfrag + 0, wfrag + 131072, l1b_f, 1);
  k_heads_gemm<<<cT*cKN/16, 256, 0, stream>>>(o1b, uA + 163840, locb1_f, sclb1_f, yhd);
  k_heads_ln<<<cT*cKN/32, 256, 0, stream>>>(yhd, locg_f, locbe_f, locW2_f, locb2_f,
                                        sclg_f, sclbe_f, sclW2_f, sclb2_f,
                                        d_out, 0, locsc, mx_f, sv_f, flagp);
  k_mask<<<cS*cT, 256, 0, stream>>>(locsc, maskb);
  k_gemm3<<<cT*cKN/16, 256, 0, stream>>>(o1b, uA, bq_f, bk_f, bv_f, Qb, Kb, Vb);
  {
    dim3 ag(5, 4, cS*cT);
    k_attn<<<ag, 256, 0, stream>>>(Qb, Kb, Vb, maskb, o1b);   // ctx overlays out1
  }
  k_wo12<<<cT*cKN/16, 256, 0, stream>>>(o1b, uA + 98304, bo1_f, uB, bo2_f, social);
  k_lstm_mfma<<<160, 512, 0, stream>>>(geb, o1b, hs_f, cn_f, social,
                                       wfrag + 262144, wfrag + 393216, l2b_f, 2);
  k_heads_gemm<<<cT*cKN/16, 256, 0, stream>>>(o1b, uA + 163840, locb1_f, sclb1_f, yhd);
  k_heads_ln<<<cT*cKN/32, 256, 0, stream>>>(yhd, locg_f, locbe_f, locW2_f, locb2_f,
                                        sclg_f, sclbe_f, sclW2_f, sclb2_f,
                                        d_out, 2, (float*)0, mx_f, sv_f, flagp);
}